// Round 12
// baseline (664.296 us; speedup 1.0000x reference)
//
#include <hip/hip_runtime.h>
#include <hip/hip_bf16.h>

#define E_NUM 160000
#define NN 10000
#define PI_F 3.14159265358979323846f

using u16 = unsigned short;
using u32 = unsigned int;
typedef short bf16x8 __attribute__((ext_vector_type(8)));
typedef float f32x16 __attribute__((ext_vector_type(16)));
typedef u32 u32x4 __attribute__((ext_vector_type(4)));

__device__ __forceinline__ float silu_fast(float z) {
    return z * __builtin_amdgcn_rcpf(1.0f + __expf(-z));
}
__device__ __forceinline__ float bfb2f(u32 bits16) {
    return __builtin_bit_cast(float, bits16 << 16);
}
__device__ __forceinline__ u32 f2bfb(float f) {
    return (u32)__builtin_bit_cast(u16, __float2bfloat16(f));
}
__device__ __forceinline__ u32 pack2(float lo, float hi) {
    return f2bfb(lo) | (f2bfb(hi) << 16);
}

// ---------------- dtype detection (inputs fp32 vs bf16) ----------------
__global__ void k_detect(const u16* __restrict__ posraw, int* __restrict__ flag) {
    int i = blockIdx.x * 256 + threadIdx.x;
    if (i >= 15000) return;
    float v = bfb2f((u32)posraw[2 * i]);
    if (!(fabsf(v) < 1e4f)) atomicOr(flag, 1);
}

// ---------------- fused dual-dtype ingest of all 9 fp tensors ----------------
__global__ void k_cvt_all(const void* s0, const void* s1, const void* s2,
                          const void* s3, const void* s4, const void* s5,
                          const void* s6, const void* s7, const void* s8,
                          float* __restrict__ dst, const int* __restrict__ flag) {
    int i = blockIdx.x * 256 + threadIdx.x;
    if (i >= 359792) return;
    const void* src; int off;
    if      (i < 30000)  { src = s0; off = i; }
    else if (i < 36144)  { src = s1; off = i - 30000; }
    else if (i < 68912)  { src = s2; off = i - 36144; }
    else if (i < 73008)  { src = s3; off = i - 68912; }
    else if (i < 81200)  { src = s4; off = i - 73008; }
    else if (i < 277808) { src = s5; off = i - 81200; }
    else if (i < 343344) { src = s6; off = i - 277808; }
    else if (i < 359728) { src = s7; off = i - 343344; }
    else                 { src = s8; off = i - 359728; }
    if (*flag) dst[i] = ((const float*)src)[i >= 30000 ? off : i];
    else       dst[i] = bfb2f((u32)((const u16*)src)[off]);
}

// ---------------- weight packers: [K][N] fp32 -> B-frag layout hi/lo ----------------
__global__ void k_pack(const float* __restrict__ W, int K, int Nshift,
                       u16* __restrict__ hi, u16* __restrict__ lo) {
    int i = blockIdx.x * 256 + threadIdx.x;
    int total = K << Nshift;
    if (i >= total) return;
    int k = i >> Nshift, n = i & ((1 << Nshift) - 1);
    float w = W[i];
    u16 h = (u16)f2bfb(w);
    float r = w - bfb2f((u32)h);
    int idx = ((((k >> 3) << Nshift) + n) << 3) + (k & 7);
    hi[idx] = h; lo[idx] = (u16)f2bfb(r);
}

// emb W1: rows 0..11 = hi(W), 12..23 = hi(W), 24..35 = lo(W), 36..63 = 0
__global__ void k_pack_emb1(const float* __restrict__ W /*12x512*/, u16* __restrict__ pk) {
    int i = blockIdx.x * 256 + threadIdx.x;
    if (i >= 64 * 512) return;
    int k = i >> 9, n = i & 511;
    u16 out = 0;
    if (k < 24) {
        out = (u16)f2bfb(W[(k % 12) * 512 + n]);
    } else if (k < 36) {
        float w = W[(k - 24) * 512 + n];
        u16 h = (u16)f2bfb(w);
        out = (u16)f2bfb(w - bfb2f((u32)h));
    }
    pk[((((k >> 3) << 9) + n) << 3) + (k & 7)] = out;
}

// ---------------- CSR build ----------------
__global__ void k_hist(const int* __restrict__ senders, int* __restrict__ counts) {
    int e = blockIdx.x * 256 + threadIdx.x;
    if (e < E_NUM) atomicAdd(&counts[senders[e]], 1);
}

__global__ __launch_bounds__(1024) void k_scan(const int* __restrict__ counts,
                                               int* __restrict__ rowstart) {
    __shared__ int part[1024];
    int t = threadIdx.x;
    int base = t * 10;
    int local[10];
    int sum = 0;
    #pragma unroll
    for (int i = 0; i < 10; i++) {
        int v = (base + i < NN) ? counts[base + i] : 0;
        local[i] = sum; sum += v;
    }
    part[t] = sum;
    __syncthreads();
    for (int off = 1; off < 1024; off <<= 1) {
        int v = (t >= off) ? part[t - off] : 0;
        __syncthreads();
        part[t] += v;
        __syncthreads();
    }
    int pre = (t == 0) ? 0 : part[t - 1];
    #pragma unroll
    for (int i = 0; i < 10; i++)
        if (base + i < NN) rowstart[base + i] = pre + local[i];
    if (t == 1023) rowstart[NN] = part[1023];
}

__global__ void k_copy_int(const int* __restrict__ src, int* __restrict__ dst, int n) {
    int i = blockIdx.x * 256 + threadIdx.x;
    if (i < n) dst[i] = src[i];
}

__global__ void k_fill(const int* __restrict__ senders, int* __restrict__ cursor,
                       int* __restrict__ edge_list) {
    int e = blockIdx.x * 256 + threadIdx.x;
    if (e >= E_NUM) return;
    int pos = atomicAdd(&cursor[senders[e]], 1);
    edge_list[pos] = e;
}

// ---------------- geometry in SORTED edge space ----------------
__global__ void k_geom(const float* __restrict__ posf, const int* __restrict__ species,
                       const int* __restrict__ senders, const int* __restrict__ receivers,
                       const int* __restrict__ edge_list,
                       int* __restrict__ ssend, int* __restrict__ srecv,
                       float* __restrict__ ux, float* __restrict__ uy, float* __restrict__ uz,
                       float* __restrict__ envb, u32* __restrict__ latin) {
    int e = blockIdx.x * 256 + threadIdx.x;
    if (e >= E_NUM) return;
    int orig = edge_list[e];
    int s = senders[orig], r = receivers[orig];
    ssend[e] = s; srecv[e] = r;
    float rx = posf[3 * r + 0] - posf[3 * s + 0];
    float ry = posf[3 * r + 1] - posf[3 * s + 1];
    float rz = posf[3 * r + 2] - posf[3 * s + 2];
    float d = sqrtf(rx * rx + ry * ry + rz * rz);
    float inv = 1.0f / fmaxf(d, 1e-6f);
    ux[e] = rx * inv; uy[e] = ry * inv; uz[e] = rz * inv;
    float xc = d * 0.5f;
    float env = 0.0f;
    if (xc < 1.0f) { float t = 1.0f - xc * xc; env = t * t; }
    envb[e] = env;
    float ft[12];
    float se = env * inv;
    #pragma unroll
    for (int n = 1; n <= 8; n++) ft[n - 1] = __sinf((float)n * PI_F * xc) * se;
    int ss = species[s], sr = species[r];
    ft[8] = (ss == 0) ? 1.0f : 0.0f;
    ft[9] = (ss == 1) ? 1.0f : 0.0f;
    ft[10] = (sr == 0) ? 1.0f : 0.0f;
    ft[11] = (sr == 1) ? 1.0f : 0.0f;
    u32 fh[12]; float fl[12];
    #pragma unroll
    for (int i = 0; i < 12; i++) {
        fh[i] = f2bfb(ft[i]);
        fl[i] = ft[i] - bfb2f(fh[i]);
    }
    #pragma unroll
    for (int j = 0; j < 6; j++) {
        u32 v = fh[2 * j] | (fh[2 * j + 1] << 16);
        latin[(size_t)j * E_NUM + e] = v;
        latin[(size_t)(12 + j) * E_NUM + e] = v;
        latin[(size_t)(6 + j) * E_NUM + e] = pack2(fl[2 * j], fl[2 * j + 1]);
    }
}

// ---------------- w_e = x @ W_env, edge-major fp32 [E,64] (layer 1 only) ----------------
__global__ __launch_bounds__(256) void k_we(const u16* __restrict__ x,
                                            const float* __restrict__ Wenv,
                                            float* __restrict__ we) {
    __shared__ float lds[256 * 33];
    int t = threadIdx.x;
    int e = blockIdx.x * 256 + t;
    float acc[64];
    #pragma unroll
    for (int c = 0; c < 64; c++) acc[c] = 0.0f;
    for (int k = 0; k < 64; k++) {
        float v = bfb2f((u32)x[(size_t)k * E_NUM + e]);
        const float* wr = Wenv + k * 64;
        #pragma unroll
        for (int c = 0; c < 64; c++) acc[c] = fmaf(v, wr[c], acc[c]);
    }
    float* dstb = we + (size_t)blockIdx.x * 256 * 64;
    for (int half = 0; half < 2; half++) {
        if (half) __syncthreads();
        #pragma unroll
        for (int c = 0; c < 32; c++) lds[t * 33 + c] = acc[half * 32 + c];
        __syncthreads();
        float* dst = dstb + half * 32;
        #pragma unroll
        for (int k = 0; k < 32; k++) {
            int g = k * 256 + t;
            int el = g >> 5, c = g & 31;
            dst[(size_t)el * 64 + c] = lds[el * 33 + c];
        }
    }
}

// ---------------- rho gather ----------------
__global__ __launch_bounds__(256) void k_rho_gather(
    const float* __restrict__ we, const int* __restrict__ rowstart,
    const float* __restrict__ ux, const float* __restrict__ uy,
    const float* __restrict__ uz,
    float* __restrict__ rho0, float* __restrict__ rho1) {
    int wv = (blockIdx.x * 256 + threadIdx.x) >> 6;
    int c = threadIdx.x & 63;
    if (wv >= NN) return;
    int start = rowstart[wv], end = rowstart[wv + 1];
    float s0 = 0.0f, sx = 0.0f, sy = 0.0f, sz = 0.0f;
    for (int j = start; j < end; j++) {
        float w = we[(size_t)j * 64 + c];
        float a = ux[j], b = uy[j], g = uz[j];
        s0 += w;
        sx = fmaf(w, a, sx);
        sy = fmaf(w, b, sy);
        sz = fmaf(w, g, sz);
    }
    const float inv3 = 1.0f / 3.0f;
    rho0[(size_t)wv * 64 + c] = s0 * inv3;
    rho1[(size_t)wv * 192 + 3 * c + 0] = sx * inv3;
    rho1[(size_t)wv * 192 + 3 * c + 1] = sy * inv3;
    rho1[(size_t)wv * 192 + 3 * c + 2] = sz * inv3;
}

// ---------------- stage layer 0 ----------------
__global__ __launch_bounds__(512) void k_stage_l0(
    const float* __restrict__ Wv,
    const float* __restrict__ rho0A, const float* __restrict__ rho1A,
    const int* __restrict__ ssend,
    const float* __restrict__ ux, const float* __restrict__ uy,
    const float* __restrict__ uz,
    const u16* __restrict__ x0, u32* __restrict__ latin) {
    __shared__ u32 in2[32 * 64];
    int lane = threadIdx.x & 63;
    int sub = threadIdx.x >> 6;
    int subu = __builtin_amdgcn_readfirstlane(sub);
    int e = blockIdx.x * 64 + lane;
    int s = ssend[e];
    const float* r1 = rho1A + (size_t)s * 192;
    const float* r0 = rho0A + (size_t)s * 64;

    #pragma unroll
    for (int j = 0; j < 4; j++) {
        int rr = subu * 4 + j;
        u32 v = (u32)x0[(size_t)(2 * rr) * E_NUM + e] |
                ((u32)x0[(size_t)(2 * rr + 1) * E_NUM + e] << 16);
        in2[rr * 64 + lane] = v;
        latin[(size_t)rr * E_NUM + e] = v;
    }
    __syncthreads();

    int c0 = subu * 8;
    float a[8] = {0, 0, 0, 0, 0, 0, 0, 0};
    for (int k2 = 0; k2 < 32; k2++) {
        u32 p = in2[k2 * 64 + lane];
        float v0 = bfb2f(p & 0xffffu), v1 = bfb2f(p >> 16);
        const float* wv0 = Wv + (2 * k2) * 64 + c0;
        const float* wv1 = wv0 + 64;
        #pragma unroll
        for (int i = 0; i < 8; i++) a[i] = fmaf(v0, wv0[i], a[i]);
        #pragma unroll
        for (int i = 0; i < 8; i++) a[i] = fmaf(v1, wv1[i], a[i]);
    }
    float u0 = ux[e], u1 = uy[e], u2 = uz[e];
    float ts[8];
    #pragma unroll
    for (int i = 0; i < 8; i++) {
        int c = c0 + i;
        float dot = u0 * r1[3 * c] + u1 * r1[3 * c + 1] + u2 * r1[3 * c + 2];
        ts[i] = a[i] * dot;
    }
    #pragma unroll
    for (int j = 0; j < 4; j++) {
        latin[(size_t)(32 + subu * 4 + j) * E_NUM + e] = pack2(ts[2 * j], ts[2 * j + 1]);
    }
    #pragma unroll
    for (int j = 0; j < 4; j++) {
        int ch = 2 * (subu * 4 + j);
        latin[(size_t)(64 + subu * 4 + j) * E_NUM + e] = pack2(r0[ch], r0[ch + 1]);
    }
}

// ---------------- stage layer 1 ----------------
__global__ __launch_bounds__(512) void k_stage_l1(
    const float* __restrict__ Wv, const float* __restrict__ Wmix0,
    const float* __restrict__ rho0A, const float* __restrict__ rho1A,
    const float* __restrict__ rho0B, const float* __restrict__ rho1B,
    const int* __restrict__ ssend,
    const float* __restrict__ ux, const float* __restrict__ uy,
    const float* __restrict__ uz,
    const u16* __restrict__ x0, const u16* __restrict__ x1,
    u32* __restrict__ latin) {
    __shared__ u32 in2[32 * 64];
    __shared__ u32 xt0[32 * 64];
    int lane = threadIdx.x & 63;
    int sub = threadIdx.x >> 6;
    int subu = __builtin_amdgcn_readfirstlane(sub);
    int e = blockIdx.x * 64 + lane;
    int s = ssend[e];

    #pragma unroll
    for (int j = 0; j < 4; j++) {
        int rr = subu * 4 + j;
        u32 v = (u32)x1[(size_t)(2 * rr) * E_NUM + e] |
                ((u32)x1[(size_t)(2 * rr + 1) * E_NUM + e] << 16);
        in2[rr * 64 + lane] = v;
        latin[(size_t)rr * E_NUM + e] = v;
        u32 v0 = (u32)x0[(size_t)(2 * rr) * E_NUM + e] |
                 ((u32)x0[(size_t)(2 * rr + 1) * E_NUM + e] << 16);
        xt0[rr * 64 + lane] = v0;
    }
    __syncthreads();

    int c0 = subu * 8;
    float a[8] = {0, 0, 0, 0, 0, 0, 0, 0};
    float m1[8] = {0, 0, 0, 0, 0, 0, 0, 0};
    float m2[8] = {0, 0, 0, 0, 0, 0, 0, 0};
    for (int k2 = 0; k2 < 32; k2++) {
        u32 p0 = xt0[k2 * 64 + lane];
        float a0 = bfb2f(p0 & 0xffffu), a1 = bfb2f(p0 >> 16);
        const float* wv0 = Wv + (2 * k2) * 64 + c0;
        const float* wv1 = wv0 + 64;
        #pragma unroll
        for (int i = 0; i < 8; i++) a[i] = fmaf(a0, wv0[i], a[i]);
        #pragma unroll
        for (int i = 0; i < 8; i++) a[i] = fmaf(a1, wv1[i], a[i]);
        u32 p1 = in2[k2 * 64 + lane];
        float b0 = bfb2f(p1 & 0xffffu), b1 = bfb2f(p1 >> 16);
        const float* wm0 = Wmix0 + (2 * k2) * 128 + c0;
        const float* wm1 = wm0 + 128;
        #pragma unroll
        for (int i = 0; i < 8; i++) {
            m1[i] = fmaf(b0, wm0[i], m1[i]);
            m2[i] = fmaf(b0, wm0[64 + i], m2[i]);
            m1[i] = fmaf(b1, wm1[i], m1[i]);
            m2[i] = fmaf(b1, wm1[64 + i], m2[i]);
        }
    }
    float u0 = ux[e], u1 = uy[e], u2 = uz[e];
    const float* r1A = rho1A + (size_t)s * 192;
    const float* r0A = rho0A + (size_t)s * 64;
    const float* r1B = rho1B + (size_t)s * 192;
    const float* r0B = rho0B + (size_t)s * 64;
    float ts[8];
    #pragma unroll
    for (int i = 0; i < 8; i++) {
        int c = c0 + i;
        float v0 = a[i] * u0, v1 = a[i] * u1, v2 = a[i] * u2;
        float aA0 = r1A[3 * c], aA1 = r1A[3 * c + 1], aA2 = r1A[3 * c + 2];
        float rc = r0A[c];
        float w0 = m1[i] * v0 * rc + m2[i] * (v1 * aA2 - v2 * aA1);
        float w1 = m1[i] * v1 * rc + m2[i] * (v2 * aA0 - v0 * aA2);
        float w2 = m1[i] * v2 * rc + m2[i] * (v0 * aA1 - v1 * aA0);
        ts[i] = w0 * r1B[3 * c] + w1 * r1B[3 * c + 1] + w2 * r1B[3 * c + 2];
    }
    #pragma unroll
    for (int j = 0; j < 4; j++) {
        latin[(size_t)(32 + subu * 4 + j) * E_NUM + e] = pack2(ts[2 * j], ts[2 * j + 1]);
    }
    #pragma unroll
    for (int j = 0; j < 4; j++) {
        int ch = 2 * (subu * 4 + j);
        latin[(size_t)(64 + subu * 4 + j) * E_NUM + e] = pack2(r0B[ch], r0B[ch + 1]);
    }
}

// =====================================================================
// MFMA MLP v5: 32x32x16 shape (half the MFMA instrs + half the LDS reads
// of the 16x16x32 version). Halves of 256 hidden cols. Optional fused
// we = x @ Wenv mini-GEMM on the epilogue (emb only).
// Layouts (guide-verified): A/B m|n = lane&31, k = (lane>>5)*8+j;
// C/D col = lane&31, row = (reg&3)+8*(reg>>2)+4*(lane>>5).
// =====================================================================
template<int KSTEPS, int MODE, int HASLO, int FUSEWE>
__global__ __launch_bounds__(512) void k_mlp(
    const u32* __restrict__ latin,
    const u16* __restrict__ W1hi, const u16* __restrict__ W1lo,
    const u16* __restrict__ W2hi, const u16* __restrict__ W2lo,
    const float* __restrict__ envb,
    const u16* __restrict__ xprev,
    u16* __restrict__ xout,
    const u16* __restrict__ wehi, const u16* __restrict__ welo,
    float* __restrict__ webuf) {
    constexpr int INA_DW = KSTEPS * 16;          // dwords per inA row
    __shared__ __align__(16) char smem[KSTEPS * 4096 + 65536];
    u32* inA = (u32*)smem;                        // 64 rows x INA_DW
    u16* hA = (u16*)(smem + KSTEPS * 4096);       // 64 rows x 256 cols (half of h)
    float* epi = (float*)smem;                    // 64 x 65 fp32 (epilogue)
    int lane = threadIdx.x & 63;
    int sub = threadIdx.x >> 6;
    int w = __builtin_amdgcn_readfirstlane(sub);
    int l31 = lane & 31, khi = lane >> 5;
    int e0 = blockIdx.x * 64;
    int e = e0 + lane;

    // ---- stage lat_in ----
    constexpr int NCH = KSTEPS * 4;
    constexpr int CPW = NCH / 8;
    #pragma unroll
    for (int j = 0; j < CPW; j++) {
        int c = w * CPW + j;
        u32x4 v;
        #pragma unroll
        for (int i = 0; i < 4; i++) v[i] = latin[(size_t)(c * 4 + i) * E_NUM + e];
        int slot = (c & ~7) | ((c ^ lane) & 7);
        *(u32x4*)(&inA[lane * INA_DW + slot * 4]) = v;
    }
    __syncthreads();

    // phase-2 wave assignment
    int mt2 = w & 1, nt2 = (w >> 1) & 1, kq = w >> 2;
    f32x16 acc2;
    #pragma unroll
    for (int i = 0; i < 16; i++) acc2[i] = 0.0f;

    constexpr int KS16 = KSTEPS * 2;   // number of K=16 steps in phase 1

    #pragma unroll
    for (int hh = 0; hh < 2; hh++) {
        // ---- phase 1: n-tile = w (cols hh*256 + w*32 .. +32), all 64 rows ----
        f32x16 acc1[2];
        #pragma unroll
        for (int mt = 0; mt < 2; mt++)
            #pragma unroll
            for (int i = 0; i < 16; i++) acc1[mt][i] = 0.0f;
        int n1 = hh * 256 + w * 32 + l31;
        #pragma unroll
        for (int ks = 0; ks < KS16; ks++) {
            int c = ks * 2 + khi;
            bf16x8 afr[2];
            #pragma unroll
            for (int mt = 0; mt < 2; mt++) {
                int row = mt * 32 + l31;
                int slot = (c & ~7) | ((c ^ row) & 7);
                afr[mt] = *(const bf16x8*)(&inA[row * INA_DW + slot * 4]);
            }
            size_t bidx = (((size_t)c << 9) + n1) << 3;
            bf16x8 bh = *(const bf16x8*)(W1hi + bidx);
            acc1[0] = __builtin_amdgcn_mfma_f32_32x32x16_bf16(afr[0], bh, acc1[0], 0, 0, 0);
            acc1[1] = __builtin_amdgcn_mfma_f32_32x32x16_bf16(afr[1], bh, acc1[1], 0, 0, 0);
            if (HASLO) {
                bf16x8 bl = *(const bf16x8*)(W1lo + bidx);
                acc1[0] = __builtin_amdgcn_mfma_f32_32x32x16_bf16(afr[0], bl, acc1[0], 0, 0, 0);
                acc1[1] = __builtin_amdgcn_mfma_f32_32x32x16_bf16(afr[1], bl, acc1[1], 0, 0, 0);
            }
        }
        __syncthreads();   // prior half's hA reads done
        // hA write: col kh = w*32 + l31, m = mt*32 + (reg&3)+8*(reg>>2)+4*khi
        {
            int kh = w * 32 + l31;
            int c2 = kh >> 3;
            #pragma unroll
            for (int mt = 0; mt < 2; mt++) {
                #pragma unroll
                for (int reg = 0; reg < 16; reg++) {
                    int m = mt * 32 + (reg & 3) + 8 * (reg >> 2) + 4 * khi;
                    int slot = (c2 & 24) | ((c2 ^ m) & 7);
                    hA[m * 256 + slot * 8 + (kh & 7)] = (u16)f2bfb(silu_fast(acc1[mt][reg]));
                }
            }
        }
        __syncthreads();
        // ---- phase 2 partial: this half's 256 K-cols, wave's quarter (128) ----
        #pragma unroll
        for (int ks = 0; ks < 8; ks++) {
            int cl = kq * 16 + ks * 2 + khi;
            int row = mt2 * 32 + l31;
            int slot = (cl & 24) | ((cl ^ row) & 7);
            bf16x8 a = *(const bf16x8*)(&hA[row * 256 + slot * 8]);
            int kc2 = hh * 32 + cl;
            int n2 = nt2 * 32 + l31;
            size_t bidx = (((size_t)kc2 << 6) + n2) << 3;
            bf16x8 bh = *(const bf16x8*)(W2hi + bidx);
            acc2 = __builtin_amdgcn_mfma_f32_32x32x16_bf16(a, bh, acc2, 0, 0, 0);
            bf16x8 bl = *(const bf16x8*)(W2lo + bidx);
            acc2 = __builtin_amdgcn_mfma_f32_32x32x16_bf16(a, bl, acc2, 0, 0, 0);
        }
    }
    __syncthreads();   // all inA/hA use done; epi overlays
    // reduce K-partials: kq=0 writes, kq=1 adds
    if (kq == 0) {
        #pragma unroll
        for (int reg = 0; reg < 16; reg++) {
            int m = mt2 * 32 + (reg & 3) + 8 * (reg >> 2) + 4 * khi;
            int cc = nt2 * 32 + l31;
            epi[cc * 65 + m] = acc2[reg];
        }
    }
    __syncthreads();
    if (kq == 1) {
        #pragma unroll
        for (int reg = 0; reg < 16; reg++) {
            int m = mt2 * 32 + (reg & 3) + 8 * (reg >> 2) + 4 * khi;
            int cc = nt2 * 32 + l31;
            epi[cc * 65 + m] += acc2[reg];
        }
    }
    __syncthreads();
    float env = envb[e];
    const float is2 = 0.70710678118654752f;
    #pragma unroll
    for (int i = 0; i < 8; i++) {
        int cc = w * 8 + i;
        float v = epi[cc * 65 + lane];
        float res;
        if (MODE) res = (bfb2f((u32)xprev[(size_t)cc * E_NUM + e]) + v * env) * is2;
        else      res = v * env;
        xout[(size_t)cc * E_NUM + e] = (u16)f2bfb(res);
        if (FUSEWE) epi[cc * 65 + lane] = res;   // overwrite with final value
    }
    if (FUSEWE) {
        __syncthreads();
        if (w < 4) {
            int mtw = w & 1, ntw = w >> 1;
            f32x16 accw;
            #pragma unroll
            for (int i = 0; i < 16; i++) accw[i] = 0.0f;
            #pragma unroll
            for (int ks = 0; ks < 4; ks++) {
                int c4 = ks * 2 + khi;
                int row = mtw * 32 + l31;
                bf16x8 af;
                #pragma unroll
                for (int j = 0; j < 8; j++)
                    af[j] = (short)f2bfb(epi[(c4 * 8 + j) * 65 + row]);
                int n4 = ntw * 32 + l31;
                size_t bidx = (((size_t)c4 << 6) + n4) << 3;
                bf16x8 bh = *(const bf16x8*)(wehi + bidx);
                accw = __builtin_amdgcn_mfma_f32_32x32x16_bf16(af, bh, accw, 0, 0, 0);
                bf16x8 bl = *(const bf16x8*)(welo + bidx);
                accw = __builtin_amdgcn_mfma_f32_32x32x16_bf16(af, bl, accw, 0, 0, 0);
            }
            #pragma unroll
            for (int reg = 0; reg < 16; reg++) {
                int rowD = mtw * 32 + (reg & 3) + 8 * (reg >> 2) + 4 * khi;
                int colD = ntw * 32 + l31;
                webuf[(size_t)(e0 + rowD) * 64 + colD] = accw[reg];
            }
        }
    }
}

// ---------------- readout ----------------
__global__ void k_readout(const u16* __restrict__ x, const float* __restrict__ Wout,
                          const float* __restrict__ envb, const int* __restrict__ srecv,
                          float* __restrict__ node_acc) {
    int e = blockIdx.x * 256 + threadIdx.x;
    if (e >= E_NUM) return;
    float a = 0.0f;
    #pragma unroll
    for (int c = 0; c < 64; c++) {
        a = fmaf(bfb2f((u32)x[(size_t)c * E_NUM + e]), Wout[c], a);
    }
    a *= envb[e] * (1.0f / 3.0f);
    atomicAdd(&node_acc[srecv[e]], a);
}

__global__ void k_out(const float* __restrict__ node_acc, void* __restrict__ out,
                      const int* __restrict__ flag) {
    int n = blockIdx.x * 256 + threadIdx.x;
    if (n >= NN) return;
    float v = node_acc[n];
    if (*flag) ((float*)out)[n] = v;
    else       ((u16*)out)[n] = (u16)f2bfb(v);
}

extern "C" void kernel_launch(void* const* d_in, const int* in_sizes, int n_in,
                              void* d_out, int out_size, void* d_ws, size_t ws_size,
                              hipStream_t stream) {
    const void* posr   = d_in[0];
    const void* Wemb1r = d_in[1];
    const void* Wemb2r = d_in[2];
    const void* Wvr    = d_in[3];
    const void* Wenvr  = d_in[4];
    const void* Wlat1r = d_in[5];
    const void* Wlat2r = d_in[6];
    const void* Wmixr  = d_in[7];
    const void* Woutr  = d_in[8];
    const int* species   = (const int*)d_in[9];
    const int* senders   = (const int*)d_in[10];
    const int* receivers = (const int*)d_in[11];

    char* p = (char*)d_ws;
    auto alloc = [&](size_t bytes) -> void* {
        void* rp = (void*)p;
        p += (bytes + 255) & ~(size_t)255;
        return rp;
    };
    int*   flag  = (int*)alloc(4);
    float* wbuf  = (float*)alloc(359792 * 4);
    float* posf  = wbuf;
    float* Wemb1 = wbuf + 30000;
    float* Wemb2 = wbuf + 36144;
    float* Wv    = wbuf + 68912;
    float* Wenv  = wbuf + 73008;
    float* Wlat1 = wbuf + 81200;
    float* Wlat2 = wbuf + 277808;
    float* Wmix  = wbuf + 343344;
    float* Wout  = wbuf + 359728;
    const size_t E = E_NUM;
    float* ux   = (float*)alloc(E * 4);
    float* uy   = (float*)alloc(E * 4);
    float* uz   = (float*)alloc(E * 4);
    float* envb = (float*)alloc(E * 4);
    float* rho0A = (float*)alloc((size_t)NN * 64 * 4);
    float* rho1A = (float*)alloc((size_t)NN * 192 * 4);
    float* rho0B = (float*)alloc((size_t)NN * 64 * 4);
    float* rho1B = (float*)alloc((size_t)NN * 192 * 4);
    float* node_acc = (float*)alloc((size_t)NN * 4);
    int* counts    = (int*)alloc((size_t)NN * 4);
    int* rowstart  = (int*)alloc((size_t)(NN + 1) * 4);
    int* cursor    = (int*)alloc((size_t)NN * 4);
    int* edge_list = (int*)alloc(E * 4);
    int* ssend     = (int*)alloc(E * 4);
    int* srecv     = (int*)alloc(E * 4);
    void* unionbuf = alloc(96 * E * 4);
    u32*   latin = (u32*)unionbuf;
    float* webuf = (float*)unionbuf;                       // layer-1 we (base)
    float* we0   = (float*)unionbuf + (size_t)32 * E;      // layer-0 we (rows 32..95)
    u16* x0 = (u16*)alloc(64 * E * 2);
    u16* x1 = (u16*)alloc(64 * E * 2);
    u16* w1hi = (u16*)alloc(2 * 98304 * 2);
    u16* w1lo = (u16*)alloc(2 * 98304 * 2);
    u16* w2hi = (u16*)alloc(2 * 32768 * 2);
    u16* w2lo = (u16*)alloc(2 * 32768 * 2);
    u16* e1hi = (u16*)alloc(32768 * 2);
    u16* e2hi = (u16*)alloc(32768 * 2);
    u16* e2lo = (u16*)alloc(32768 * 2);
    u16* wvhi = (u16*)alloc(4096 * 2);   // packed Wenv layer 0 (for fused we)
    u16* wvlo = (u16*)alloc(4096 * 2);

    hipMemsetAsync(flag, 0, 4, stream);
    hipMemsetAsync(counts, 0, (size_t)NN * 4, stream);
    hipMemsetAsync(node_acc, 0, (size_t)NN * 4, stream);
    hipMemsetAsync(latin + (size_t)18 * E, 0, (size_t)14 * E * 4, stream);

    k_detect<<<(15000 + 255) / 256, 256, 0, stream>>>((const u16*)posr, flag);

    k_cvt_all<<<(359792 + 255) / 256, 256, 0, stream>>>(
        posr, Wemb1r, Wemb2r, Wvr, Wenvr, Wlat1r, Wlat2r, Wmixr, Woutr,
        wbuf, flag);

    k_pack_emb1<<<128, 256, 0, stream>>>(Wemb1, e1hi);
    k_pack<<<128, 256, 0, stream>>>(Wemb2, 512, 6, e2hi, e2lo);
    k_pack<<<16, 256, 0, stream>>>(Wenv, 64, 6, wvhi, wvlo);
    for (int l = 0; l < 2; l++) {
        k_pack<<<384, 256, 0, stream>>>(Wlat1 + l * 98304, 192, 9,
                                        w1hi + l * 98304, w1lo + l * 98304);
        k_pack<<<128, 256, 0, stream>>>(Wlat2 + l * 32768, 512, 6,
                                        w2hi + l * 32768, w2lo + l * 32768);
    }

    // CSR over senders -> sorted edge order
    k_hist<<<625, 256, 0, stream>>>(senders, counts);
    k_scan<<<1, 1024, 0, stream>>>(counts, rowstart);
    k_copy_int<<<(NN + 255) / 256, 256, 0, stream>>>(rowstart, cursor, NN);
    k_fill<<<625, 256, 0, stream>>>(senders, cursor, edge_list);

    // embedding (sorted edge space) + fused layer-0 we
    k_geom<<<625, 256, 0, stream>>>(posf, species, senders, receivers, edge_list,
                                    ssend, srecv, ux, uy, uz, envb, latin);
    k_mlp<2, 0, 0, 1><<<2500, 512, 0, stream>>>(latin, e1hi, nullptr, e2hi, e2lo,
                                                envb, nullptr, x0, wvhi, wvlo, we0);

    // layer 0
    k_rho_gather<<<2500, 256, 0, stream>>>(we0, rowstart, ux, uy, uz,
                                           rho0A, rho1A);
    k_stage_l0<<<2500, 512, 0, stream>>>(Wv, rho0A, rho1A, ssend, ux, uy, uz,
                                         x0, latin);
    k_mlp<6, 1, 1, 0><<<2500, 512, 0, stream>>>(latin, w1hi, w1lo, w2hi, w2lo,
                                                envb, x0, x1, nullptr, nullptr, nullptr);

    // layer 1
    k_we<<<625, 256, 0, stream>>>(x1, Wenv + 4096, webuf);
    k_rho_gather<<<2500, 256, 0, stream>>>(webuf, rowstart, ux, uy, uz,
                                           rho0B, rho1B);
    k_stage_l1<<<2500, 512, 0, stream>>>(Wv, Wmix, rho0A, rho1A, rho0B, rho1B,
                                         ssend, ux, uy, uz, x0, x1, latin);
    k_mlp<6, 1, 1, 0><<<2500, 512, 0, stream>>>(latin, w1hi + 98304, w1lo + 98304,
                                                w2hi + 32768, w2lo + 32768,
                                                envb, x1, x1, nullptr, nullptr, nullptr);

    k_readout<<<625, 256, 0, stream>>>(x1, Wout, envb, srecv, node_acc);
    k_out<<<(NN + 255) / 256, 256, 0, stream>>>(node_acc, d_out, flag);
}

// Round 13
// 638.679 us; speedup vs baseline: 1.0401x; 1.0401x over previous
//
#include <hip/hip_runtime.h>
#include <hip/hip_bf16.h>

#define E_NUM 160000
#define NN 10000
#define PI_F 3.14159265358979323846f

using u16 = unsigned short;
using u32 = unsigned int;
typedef short bf16x8 __attribute__((ext_vector_type(8)));
typedef float f32x16 __attribute__((ext_vector_type(16)));
typedef u32 u32x4 __attribute__((ext_vector_type(4)));

__device__ __forceinline__ float silu_fast(float z) {
    return z * __builtin_amdgcn_rcpf(1.0f + __expf(-z));
}
__device__ __forceinline__ float bfb2f(u32 bits16) {
    return __builtin_bit_cast(float, bits16 << 16);
}
__device__ __forceinline__ u32 f2bfb(float f) {
    return (u32)__builtin_bit_cast(u16, __float2bfloat16(f));
}
__device__ __forceinline__ u32 pack2(float lo, float hi) {
    return f2bfb(lo) | (f2bfb(hi) << 16);
}

// ---------------- dtype detection (inputs fp32 vs bf16) ----------------
__global__ void k_detect(const u16* __restrict__ posraw, int* __restrict__ flag) {
    int i = blockIdx.x * 256 + threadIdx.x;
    if (i >= 15000) return;
    float v = bfb2f((u32)posraw[2 * i]);
    if (!(fabsf(v) < 1e4f)) atomicOr(flag, 1);
}

// ---------------- fused dual-dtype ingest of all 9 fp tensors ----------------
__global__ void k_cvt_all(const void* s0, const void* s1, const void* s2,
                          const void* s3, const void* s4, const void* s5,
                          const void* s6, const void* s7, const void* s8,
                          float* __restrict__ dst, const int* __restrict__ flag) {
    int i = blockIdx.x * 256 + threadIdx.x;
    if (i >= 359792) return;
    const void* src; int off;
    if      (i < 30000)  { src = s0; off = i; }
    else if (i < 36144)  { src = s1; off = i - 30000; }
    else if (i < 68912)  { src = s2; off = i - 36144; }
    else if (i < 73008)  { src = s3; off = i - 68912; }
    else if (i < 81200)  { src = s4; off = i - 73008; }
    else if (i < 277808) { src = s5; off = i - 81200; }
    else if (i < 343344) { src = s6; off = i - 277808; }
    else if (i < 359728) { src = s7; off = i - 343344; }
    else                 { src = s8; off = i - 359728; }
    if (*flag) dst[i] = ((const float*)src)[off];
    else       dst[i] = bfb2f((u32)((const u16*)src)[off]);
}

// ---------------- weight packers: [K][N] fp32 -> B-frag layout hi/lo ----------------
__global__ void k_pack(const float* __restrict__ W, int K, int Nshift,
                       u16* __restrict__ hi, u16* __restrict__ lo) {
    int i = blockIdx.x * 256 + threadIdx.x;
    int total = K << Nshift;
    if (i >= total) return;
    int k = i >> Nshift, n = i & ((1 << Nshift) - 1);
    float w = W[i];
    u16 h = (u16)f2bfb(w);
    float r = w - bfb2f((u32)h);
    int idx = ((((k >> 3) << Nshift) + n) << 3) + (k & 7);
    hi[idx] = h; lo[idx] = (u16)f2bfb(r);
}

// emb W1: rows 0..11 = hi(W), 12..23 = hi(W), 24..35 = lo(W), 36..63 = 0
__global__ void k_pack_emb1(const float* __restrict__ W /*12x512*/, u16* __restrict__ pk) {
    int i = blockIdx.x * 256 + threadIdx.x;
    if (i >= 64 * 512) return;
    int k = i >> 9, n = i & 511;
    u16 out = 0;
    if (k < 24) {
        out = (u16)f2bfb(W[(k % 12) * 512 + n]);
    } else if (k < 36) {
        float w = W[(k - 24) * 512 + n];
        u16 h = (u16)f2bfb(w);
        out = (u16)f2bfb(w - bfb2f((u32)h));
    }
    pk[((((k >> 3) << 9) + n) << 3) + (k & 7)] = out;
}

// ---------------- CSR build ----------------
__global__ void k_hist(const int* __restrict__ senders, int* __restrict__ counts) {
    int e = blockIdx.x * 256 + threadIdx.x;
    if (e < E_NUM) atomicAdd(&counts[senders[e]], 1);
}

__global__ __launch_bounds__(1024) void k_scan(const int* __restrict__ counts,
                                               int* __restrict__ rowstart) {
    __shared__ int part[1024];
    int t = threadIdx.x;
    int base = t * 10;
    int local[10];
    int sum = 0;
    #pragma unroll
    for (int i = 0; i < 10; i++) {
        int v = (base + i < NN) ? counts[base + i] : 0;
        local[i] = sum; sum += v;
    }
    part[t] = sum;
    __syncthreads();
    for (int off = 1; off < 1024; off <<= 1) {
        int v = (t >= off) ? part[t - off] : 0;
        __syncthreads();
        part[t] += v;
        __syncthreads();
    }
    int pre = (t == 0) ? 0 : part[t - 1];
    #pragma unroll
    for (int i = 0; i < 10; i++)
        if (base + i < NN) rowstart[base + i] = pre + local[i];
    if (t == 1023) rowstart[NN] = part[1023];
}

__global__ void k_copy_int(const int* __restrict__ src, int* __restrict__ dst, int n) {
    int i = blockIdx.x * 256 + threadIdx.x;
    if (i < n) dst[i] = src[i];
}

__global__ void k_fill(const int* __restrict__ senders, int* __restrict__ cursor,
                       int* __restrict__ edge_list) {
    int e = blockIdx.x * 256 + threadIdx.x;
    if (e >= E_NUM) return;
    int pos = atomicAdd(&cursor[senders[e]], 1);
    edge_list[pos] = e;
}

// ---------------- geometry in SORTED edge space ----------------
__global__ void k_geom(const float* __restrict__ posf, const int* __restrict__ species,
                       const int* __restrict__ senders, const int* __restrict__ receivers,
                       const int* __restrict__ edge_list,
                       int* __restrict__ ssend, int* __restrict__ srecv,
                       float* __restrict__ ux, float* __restrict__ uy, float* __restrict__ uz,
                       float* __restrict__ envb, u32* __restrict__ latin) {
    int e = blockIdx.x * 256 + threadIdx.x;
    if (e >= E_NUM) return;
    int orig = edge_list[e];
    int s = senders[orig], r = receivers[orig];
    ssend[e] = s; srecv[e] = r;
    float rx = posf[3 * r + 0] - posf[3 * s + 0];
    float ry = posf[3 * r + 1] - posf[3 * s + 1];
    float rz = posf[3 * r + 2] - posf[3 * s + 2];
    float d = sqrtf(rx * rx + ry * ry + rz * rz);
    float inv = 1.0f / fmaxf(d, 1e-6f);
    ux[e] = rx * inv; uy[e] = ry * inv; uz[e] = rz * inv;
    float xc = d * 0.5f;
    float env = 0.0f;
    if (xc < 1.0f) { float t = 1.0f - xc * xc; env = t * t; }
    envb[e] = env;
    float ft[12];
    float se = env * inv;
    #pragma unroll
    for (int n = 1; n <= 8; n++) ft[n - 1] = __sinf((float)n * PI_F * xc) * se;
    int ss = species[s], sr = species[r];
    ft[8] = (ss == 0) ? 1.0f : 0.0f;
    ft[9] = (ss == 1) ? 1.0f : 0.0f;
    ft[10] = (sr == 0) ? 1.0f : 0.0f;
    ft[11] = (sr == 1) ? 1.0f : 0.0f;
    u32 fh[12]; float fl[12];
    #pragma unroll
    for (int i = 0; i < 12; i++) {
        fh[i] = f2bfb(ft[i]);
        fl[i] = ft[i] - bfb2f(fh[i]);
    }
    #pragma unroll
    for (int j = 0; j < 6; j++) {
        u32 v = fh[2 * j] | (fh[2 * j + 1] << 16);
        latin[(size_t)j * E_NUM + e] = v;
        latin[(size_t)(12 + j) * E_NUM + e] = v;
        latin[(size_t)(6 + j) * E_NUM + e] = pack2(fl[2 * j], fl[2 * j + 1]);
    }
}

// ---------------- w_e = x @ W_env, edge-major fp32 [E,64] (layer 1 only) ----------------
__global__ __launch_bounds__(256) void k_we(const u16* __restrict__ x,
                                            const float* __restrict__ Wenv,
                                            float* __restrict__ we) {
    __shared__ float lds[256 * 33];
    int t = threadIdx.x;
    int e = blockIdx.x * 256 + t;
    float acc[64];
    #pragma unroll
    for (int c = 0; c < 64; c++) acc[c] = 0.0f;
    for (int k = 0; k < 64; k++) {
        float v = bfb2f((u32)x[(size_t)k * E_NUM + e]);
        const float* wr = Wenv + k * 64;
        #pragma unroll
        for (int c = 0; c < 64; c++) acc[c] = fmaf(v, wr[c], acc[c]);
    }
    float* dstb = we + (size_t)blockIdx.x * 256 * 64;
    for (int half = 0; half < 2; half++) {
        if (half) __syncthreads();
        #pragma unroll
        for (int c = 0; c < 32; c++) lds[t * 33 + c] = acc[half * 32 + c];
        __syncthreads();
        float* dst = dstb + half * 32;
        #pragma unroll
        for (int k = 0; k < 32; k++) {
            int g = k * 256 + t;
            int el = g >> 5, c = g & 31;
            dst[(size_t)el * 64 + c] = lds[el * 33 + c];
        }
    }
}

// ---------------- rho gather ----------------
__global__ __launch_bounds__(256) void k_rho_gather(
    const float* __restrict__ we, const int* __restrict__ rowstart,
    const float* __restrict__ ux, const float* __restrict__ uy,
    const float* __restrict__ uz,
    float* __restrict__ rho0, float* __restrict__ rho1) {
    int wv = (blockIdx.x * 256 + threadIdx.x) >> 6;
    int c = threadIdx.x & 63;
    if (wv >= NN) return;
    int start = rowstart[wv], end = rowstart[wv + 1];
    float s0 = 0.0f, sx = 0.0f, sy = 0.0f, sz = 0.0f;
    for (int j = start; j < end; j++) {
        float w = we[(size_t)j * 64 + c];
        float a = ux[j], b = uy[j], g = uz[j];
        s0 += w;
        sx = fmaf(w, a, sx);
        sy = fmaf(w, b, sy);
        sz = fmaf(w, g, sz);
    }
    const float inv3 = 1.0f / 3.0f;
    rho0[(size_t)wv * 64 + c] = s0 * inv3;
    rho1[(size_t)wv * 192 + 3 * c + 0] = sx * inv3;
    rho1[(size_t)wv * 192 + 3 * c + 1] = sy * inv3;
    rho1[(size_t)wv * 192 + 3 * c + 2] = sz * inv3;
}

// ---------------- stage layer 0 ----------------
__global__ __launch_bounds__(512) void k_stage_l0(
    const float* __restrict__ Wv,
    const float* __restrict__ rho0A, const float* __restrict__ rho1A,
    const int* __restrict__ ssend,
    const float* __restrict__ ux, const float* __restrict__ uy,
    const float* __restrict__ uz,
    const u16* __restrict__ x0, u32* __restrict__ latin) {
    __shared__ u32 in2[32 * 64];
    int lane = threadIdx.x & 63;
    int sub = threadIdx.x >> 6;
    int subu = __builtin_amdgcn_readfirstlane(sub);
    int e = blockIdx.x * 64 + lane;
    int s = ssend[e];
    const float* r1 = rho1A + (size_t)s * 192;
    const float* r0 = rho0A + (size_t)s * 64;

    #pragma unroll
    for (int j = 0; j < 4; j++) {
        int rr = subu * 4 + j;
        u32 v = (u32)x0[(size_t)(2 * rr) * E_NUM + e] |
                ((u32)x0[(size_t)(2 * rr + 1) * E_NUM + e] << 16);
        in2[rr * 64 + lane] = v;
        latin[(size_t)rr * E_NUM + e] = v;
    }
    __syncthreads();

    int c0 = subu * 8;
    float a[8] = {0, 0, 0, 0, 0, 0, 0, 0};
    for (int k2 = 0; k2 < 32; k2++) {
        u32 p = in2[k2 * 64 + lane];
        float v0 = bfb2f(p & 0xffffu), v1 = bfb2f(p >> 16);
        const float* wv0 = Wv + (2 * k2) * 64 + c0;
        const float* wv1 = wv0 + 64;
        #pragma unroll
        for (int i = 0; i < 8; i++) a[i] = fmaf(v0, wv0[i], a[i]);
        #pragma unroll
        for (int i = 0; i < 8; i++) a[i] = fmaf(v1, wv1[i], a[i]);
    }
    float u0 = ux[e], u1 = uy[e], u2 = uz[e];
    float ts[8];
    #pragma unroll
    for (int i = 0; i < 8; i++) {
        int c = c0 + i;
        float dot = u0 * r1[3 * c] + u1 * r1[3 * c + 1] + u2 * r1[3 * c + 2];
        ts[i] = a[i] * dot;
    }
    #pragma unroll
    for (int j = 0; j < 4; j++) {
        latin[(size_t)(32 + subu * 4 + j) * E_NUM + e] = pack2(ts[2 * j], ts[2 * j + 1]);
    }
    #pragma unroll
    for (int j = 0; j < 4; j++) {
        int ch = 2 * (subu * 4 + j);
        latin[(size_t)(64 + subu * 4 + j) * E_NUM + e] = pack2(r0[ch], r0[ch + 1]);
    }
}

// ---------------- stage layer 1 ----------------
__global__ __launch_bounds__(512) void k_stage_l1(
    const float* __restrict__ Wv, const float* __restrict__ Wmix0,
    const float* __restrict__ rho0A, const float* __restrict__ rho1A,
    const float* __restrict__ rho0B, const float* __restrict__ rho1B,
    const int* __restrict__ ssend,
    const float* __restrict__ ux, const float* __restrict__ uy,
    const float* __restrict__ uz,
    const u16* __restrict__ x0, const u16* __restrict__ x1,
    u32* __restrict__ latin) {
    __shared__ u32 in2[32 * 64];
    __shared__ u32 xt0[32 * 64];
    int lane = threadIdx.x & 63;
    int sub = threadIdx.x >> 6;
    int subu = __builtin_amdgcn_readfirstlane(sub);
    int e = blockIdx.x * 64 + lane;
    int s = ssend[e];

    #pragma unroll
    for (int j = 0; j < 4; j++) {
        int rr = subu * 4 + j;
        u32 v = (u32)x1[(size_t)(2 * rr) * E_NUM + e] |
                ((u32)x1[(size_t)(2 * rr + 1) * E_NUM + e] << 16);
        in2[rr * 64 + lane] = v;
        latin[(size_t)rr * E_NUM + e] = v;
        u32 v0 = (u32)x0[(size_t)(2 * rr) * E_NUM + e] |
                 ((u32)x0[(size_t)(2 * rr + 1) * E_NUM + e] << 16);
        xt0[rr * 64 + lane] = v0;
    }
    __syncthreads();

    int c0 = subu * 8;
    float a[8] = {0, 0, 0, 0, 0, 0, 0, 0};
    float m1[8] = {0, 0, 0, 0, 0, 0, 0, 0};
    float m2[8] = {0, 0, 0, 0, 0, 0, 0, 0};
    for (int k2 = 0; k2 < 32; k2++) {
        u32 p0 = xt0[k2 * 64 + lane];
        float a0 = bfb2f(p0 & 0xffffu), a1 = bfb2f(p0 >> 16);
        const float* wv0 = Wv + (2 * k2) * 64 + c0;
        const float* wv1 = wv0 + 64;
        #pragma unroll
        for (int i = 0; i < 8; i++) a[i] = fmaf(a0, wv0[i], a[i]);
        #pragma unroll
        for (int i = 0; i < 8; i++) a[i] = fmaf(a1, wv1[i], a[i]);
        u32 p1 = in2[k2 * 64 + lane];
        float b0 = bfb2f(p1 & 0xffffu), b1 = bfb2f(p1 >> 16);
        const float* wm0 = Wmix0 + (2 * k2) * 128 + c0;
        const float* wm1 = wm0 + 128;
        #pragma unroll
        for (int i = 0; i < 8; i++) {
            m1[i] = fmaf(b0, wm0[i], m1[i]);
            m2[i] = fmaf(b0, wm0[64 + i], m2[i]);
            m1[i] = fmaf(b1, wm1[i], m1[i]);
            m2[i] = fmaf(b1, wm1[64 + i], m2[i]);
        }
    }
    float u0 = ux[e], u1 = uy[e], u2 = uz[e];
    const float* r1A = rho1A + (size_t)s * 192;
    const float* r0A = rho0A + (size_t)s * 64;
    const float* r1B = rho1B + (size_t)s * 192;
    const float* r0B = rho0B + (size_t)s * 64;
    float ts[8];
    #pragma unroll
    for (int i = 0; i < 8; i++) {
        int c = c0 + i;
        float v0 = a[i] * u0, v1 = a[i] * u1, v2 = a[i] * u2;
        float aA0 = r1A[3 * c], aA1 = r1A[3 * c + 1], aA2 = r1A[3 * c + 2];
        float rc = r0A[c];
        float w0 = m1[i] * v0 * rc + m2[i] * (v1 * aA2 - v2 * aA1);
        float w1 = m1[i] * v1 * rc + m2[i] * (v2 * aA0 - v0 * aA2);
        float w2 = m1[i] * v2 * rc + m2[i] * (v0 * aA1 - v1 * aA0);
        ts[i] = w0 * r1B[3 * c] + w1 * r1B[3 * c + 1] + w2 * r1B[3 * c + 2];
    }
    #pragma unroll
    for (int j = 0; j < 4; j++) {
        latin[(size_t)(32 + subu * 4 + j) * E_NUM + e] = pack2(ts[2 * j], ts[2 * j + 1]);
    }
    #pragma unroll
    for (int j = 0; j < 4; j++) {
        int ch = 2 * (subu * 4 + j);
        latin[(size_t)(64 + subu * 4 + j) * E_NUM + e] = pack2(r0B[ch], r0B[ch + 1]);
    }
}

// =====================================================================
// MFMA MLP v5.1: 32x32x16 shape, LDS sizing fixed (hA = 32 KB, not 64).
// lat blob = 56 KB -> 2 blocks/CU; emb = 40 KB.
// =====================================================================
template<int KSTEPS, int MODE, int HASLO, int FUSEWE>
__global__ __launch_bounds__(512) void k_mlp(
    const u32* __restrict__ latin,
    const u16* __restrict__ W1hi, const u16* __restrict__ W1lo,
    const u16* __restrict__ W2hi, const u16* __restrict__ W2lo,
    const float* __restrict__ envb,
    const u16* __restrict__ xprev,
    u16* __restrict__ xout,
    const u16* __restrict__ wehi, const u16* __restrict__ welo,
    float* __restrict__ webuf) {
    constexpr int INA_DW = KSTEPS * 16;          // dwords per inA row
    __shared__ __align__(16) char smem[KSTEPS * 4096 + 32768];
    u32* inA = (u32*)smem;                        // 64 rows x INA_DW
    u16* hA = (u16*)(smem + KSTEPS * 4096);       // 64 rows x 256 cols = 32 KB
    float* epi = (float*)smem;                    // 64 x 65 fp32 (epilogue overlay)
    int lane = threadIdx.x & 63;
    int sub = threadIdx.x >> 6;
    int w = __builtin_amdgcn_readfirstlane(sub);
    int l31 = lane & 31, khi = lane >> 5;
    int e0 = blockIdx.x * 64;
    int e = e0 + lane;

    // ---- stage lat_in ----
    constexpr int NCH = KSTEPS * 4;
    constexpr int CPW = NCH / 8;
    #pragma unroll
    for (int j = 0; j < CPW; j++) {
        int c = w * CPW + j;
        u32x4 v;
        #pragma unroll
        for (int i = 0; i < 4; i++) v[i] = latin[(size_t)(c * 4 + i) * E_NUM + e];
        int slot = (c & ~7) | ((c ^ lane) & 7);
        *(u32x4*)(&inA[lane * INA_DW + slot * 4]) = v;
    }
    __syncthreads();

    // phase-2 wave assignment
    int mt2 = w & 1, nt2 = (w >> 1) & 1, kq = w >> 2;
    f32x16 acc2;
    #pragma unroll
    for (int i = 0; i < 16; i++) acc2[i] = 0.0f;

    constexpr int KS16 = KSTEPS * 2;   // number of K=16 steps in phase 1

    #pragma unroll
    for (int hh = 0; hh < 2; hh++) {
        // ---- phase 1: n-tile = w (cols hh*256 + w*32 .. +32), all 64 rows ----
        f32x16 acc1[2];
        #pragma unroll
        for (int mt = 0; mt < 2; mt++)
            #pragma unroll
            for (int i = 0; i < 16; i++) acc1[mt][i] = 0.0f;
        int n1 = hh * 256 + w * 32 + l31;
        #pragma unroll
        for (int ks = 0; ks < KS16; ks++) {
            int c = ks * 2 + khi;
            bf16x8 afr[2];
            #pragma unroll
            for (int mt = 0; mt < 2; mt++) {
                int row = mt * 32 + l31;
                int slot = (c & ~7) | ((c ^ row) & 7);
                afr[mt] = *(const bf16x8*)(&inA[row * INA_DW + slot * 4]);
            }
            size_t bidx = (((size_t)c << 9) + n1) << 3;
            bf16x8 bh = *(const bf16x8*)(W1hi + bidx);
            acc1[0] = __builtin_amdgcn_mfma_f32_32x32x16_bf16(afr[0], bh, acc1[0], 0, 0, 0);
            acc1[1] = __builtin_amdgcn_mfma_f32_32x32x16_bf16(afr[1], bh, acc1[1], 0, 0, 0);
            if (HASLO) {
                bf16x8 bl = *(const bf16x8*)(W1lo + bidx);
                acc1[0] = __builtin_amdgcn_mfma_f32_32x32x16_bf16(afr[0], bl, acc1[0], 0, 0, 0);
                acc1[1] = __builtin_amdgcn_mfma_f32_32x32x16_bf16(afr[1], bl, acc1[1], 0, 0, 0);
            }
        }
        __syncthreads();   // prior half's hA reads done
        // hA write: col kh = w*32 + l31, m = mt*32 + (reg&3)+8*(reg>>2)+4*khi
        {
            int kh = w * 32 + l31;
            int c2 = kh >> 3;
            #pragma unroll
            for (int mt = 0; mt < 2; mt++) {
                #pragma unroll
                for (int reg = 0; reg < 16; reg++) {
                    int m = mt * 32 + (reg & 3) + 8 * (reg >> 2) + 4 * khi;
                    int slot = (c2 & 24) | ((c2 ^ m) & 7);
                    hA[m * 256 + slot * 8 + (kh & 7)] = (u16)f2bfb(silu_fast(acc1[mt][reg]));
                }
            }
        }
        __syncthreads();
        // ---- phase 2 partial: this half's 256 K-cols, wave's quarter (128) ----
        #pragma unroll
        for (int ks = 0; ks < 8; ks++) {
            int cl = kq * 16 + ks * 2 + khi;
            int row = mt2 * 32 + l31;
            int slot = (cl & 24) | ((cl ^ row) & 7);
            bf16x8 a = *(const bf16x8*)(&hA[row * 256 + slot * 8]);
            int kc2 = hh * 32 + cl;
            int n2 = nt2 * 32 + l31;
            size_t bidx = (((size_t)kc2 << 6) + n2) << 3;
            bf16x8 bh = *(const bf16x8*)(W2hi + bidx);
            acc2 = __builtin_amdgcn_mfma_f32_32x32x16_bf16(a, bh, acc2, 0, 0, 0);
            bf16x8 bl = *(const bf16x8*)(W2lo + bidx);
            acc2 = __builtin_amdgcn_mfma_f32_32x32x16_bf16(a, bl, acc2, 0, 0, 0);
        }
    }
    __syncthreads();   // all inA/hA use done; epi overlays
    // reduce K-partials: kq=0 writes, kq=1 adds
    if (kq == 0) {
        #pragma unroll
        for (int reg = 0; reg < 16; reg++) {
            int m = mt2 * 32 + (reg & 3) + 8 * (reg >> 2) + 4 * khi;
            int cc = nt2 * 32 + l31;
            epi[cc * 65 + m] = acc2[reg];
        }
    }
    __syncthreads();
    if (kq == 1) {
        #pragma unroll
        for (int reg = 0; reg < 16; reg++) {
            int m = mt2 * 32 + (reg & 3) + 8 * (reg >> 2) + 4 * khi;
            int cc = nt2 * 32 + l31;
            epi[cc * 65 + m] += acc2[reg];
        }
    }
    __syncthreads();
    float env = envb[e];
    const float is2 = 0.70710678118654752f;
    #pragma unroll
    for (int i = 0; i < 8; i++) {
        int cc = w * 8 + i;
        float v = epi[cc * 65 + lane];
        float res;
        if (MODE) res = (bfb2f((u32)xprev[(size_t)cc * E_NUM + e]) + v * env) * is2;
        else      res = v * env;
        xout[(size_t)cc * E_NUM + e] = (u16)f2bfb(res);
        if (FUSEWE) epi[cc * 65 + lane] = res;   // overwrite with final value
    }
    if (FUSEWE) {
        __syncthreads();
        if (w < 4) {
            int mtw = w & 1, ntw = w >> 1;
            f32x16 accw;
            #pragma unroll
            for (int i = 0; i < 16; i++) accw[i] = 0.0f;
            #pragma unroll
            for (int ks = 0; ks < 4; ks++) {
                int c4 = ks * 2 + khi;
                int row = mtw * 32 + l31;
                bf16x8 af;
                #pragma unroll
                for (int j = 0; j < 8; j++)
                    af[j] = (short)f2bfb(epi[(c4 * 8 + j) * 65 + row]);
                int n4 = ntw * 32 + l31;
                size_t bidx = (((size_t)c4 << 6) + n4) << 3;
                bf16x8 bh = *(const bf16x8*)(wehi + bidx);
                accw = __builtin_amdgcn_mfma_f32_32x32x16_bf16(af, bh, accw, 0, 0, 0);
                bf16x8 bl = *(const bf16x8*)(welo + bidx);
                accw = __builtin_amdgcn_mfma_f32_32x32x16_bf16(af, bl, accw, 0, 0, 0);
            }
            #pragma unroll
            for (int reg = 0; reg < 16; reg++) {
                int rowD = mtw * 32 + (reg & 3) + 8 * (reg >> 2) + 4 * khi;
                int colD = ntw * 32 + l31;
                webuf[(size_t)(e0 + rowD) * 64 + colD] = accw[reg];
            }
        }
    }
}

// ---------------- readout ----------------
__global__ void k_readout(const u16* __restrict__ x, const float* __restrict__ Wout,
                          const float* __restrict__ envb, const int* __restrict__ srecv,
                          float* __restrict__ node_acc) {
    int e = blockIdx.x * 256 + threadIdx.x;
    if (e >= E_NUM) return;
    float a = 0.0f;
    #pragma unroll
    for (int c = 0; c < 64; c++) {
        a = fmaf(bfb2f((u32)x[(size_t)c * E_NUM + e]), Wout[c], a);
    }
    a *= envb[e] * (1.0f / 3.0f);
    atomicAdd(&node_acc[srecv[e]], a);
}

__global__ void k_out(const float* __restrict__ node_acc, void* __restrict__ out,
                      const int* __restrict__ flag) {
    int n = blockIdx.x * 256 + threadIdx.x;
    if (n >= NN) return;
    float v = node_acc[n];
    if (*flag) ((float*)out)[n] = v;
    else       ((u16*)out)[n] = (u16)f2bfb(v);
}

extern "C" void kernel_launch(void* const* d_in, const int* in_sizes, int n_in,
                              void* d_out, int out_size, void* d_ws, size_t ws_size,
                              hipStream_t stream) {
    const void* posr   = d_in[0];
    const void* Wemb1r = d_in[1];
    const void* Wemb2r = d_in[2];
    const void* Wvr    = d_in[3];
    const void* Wenvr  = d_in[4];
    const void* Wlat1r = d_in[5];
    const void* Wlat2r = d_in[6];
    const void* Wmixr  = d_in[7];
    const void* Woutr  = d_in[8];
    const int* species   = (const int*)d_in[9];
    const int* senders   = (const int*)d_in[10];
    const int* receivers = (const int*)d_in[11];

    char* p = (char*)d_ws;
    auto alloc = [&](size_t bytes) -> void* {
        void* rp = (void*)p;
        p += (bytes + 255) & ~(size_t)255;
        return rp;
    };
    int*   flag  = (int*)alloc(4);
    float* wbuf  = (float*)alloc(359792 * 4);
    float* posf  = wbuf;
    float* Wemb1 = wbuf + 30000;
    float* Wemb2 = wbuf + 36144;
    float* Wv    = wbuf + 68912;
    float* Wenv  = wbuf + 73008;
    float* Wlat1 = wbuf + 81200;
    float* Wlat2 = wbuf + 277808;
    float* Wmix  = wbuf + 343344;
    float* Wout  = wbuf + 359728;
    const size_t E = E_NUM;
    float* ux   = (float*)alloc(E * 4);
    float* uy   = (float*)alloc(E * 4);
    float* uz   = (float*)alloc(E * 4);
    float* envb = (float*)alloc(E * 4);
    float* rho0A = (float*)alloc((size_t)NN * 64 * 4);
    float* rho1A = (float*)alloc((size_t)NN * 192 * 4);
    float* rho0B = (float*)alloc((size_t)NN * 64 * 4);
    float* rho1B = (float*)alloc((size_t)NN * 192 * 4);
    float* node_acc = (float*)alloc((size_t)NN * 4);
    int* counts    = (int*)alloc((size_t)NN * 4);
    int* rowstart  = (int*)alloc((size_t)(NN + 1) * 4);
    int* cursor    = (int*)alloc((size_t)NN * 4);
    int* edge_list = (int*)alloc(E * 4);
    int* ssend     = (int*)alloc(E * 4);
    int* srecv     = (int*)alloc(E * 4);
    void* unionbuf = alloc(96 * E * 4);
    u32*   latin = (u32*)unionbuf;
    float* webuf = (float*)unionbuf;                       // layer-1 we (base)
    float* we0   = (float*)unionbuf + (size_t)32 * E;      // layer-0 we (rows 32..95)
    u16* x0 = (u16*)alloc(64 * E * 2);
    u16* x1 = (u16*)alloc(64 * E * 2);
    u16* w1hi = (u16*)alloc(2 * 98304 * 2);
    u16* w1lo = (u16*)alloc(2 * 98304 * 2);
    u16* w2hi = (u16*)alloc(2 * 32768 * 2);
    u16* w2lo = (u16*)alloc(2 * 32768 * 2);
    u16* e1hi = (u16*)alloc(32768 * 2);
    u16* e2hi = (u16*)alloc(32768 * 2);
    u16* e2lo = (u16*)alloc(32768 * 2);
    u16* wvhi = (u16*)alloc(4096 * 2);
    u16* wvlo = (u16*)alloc(4096 * 2);

    hipMemsetAsync(flag, 0, 4, stream);
    hipMemsetAsync(counts, 0, (size_t)NN * 4, stream);
    hipMemsetAsync(node_acc, 0, (size_t)NN * 4, stream);
    hipMemsetAsync(latin + (size_t)18 * E, 0, (size_t)14 * E * 4, stream);

    k_detect<<<(15000 + 255) / 256, 256, 0, stream>>>((const u16*)posr, flag);

    k_cvt_all<<<(359792 + 255) / 256, 256, 0, stream>>>(
        posr, Wemb1r, Wemb2r, Wvr, Wenvr, Wlat1r, Wlat2r, Wmixr, Woutr,
        wbuf, flag);

    k_pack_emb1<<<128, 256, 0, stream>>>(Wemb1, e1hi);
    k_pack<<<128, 256, 0, stream>>>(Wemb2, 512, 6, e2hi, e2lo);
    k_pack<<<16, 256, 0, stream>>>(Wenv, 64, 6, wvhi, wvlo);
    for (int l = 0; l < 2; l++) {
        k_pack<<<384, 256, 0, stream>>>(Wlat1 + l * 98304, 192, 9,
                                        w1hi + l * 98304, w1lo + l * 98304);
        k_pack<<<128, 256, 0, stream>>>(Wlat2 + l * 32768, 512, 6,
                                        w2hi + l * 32768, w2lo + l * 32768);
    }

    // CSR over senders -> sorted edge order
    k_hist<<<625, 256, 0, stream>>>(senders, counts);
    k_scan<<<1, 1024, 0, stream>>>(counts, rowstart);
    k_copy_int<<<(NN + 255) / 256, 256, 0, stream>>>(rowstart, cursor, NN);
    k_fill<<<625, 256, 0, stream>>>(senders, cursor, edge_list);

    // embedding (sorted edge space) + fused layer-0 we
    k_geom<<<625, 256, 0, stream>>>(posf, species, senders, receivers, edge_list,
                                    ssend, srecv, ux, uy, uz, envb, latin);
    k_mlp<2, 0, 0, 1><<<2500, 512, 0, stream>>>(latin, e1hi, nullptr, e2hi, e2lo,
                                                envb, nullptr, x0, wvhi, wvlo, we0);

    // layer 0
    k_rho_gather<<<2500, 256, 0, stream>>>(we0, rowstart, ux, uy, uz,
                                           rho0A, rho1A);
    k_stage_l0<<<2500, 512, 0, stream>>>(Wv, rho0A, rho1A, ssend, ux, uy, uz,
                                         x0, latin);
    k_mlp<6, 1, 1, 0><<<2500, 512, 0, stream>>>(latin, w1hi, w1lo, w2hi, w2lo,
                                                envb, x0, x1, nullptr, nullptr, nullptr);

    // layer 1
    k_we<<<625, 256, 0, stream>>>(x1, Wenv + 4096, webuf);
    k_rho_gather<<<2500, 256, 0, stream>>>(webuf, rowstart, ux, uy, uz,
                                           rho0B, rho1B);
    k_stage_l1<<<2500, 512, 0, stream>>>(Wv, Wmix, rho0A, rho1A, rho0B, rho1B,
                                         ssend, ux, uy, uz, x0, x1, latin);
    k_mlp<6, 1, 1, 0><<<2500, 512, 0, stream>>>(latin, w1hi + 98304, w1lo + 98304,
                                                w2hi + 32768, w2lo + 32768,
                                                envb, x1, x1, nullptr, nullptr, nullptr);

    k_readout<<<625, 256, 0, stream>>>(x1, Wout, envb, srecv, node_acc);
    k_out<<<(NN + 255) / 256, 256, 0, stream>>>(node_acc, d_out, flag);
}

// Round 14
// 603.174 us; speedup vs baseline: 1.1013x; 1.0589x over previous
//
#include <hip/hip_runtime.h>
#include <hip/hip_bf16.h>

#define E_NUM 160000
#define NN 10000
#define PI_F 3.14159265358979323846f

using u16 = unsigned short;
using u32 = unsigned int;
typedef short bf16x8 __attribute__((ext_vector_type(8)));
typedef float f32x4 __attribute__((ext_vector_type(4)));
typedef u32 u32x4 __attribute__((ext_vector_type(4)));

__device__ __forceinline__ float silu_fast(float z) {
    return z * __builtin_amdgcn_rcpf(1.0f + __expf(-z));
}
__device__ __forceinline__ float bfb2f(u32 bits16) {
    return __builtin_bit_cast(float, bits16 << 16);
}
__device__ __forceinline__ u32 f2bfb(float f) {
    return (u32)__builtin_bit_cast(u16, __float2bfloat16(f));
}
__device__ __forceinline__ u32 pack2(float lo, float hi) {
    return f2bfb(lo) | (f2bfb(hi) << 16);
}

// ---------------- dtype detection (inputs fp32 vs bf16) ----------------
__global__ void k_detect(const u16* __restrict__ posraw, int* __restrict__ flag) {
    int i = blockIdx.x * 256 + threadIdx.x;
    if (i >= 15000) return;
    float v = bfb2f((u32)posraw[2 * i]);
    if (!(fabsf(v) < 1e4f)) atomicOr(flag, 1);
}

// ---------------- fused dual-dtype ingest of all 9 fp tensors ----------------
__global__ void k_cvt_all(const void* s0, const void* s1, const void* s2,
                          const void* s3, const void* s4, const void* s5,
                          const void* s6, const void* s7, const void* s8,
                          float* __restrict__ dst, const int* __restrict__ flag) {
    int i = blockIdx.x * 256 + threadIdx.x;
    if (i >= 359792) return;
    const void* src; int off;
    if      (i < 30000)  { src = s0; off = i; }
    else if (i < 36144)  { src = s1; off = i - 30000; }
    else if (i < 68912)  { src = s2; off = i - 36144; }
    else if (i < 73008)  { src = s3; off = i - 68912; }
    else if (i < 81200)  { src = s4; off = i - 73008; }
    else if (i < 277808) { src = s5; off = i - 81200; }
    else if (i < 343344) { src = s6; off = i - 277808; }
    else if (i < 359728) { src = s7; off = i - 343344; }
    else                 { src = s8; off = i - 359728; }
    if (*flag) dst[i] = ((const float*)src)[off];
    else       dst[i] = bfb2f((u32)((const u16*)src)[off]);
}

// ---------------- weight packers: [K][N] fp32 -> B-frag layout hi/lo ----------------
__global__ void k_pack(const float* __restrict__ W, int K, int Nshift,
                       u16* __restrict__ hi, u16* __restrict__ lo) {
    int i = blockIdx.x * 256 + threadIdx.x;
    int total = K << Nshift;
    if (i >= total) return;
    int k = i >> Nshift, n = i & ((1 << Nshift) - 1);
    float w = W[i];
    u16 h = (u16)f2bfb(w);
    float r = w - bfb2f((u32)h);
    int idx = ((((k >> 3) << Nshift) + n) << 3) + (k & 7);
    hi[idx] = h; lo[idx] = (u16)f2bfb(r);
}

// emb W1: rows 0..11 = hi(W), 12..23 = hi(W), 24..35 = lo(W), 36..63 = 0
__global__ void k_pack_emb1(const float* __restrict__ W /*12x512*/, u16* __restrict__ pk) {
    int i = blockIdx.x * 256 + threadIdx.x;
    if (i >= 64 * 512) return;
    int k = i >> 9, n = i & 511;
    u16 out = 0;
    if (k < 24) {
        out = (u16)f2bfb(W[(k % 12) * 512 + n]);
    } else if (k < 36) {
        float w = W[(k - 24) * 512 + n];
        u16 h = (u16)f2bfb(w);
        out = (u16)f2bfb(w - bfb2f((u32)h));
    }
    pk[((((k >> 3) << 9) + n) << 3) + (k & 7)] = out;
}

// ---------------- CSR build ----------------
__global__ void k_hist(const int* __restrict__ senders, int* __restrict__ counts) {
    int e = blockIdx.x * 256 + threadIdx.x;
    if (e < E_NUM) atomicAdd(&counts[senders[e]], 1);
}

__global__ __launch_bounds__(1024) void k_scan(const int* __restrict__ counts,
                                               int* __restrict__ rowstart) {
    __shared__ int part[1024];
    int t = threadIdx.x;
    int base = t * 10;
    int local[10];
    int sum = 0;
    #pragma unroll
    for (int i = 0; i < 10; i++) {
        int v = (base + i < NN) ? counts[base + i] : 0;
        local[i] = sum; sum += v;
    }
    part[t] = sum;
    __syncthreads();
    for (int off = 1; off < 1024; off <<= 1) {
        int v = (t >= off) ? part[t - off] : 0;
        __syncthreads();
        part[t] += v;
        __syncthreads();
    }
    int pre = (t == 0) ? 0 : part[t - 1];
    #pragma unroll
    for (int i = 0; i < 10; i++)
        if (base + i < NN) rowstart[base + i] = pre + local[i];
    if (t == 1023) rowstart[NN] = part[1023];
}

__global__ void k_copy_int(const int* __restrict__ src, int* __restrict__ dst, int n) {
    int i = blockIdx.x * 256 + threadIdx.x;
    if (i < n) dst[i] = src[i];
}

__global__ void k_fill(const int* __restrict__ senders, int* __restrict__ cursor,
                       int* __restrict__ edge_list) {
    int e = blockIdx.x * 256 + threadIdx.x;
    if (e >= E_NUM) return;
    int pos = atomicAdd(&cursor[senders[e]], 1);
    edge_list[pos] = e;
}

// ---------------- geometry in SORTED edge space ----------------
__global__ void k_geom(const float* __restrict__ posf, const int* __restrict__ species,
                       const int* __restrict__ senders, const int* __restrict__ receivers,
                       const int* __restrict__ edge_list,
                       int* __restrict__ ssend, int* __restrict__ srecv,
                       float* __restrict__ ux, float* __restrict__ uy, float* __restrict__ uz,
                       float* __restrict__ envb, u32* __restrict__ latin) {
    int e = blockIdx.x * 256 + threadIdx.x;
    if (e >= E_NUM) return;
    int orig = edge_list[e];
    int s = senders[orig], r = receivers[orig];
    ssend[e] = s; srecv[e] = r;
    float rx = posf[3 * r + 0] - posf[3 * s + 0];
    float ry = posf[3 * r + 1] - posf[3 * s + 1];
    float rz = posf[3 * r + 2] - posf[3 * s + 2];
    float d = sqrtf(rx * rx + ry * ry + rz * rz);
    float inv = 1.0f / fmaxf(d, 1e-6f);
    ux[e] = rx * inv; uy[e] = ry * inv; uz[e] = rz * inv;
    float xc = d * 0.5f;
    float env = 0.0f;
    if (xc < 1.0f) { float t = 1.0f - xc * xc; env = t * t; }
    envb[e] = env;
    float ft[12];
    float se = env * inv;
    #pragma unroll
    for (int n = 1; n <= 8; n++) ft[n - 1] = __sinf((float)n * PI_F * xc) * se;
    int ss = species[s], sr = species[r];
    ft[8] = (ss == 0) ? 1.0f : 0.0f;
    ft[9] = (ss == 1) ? 1.0f : 0.0f;
    ft[10] = (sr == 0) ? 1.0f : 0.0f;
    ft[11] = (sr == 1) ? 1.0f : 0.0f;
    u32 fh[12]; float fl[12];
    #pragma unroll
    for (int i = 0; i < 12; i++) {
        fh[i] = f2bfb(ft[i]);
        fl[i] = ft[i] - bfb2f(fh[i]);
    }
    #pragma unroll
    for (int j = 0; j < 6; j++) {
        u32 v = fh[2 * j] | (fh[2 * j + 1] << 16);
        latin[(size_t)j * E_NUM + e] = v;
        latin[(size_t)(12 + j) * E_NUM + e] = v;
        latin[(size_t)(6 + j) * E_NUM + e] = pack2(fl[2 * j], fl[2 * j + 1]);
    }
}

// ---------------- w_e = x @ W_env, edge-major fp32 [E,64] (layer 1 only) ----------------
__global__ __launch_bounds__(256) void k_we(const u16* __restrict__ x,
                                            const float* __restrict__ Wenv,
                                            float* __restrict__ we) {
    __shared__ float lds[256 * 33];
    int t = threadIdx.x;
    int e = blockIdx.x * 256 + t;
    float acc[64];
    #pragma unroll
    for (int c = 0; c < 64; c++) acc[c] = 0.0f;
    for (int k = 0; k < 64; k++) {
        float v = bfb2f((u32)x[(size_t)k * E_NUM + e]);
        const float* wr = Wenv + k * 64;
        #pragma unroll
        for (int c = 0; c < 64; c++) acc[c] = fmaf(v, wr[c], acc[c]);
    }
    float* dstb = we + (size_t)blockIdx.x * 256 * 64;
    for (int half = 0; half < 2; half++) {
        if (half) __syncthreads();
        #pragma unroll
        for (int c = 0; c < 32; c++) lds[t * 33 + c] = acc[half * 32 + c];
        __syncthreads();
        float* dst = dstb + half * 32;
        #pragma unroll
        for (int k = 0; k < 32; k++) {
            int g = k * 256 + t;
            int el = g >> 5, c = g & 31;
            dst[(size_t)el * 64 + c] = lds[el * 33 + c];
        }
    }
}

// ---------------- rho gather ----------------
__global__ __launch_bounds__(256) void k_rho_gather(
    const float* __restrict__ we, const int* __restrict__ rowstart,
    const float* __restrict__ ux, const float* __restrict__ uy,
    const float* __restrict__ uz,
    float* __restrict__ rho0, float* __restrict__ rho1) {
    int wv = (blockIdx.x * 256 + threadIdx.x) >> 6;
    int c = threadIdx.x & 63;
    if (wv >= NN) return;
    int start = rowstart[wv], end = rowstart[wv + 1];
    float s0 = 0.0f, sx = 0.0f, sy = 0.0f, sz = 0.0f;
    for (int j = start; j < end; j++) {
        float w = we[(size_t)j * 64 + c];
        float a = ux[j], b = uy[j], g = uz[j];
        s0 += w;
        sx = fmaf(w, a, sx);
        sy = fmaf(w, b, sy);
        sz = fmaf(w, g, sz);
    }
    const float inv3 = 1.0f / 3.0f;
    rho0[(size_t)wv * 64 + c] = s0 * inv3;
    rho1[(size_t)wv * 192 + 3 * c + 0] = sx * inv3;
    rho1[(size_t)wv * 192 + 3 * c + 1] = sy * inv3;
    rho1[(size_t)wv * 192 + 3 * c + 2] = sz * inv3;
}

// ---------------- stage layer 0 ----------------
__global__ __launch_bounds__(512) void k_stage_l0(
    const float* __restrict__ Wv,
    const float* __restrict__ rho0A, const float* __restrict__ rho1A,
    const int* __restrict__ ssend,
    const float* __restrict__ ux, const float* __restrict__ uy,
    const float* __restrict__ uz,
    const u16* __restrict__ x0, u32* __restrict__ latin) {
    __shared__ u32 in2[32 * 64];
    int lane = threadIdx.x & 63;
    int sub = threadIdx.x >> 6;
    int subu = __builtin_amdgcn_readfirstlane(sub);
    int e = blockIdx.x * 64 + lane;
    int s = ssend[e];
    const float* r1 = rho1A + (size_t)s * 192;
    const float* r0 = rho0A + (size_t)s * 64;

    #pragma unroll
    for (int j = 0; j < 4; j++) {
        int rr = subu * 4 + j;
        u32 v = (u32)x0[(size_t)(2 * rr) * E_NUM + e] |
                ((u32)x0[(size_t)(2 * rr + 1) * E_NUM + e] << 16);
        in2[rr * 64 + lane] = v;
        latin[(size_t)rr * E_NUM + e] = v;
    }
    __syncthreads();

    int c0 = subu * 8;
    float a[8] = {0, 0, 0, 0, 0, 0, 0, 0};
    for (int k2 = 0; k2 < 32; k2++) {
        u32 p = in2[k2 * 64 + lane];
        float v0 = bfb2f(p & 0xffffu), v1 = bfb2f(p >> 16);
        const float* wv0 = Wv + (2 * k2) * 64 + c0;
        const float* wv1 = wv0 + 64;
        #pragma unroll
        for (int i = 0; i < 8; i++) a[i] = fmaf(v0, wv0[i], a[i]);
        #pragma unroll
        for (int i = 0; i < 8; i++) a[i] = fmaf(v1, wv1[i], a[i]);
    }
    float u0 = ux[e], u1 = uy[e], u2 = uz[e];
    float ts[8];
    #pragma unroll
    for (int i = 0; i < 8; i++) {
        int c = c0 + i;
        float dot = u0 * r1[3 * c] + u1 * r1[3 * c + 1] + u2 * r1[3 * c + 2];
        ts[i] = a[i] * dot;
    }
    #pragma unroll
    for (int j = 0; j < 4; j++) {
        latin[(size_t)(32 + subu * 4 + j) * E_NUM + e] = pack2(ts[2 * j], ts[2 * j + 1]);
    }
    #pragma unroll
    for (int j = 0; j < 4; j++) {
        int ch = 2 * (subu * 4 + j);
        latin[(size_t)(64 + subu * 4 + j) * E_NUM + e] = pack2(r0[ch], r0[ch + 1]);
    }
}

// ---------------- stage layer 1 ----------------
__global__ __launch_bounds__(512) void k_stage_l1(
    const float* __restrict__ Wv, const float* __restrict__ Wmix0,
    const float* __restrict__ rho0A, const float* __restrict__ rho1A,
    const float* __restrict__ rho0B, const float* __restrict__ rho1B,
    const int* __restrict__ ssend,
    const float* __restrict__ ux, const float* __restrict__ uy,
    const float* __restrict__ uz,
    const u16* __restrict__ x0, const u16* __restrict__ x1,
    u32* __restrict__ latin) {
    __shared__ u32 in2[32 * 64];
    __shared__ u32 xt0[32 * 64];
    int lane = threadIdx.x & 63;
    int sub = threadIdx.x >> 6;
    int subu = __builtin_amdgcn_readfirstlane(sub);
    int e = blockIdx.x * 64 + lane;
    int s = ssend[e];

    #pragma unroll
    for (int j = 0; j < 4; j++) {
        int rr = subu * 4 + j;
        u32 v = (u32)x1[(size_t)(2 * rr) * E_NUM + e] |
                ((u32)x1[(size_t)(2 * rr + 1) * E_NUM + e] << 16);
        in2[rr * 64 + lane] = v;
        latin[(size_t)rr * E_NUM + e] = v;
        u32 v0 = (u32)x0[(size_t)(2 * rr) * E_NUM + e] |
                 ((u32)x0[(size_t)(2 * rr + 1) * E_NUM + e] << 16);
        xt0[rr * 64 + lane] = v0;
    }
    __syncthreads();

    int c0 = subu * 8;
    float a[8] = {0, 0, 0, 0, 0, 0, 0, 0};
    float m1[8] = {0, 0, 0, 0, 0, 0, 0, 0};
    float m2[8] = {0, 0, 0, 0, 0, 0, 0, 0};
    for (int k2 = 0; k2 < 32; k2++) {
        u32 p0 = xt0[k2 * 64 + lane];
        float a0 = bfb2f(p0 & 0xffffu), a1 = bfb2f(p0 >> 16);
        const float* wv0 = Wv + (2 * k2) * 64 + c0;
        const float* wv1 = wv0 + 64;
        #pragma unroll
        for (int i = 0; i < 8; i++) a[i] = fmaf(a0, wv0[i], a[i]);
        #pragma unroll
        for (int i = 0; i < 8; i++) a[i] = fmaf(a1, wv1[i], a[i]);
        u32 p1 = in2[k2 * 64 + lane];
        float b0 = bfb2f(p1 & 0xffffu), b1 = bfb2f(p1 >> 16);
        const float* wm0 = Wmix0 + (2 * k2) * 128 + c0;
        const float* wm1 = wm0 + 128;
        #pragma unroll
        for (int i = 0; i < 8; i++) {
            m1[i] = fmaf(b0, wm0[i], m1[i]);
            m2[i] = fmaf(b0, wm0[64 + i], m2[i]);
            m1[i] = fmaf(b1, wm1[i], m1[i]);
            m2[i] = fmaf(b1, wm1[64 + i], m2[i]);
        }
    }
    float u0 = ux[e], u1 = uy[e], u2 = uz[e];
    const float* r1A = rho1A + (size_t)s * 192;
    const float* r0A = rho0A + (size_t)s * 64;
    const float* r1B = rho1B + (size_t)s * 192;
    const float* r0B = rho0B + (size_t)s * 64;
    float ts[8];
    #pragma unroll
    for (int i = 0; i < 8; i++) {
        int c = c0 + i;
        float v0 = a[i] * u0, v1 = a[i] * u1, v2 = a[i] * u2;
        float aA0 = r1A[3 * c], aA1 = r1A[3 * c + 1], aA2 = r1A[3 * c + 2];
        float rc = r0A[c];
        float w0 = m1[i] * v0 * rc + m2[i] * (v1 * aA2 - v2 * aA1);
        float w1 = m1[i] * v1 * rc + m2[i] * (v2 * aA0 - v0 * aA2);
        float w2 = m1[i] * v2 * rc + m2[i] * (v0 * aA1 - v1 * aA0);
        ts[i] = w0 * r1B[3 * c] + w1 * r1B[3 * c + 1] + w2 * r1B[3 * c + 2];
    }
    #pragma unroll
    for (int j = 0; j < 4; j++) {
        latin[(size_t)(32 + subu * 4 + j) * E_NUM + e] = pack2(ts[2 * j], ts[2 * j + 1]);
    }
    #pragma unroll
    for (int j = 0; j < 4; j++) {
        int ch = 2 * (subu * 4 + j);
        latin[(size_t)(64 + subu * 4 + j) * E_NUM + e] = pack2(r0B[ch], r0B[ch + 1]);
    }
}

// =====================================================================
// MFMA MLP v6: round-11's 16x16x32 kernel (best measured: 128 µs, 42%
// occupancy) + fused layer-0 we epilogue (16x16 D-layout mini-GEMM).
// =====================================================================
template<int KSTEPS, int MODE, int HASLO, int FUSEWE>
__global__ __launch_bounds__(512) void k_mlp(
    const u32* __restrict__ latin,
    const u16* __restrict__ W1hi, const u16* __restrict__ W1lo,
    const u16* __restrict__ W2hi, const u16* __restrict__ W2lo,
    const float* __restrict__ envb,
    const u16* __restrict__ xprev,
    u16* __restrict__ xout,
    const u16* __restrict__ wehi, const u16* __restrict__ welo,
    float* __restrict__ webuf) {
    __shared__ __align__(16) u32 inA[64 * 96];   // 24 KB
    __shared__ __align__(16) u16 hA[64 * 128];   // 16 KB
    int lane = threadIdx.x & 63;
    int sub = threadIdx.x >> 6;
    int w = __builtin_amdgcn_readfirstlane(sub);
    int l15 = lane & 15, quad = lane >> 4;
    int e0 = blockIdx.x * 64;
    int e = e0 + lane;

    constexpr int NCH = KSTEPS * 4;
    constexpr int CPW = NCH / 8;
    #pragma unroll
    for (int j = 0; j < CPW; j++) {
        int c = w * CPW + j;
        u32x4 v;
        #pragma unroll
        for (int i = 0; i < 4; i++) v[i] = latin[(size_t)(c * 4 + i) * E_NUM + e];
        int slot = (c & ~7) | ((c ^ lane) & 7);
        *(u32x4*)(&inA[lane * 96 + slot * 4]) = v;
    }
    __syncthreads();

    f32x4 acc2[2];
    acc2[0] = (f32x4){0.f, 0.f, 0.f, 0.f};
    acc2[1] = (f32x4){0.f, 0.f, 0.f, 0.f};
    int nt2 = w & 3;
    int mt2a = (w >> 2) * 2;

    #pragma unroll
    for (int hh = 0; hh < 4; hh++) {
        // ---- phase 1: h columns [hh*128 + w*16, +16) ----
        f32x4 acc[4];
        #pragma unroll
        for (int mt = 0; mt < 4; mt++) acc[mt] = (f32x4){0.f, 0.f, 0.f, 0.f};
        #pragma unroll
        for (int ks = 0; ks < KSTEPS; ks++) {
            int c = ks * 4 + quad;
            bf16x8 afr[4];
            #pragma unroll
            for (int mt = 0; mt < 4; mt++) {
                int m = mt * 16 + l15;
                int slot = (c & ~7) | ((c ^ m) & 7);
                afr[mt] = *(const bf16x8*)(&inA[m * 96 + slot * 4]);
            }
            int n = hh * 128 + w * 16 + l15;
            size_t bidx = (((size_t)c << 9) + n) << 3;
            bf16x8 bh = *(const bf16x8*)(W1hi + bidx);
            #pragma unroll
            for (int mt = 0; mt < 4; mt++)
                acc[mt] = __builtin_amdgcn_mfma_f32_16x16x32_bf16(afr[mt], bh, acc[mt], 0, 0, 0);
            if (HASLO) {
                bf16x8 bl = *(const bf16x8*)(W1lo + bidx);
                #pragma unroll
                for (int mt = 0; mt < 4; mt++)
                    acc[mt] = __builtin_amdgcn_mfma_f32_16x16x32_bf16(afr[mt], bl, acc[mt], 0, 0, 0);
            }
        }
        __syncthreads();   // prior quarter's hA reads done
        {
            int kh = w * 16 + l15;
            int c = kh >> 3;
            #pragma unroll
            for (int mt = 0; mt < 4; mt++) {
                #pragma unroll
                for (int r = 0; r < 4; r++) {
                    int m = mt * 16 + quad * 4 + r;
                    float s = silu_fast(acc[mt][r]);
                    int slot = (c & 8) | ((c ^ m) & 7);
                    hA[m * 128 + slot * 8 + (kh & 7)] = (u16)f2bfb(s);
                }
            }
        }
        __syncthreads();
        // ---- phase 2 partial: this quarter's K chunk of 128 ----
        #pragma unroll
        for (int ks = 0; ks < 4; ks++) {
            int c = ks * 4 + quad;
            int m0 = mt2a * 16 + l15;
            int m1v = m0 + 16;
            int s0 = (c & 8) | ((c ^ m0) & 7);
            int s1 = (c & 8) | ((c ^ m1v) & 7);
            bf16x8 a0 = *(const bf16x8*)(&hA[m0 * 128 + s0 * 8]);
            bf16x8 a1 = *(const bf16x8*)(&hA[m1v * 128 + s1 * 8]);
            size_t bidx = (((size_t)(hh * 16 + c) << 6) + nt2 * 16 + l15) << 3;
            bf16x8 bh = *(const bf16x8*)(W2hi + bidx);
            acc2[0] = __builtin_amdgcn_mfma_f32_16x16x32_bf16(a0, bh, acc2[0], 0, 0, 0);
            acc2[1] = __builtin_amdgcn_mfma_f32_16x16x32_bf16(a1, bh, acc2[1], 0, 0, 0);
            bf16x8 bl = *(const bf16x8*)(W2lo + bidx);
            acc2[0] = __builtin_amdgcn_mfma_f32_16x16x32_bf16(a0, bl, acc2[0], 0, 0, 0);
            acc2[1] = __builtin_amdgcn_mfma_f32_16x16x32_bf16(a1, bl, acc2[1], 0, 0, 0);
        }
    }
    __syncthreads();
    float* epi = (float*)inA;   // 64 x 65 fp32 overlay
    #pragma unroll
    for (int mi = 0; mi < 2; mi++) {
        #pragma unroll
        for (int r = 0; r < 4; r++) {
            int m = (mt2a + mi) * 16 + quad * 4 + r;
            int c = nt2 * 16 + l15;
            epi[c * 65 + m] = acc2[mi][r];
        }
    }
    __syncthreads();
    float env = envb[e];
    const float is2 = 0.70710678118654752f;
    #pragma unroll
    for (int i = 0; i < 8; i++) {
        int c = w * 8 + i;
        float v = epi[c * 65 + lane];
        float res;
        if (MODE) res = (bfb2f((u32)xprev[(size_t)c * E_NUM + e]) + v * env) * is2;
        else      res = v * env;
        xout[(size_t)c * E_NUM + e] = (u16)f2bfb(res);
        if (FUSEWE) epi[c * 65 + lane] = res;   // final x0 value
    }
    if (FUSEWE) {
        __syncthreads();
        // we = x0 @ Wenv (64x64, K=64) via 16x16x32 MFMA, hi/lo weights.
        // wave w: m-tile mt = w&3, n-tiles (w>>2)*2 + {0,1}.
        int mt = w & 3;
        int ntb = (w >> 2) * 2;
        f32x4 accw[2];
        accw[0] = (f32x4){0.f, 0.f, 0.f, 0.f};
        accw[1] = (f32x4){0.f, 0.f, 0.f, 0.f};
        #pragma unroll
        for (int ks = 0; ks < 2; ks++) {
            bf16x8 af;
            #pragma unroll
            for (int j = 0; j < 8; j++)
                af[j] = (short)f2bfb(epi[(ks * 32 + quad * 8 + j) * 65 + mt * 16 + l15]);
            #pragma unroll
            for (int nti = 0; nti < 2; nti++) {
                int n4 = (ntb + nti) * 16 + l15;
                size_t bidx = (((size_t)(ks * 4 + quad) << 6) + n4) << 3;
                bf16x8 bh = *(const bf16x8*)(wehi + bidx);
                accw[nti] = __builtin_amdgcn_mfma_f32_16x16x32_bf16(af, bh, accw[nti], 0, 0, 0);
                bf16x8 bl = *(const bf16x8*)(welo + bidx);
                accw[nti] = __builtin_amdgcn_mfma_f32_16x16x32_bf16(af, bl, accw[nti], 0, 0, 0);
            }
        }
        #pragma unroll
        for (int nti = 0; nti < 2; nti++) {
            #pragma unroll
            for (int r = 0; r < 4; r++) {
                int rowD = mt * 16 + quad * 4 + r;
                int colD = (ntb + nti) * 16 + l15;
                webuf[(size_t)(e0 + rowD) * 64 + colD] = accw[nti][r];
            }
        }
    }
}

// ---------------- readout ----------------
__global__ void k_readout(const u16* __restrict__ x, const float* __restrict__ Wout,
                          const float* __restrict__ envb, const int* __restrict__ srecv,
                          float* __restrict__ node_acc) {
    int e = blockIdx.x * 256 + threadIdx.x;
    if (e >= E_NUM) return;
    float a = 0.0f;
    #pragma unroll
    for (int c = 0; c < 64; c++) {
        a = fmaf(bfb2f((u32)x[(size_t)c * E_NUM + e]), Wout[c], a);
    }
    a *= envb[e] * (1.0f / 3.0f);
    atomicAdd(&node_acc[srecv[e]], a);
}

__global__ void k_out(const float* __restrict__ node_acc, void* __restrict__ out,
                      const int* __restrict__ flag) {
    int n = blockIdx.x * 256 + threadIdx.x;
    if (n >= NN) return;
    float v = node_acc[n];
    if (*flag) ((float*)out)[n] = v;
    else       ((u16*)out)[n] = (u16)f2bfb(v);
}

extern "C" void kernel_launch(void* const* d_in, const int* in_sizes, int n_in,
                              void* d_out, int out_size, void* d_ws, size_t ws_size,
                              hipStream_t stream) {
    const void* posr   = d_in[0];
    const void* Wemb1r = d_in[1];
    const void* Wemb2r = d_in[2];
    const void* Wvr    = d_in[3];
    const void* Wenvr  = d_in[4];
    const void* Wlat1r = d_in[5];
    const void* Wlat2r = d_in[6];
    const void* Wmixr  = d_in[7];
    const void* Woutr  = d_in[8];
    const int* species   = (const int*)d_in[9];
    const int* senders   = (const int*)d_in[10];
    const int* receivers = (const int*)d_in[11];

    char* p = (char*)d_ws;
    auto alloc = [&](size_t bytes) -> void* {
        void* rp = (void*)p;
        p += (bytes + 255) & ~(size_t)255;
        return rp;
    };
    int*   flag  = (int*)alloc(4);
    float* wbuf  = (float*)alloc(359792 * 4);
    float* posf  = wbuf;
    float* Wemb1 = wbuf + 30000;
    float* Wemb2 = wbuf + 36144;
    float* Wv    = wbuf + 68912;
    float* Wenv  = wbuf + 73008;
    float* Wlat1 = wbuf + 81200;
    float* Wlat2 = wbuf + 277808;
    float* Wmix  = wbuf + 343344;
    float* Wout  = wbuf + 359728;
    const size_t E = E_NUM;
    float* ux   = (float*)alloc(E * 4);
    float* uy   = (float*)alloc(E * 4);
    float* uz   = (float*)alloc(E * 4);
    float* envb = (float*)alloc(E * 4);
    float* rho0A = (float*)alloc((size_t)NN * 64 * 4);
    float* rho1A = (float*)alloc((size_t)NN * 192 * 4);
    float* rho0B = (float*)alloc((size_t)NN * 64 * 4);
    float* rho1B = (float*)alloc((size_t)NN * 192 * 4);
    float* node_acc = (float*)alloc((size_t)NN * 4);
    int* counts    = (int*)alloc((size_t)NN * 4);
    int* rowstart  = (int*)alloc((size_t)(NN + 1) * 4);
    int* cursor    = (int*)alloc((size_t)NN * 4);
    int* edge_list = (int*)alloc(E * 4);
    int* ssend     = (int*)alloc(E * 4);
    int* srecv     = (int*)alloc(E * 4);
    void* unionbuf = alloc(96 * E * 4);
    u32*   latin = (u32*)unionbuf;
    float* webuf = (float*)unionbuf;                       // layer-1 we (base)
    float* we0   = (float*)unionbuf + (size_t)32 * E;      // layer-0 we (rows 32..95)
    u16* x0 = (u16*)alloc(64 * E * 2);
    u16* x1 = (u16*)alloc(64 * E * 2);
    u16* w1hi = (u16*)alloc(2 * 98304 * 2);
    u16* w1lo = (u16*)alloc(2 * 98304 * 2);
    u16* w2hi = (u16*)alloc(2 * 32768 * 2);
    u16* w2lo = (u16*)alloc(2 * 32768 * 2);
    u16* e1hi = (u16*)alloc(32768 * 2);
    u16* e2hi = (u16*)alloc(32768 * 2);
    u16* e2lo = (u16*)alloc(32768 * 2);
    u16* wvhi = (u16*)alloc(4096 * 2);
    u16* wvlo = (u16*)alloc(4096 * 2);

    hipMemsetAsync(flag, 0, 4, stream);
    hipMemsetAsync(counts, 0, (size_t)NN * 4, stream);
    hipMemsetAsync(node_acc, 0, (size_t)NN * 4, stream);
    hipMemsetAsync(latin + (size_t)18 * E, 0, (size_t)14 * E * 4, stream);

    k_detect<<<(15000 + 255) / 256, 256, 0, stream>>>((const u16*)posr, flag);

    k_cvt_all<<<(359792 + 255) / 256, 256, 0, stream>>>(
        posr, Wemb1r, Wemb2r, Wvr, Wenvr, Wlat1r, Wlat2r, Wmixr, Woutr,
        wbuf, flag);

    k_pack_emb1<<<128, 256, 0, stream>>>(Wemb1, e1hi);
    k_pack<<<128, 256, 0, stream>>>(Wemb2, 512, 6, e2hi, e2lo);
    k_pack<<<16, 256, 0, stream>>>(Wenv, 64, 6, wvhi, wvlo);
    for (int l = 0; l < 2; l++) {
        k_pack<<<384, 256, 0, stream>>>(Wlat1 + l * 98304, 192, 9,
                                        w1hi + l * 98304, w1lo + l * 98304);
        k_pack<<<128, 256, 0, stream>>>(Wlat2 + l * 32768, 512, 6,
                                        w2hi + l * 32768, w2lo + l * 32768);
    }

    // CSR over senders -> sorted edge order
    k_hist<<<625, 256, 0, stream>>>(senders, counts);
    k_scan<<<1, 1024, 0, stream>>>(counts, rowstart);
    k_copy_int<<<(NN + 255) / 256, 256, 0, stream>>>(rowstart, cursor, NN);
    k_fill<<<625, 256, 0, stream>>>(senders, cursor, edge_list);

    // embedding (sorted edge space) + fused layer-0 we
    k_geom<<<625, 256, 0, stream>>>(posf, species, senders, receivers, edge_list,
                                    ssend, srecv, ux, uy, uz, envb, latin);
    k_mlp<2, 0, 0, 1><<<2500, 512, 0, stream>>>(latin, e1hi, nullptr, e2hi, e2lo,
                                                envb, nullptr, x0, wvhi, wvlo, we0);

    // layer 0
    k_rho_gather<<<2500, 256, 0, stream>>>(we0, rowstart, ux, uy, uz,
                                           rho0A, rho1A);
    k_stage_l0<<<2500, 512, 0, stream>>>(Wv, rho0A, rho1A, ssend, ux, uy, uz,
                                         x0, latin);
    k_mlp<6, 1, 1, 0><<<2500, 512, 0, stream>>>(latin, w1hi, w1lo, w2hi, w2lo,
                                                envb, x0, x1, nullptr, nullptr, nullptr);

    // layer 1
    k_we<<<625, 256, 0, stream>>>(x1, Wenv + 4096, webuf);
    k_rho_gather<<<2500, 256, 0, stream>>>(webuf, rowstart, ux, uy, uz,
                                           rho0B, rho1B);
    k_stage_l1<<<2500, 512, 0, stream>>>(Wv, Wmix, rho0A, rho1A, rho0B, rho1B,
                                         ssend, ux, uy, uz, x0, x1, latin);
    k_mlp<6, 1, 1, 0><<<2500, 512, 0, stream>>>(latin, w1hi + 98304, w1lo + 98304,
                                                w2hi + 32768, w2lo + 32768,
                                                envb, x1, x1, nullptr, nullptr, nullptr);

    k_readout<<<625, 256, 0, stream>>>(x1, Wout, envb, srecv, node_acc);
    k_out<<<(NN + 255) / 256, 256, 0, stream>>>(node_acc, d_out, flag);
}

// Round 16
// 541.637 us; speedup vs baseline: 1.2265x; 1.1136x over previous
//
#include <hip/hip_runtime.h>
#include <hip/hip_bf16.h>

#define E_NUM 160000
#define NN 10000
#define PI_F 3.14159265358979323846f

using u16 = unsigned short;
using u32 = unsigned int;
typedef short bf16x8 __attribute__((ext_vector_type(8)));
typedef float f32x4 __attribute__((ext_vector_type(4)));
typedef u32 u32x4 __attribute__((ext_vector_type(4)));

__device__ __forceinline__ float silu_fast(float z) {
    return z * __builtin_amdgcn_rcpf(1.0f + __expf(-z));
}
__device__ __forceinline__ float bfb2f(u32 bits16) {
    return __builtin_bit_cast(float, bits16 << 16);
}
__device__ __forceinline__ u32 f2bfb(float f) {
    return (u32)__builtin_bit_cast(u16, __float2bfloat16(f));
}
__device__ __forceinline__ u32 pack2(float lo, float hi) {
    return f2bfb(lo) | (f2bfb(hi) << 16);
}

// ---------------- dtype detection (inputs fp32 vs bf16) ----------------
__global__ void k_detect(const u16* __restrict__ posraw, int* __restrict__ flag) {
    int i = blockIdx.x * 256 + threadIdx.x;
    if (i >= 15000) return;
    float v = bfb2f((u32)posraw[2 * i]);
    if (!(fabsf(v) < 1e4f)) atomicOr(flag, 1);
}

// ---------------- fused dual-dtype ingest of all 9 fp tensors ----------------
__global__ void k_cvt_all(const void* s0, const void* s1, const void* s2,
                          const void* s3, const void* s4, const void* s5,
                          const void* s6, const void* s7, const void* s8,
                          float* __restrict__ dst, const int* __restrict__ flag) {
    int i = blockIdx.x * 256 + threadIdx.x;
    if (i >= 359792) return;
    const void* src; int off;
    if      (i < 30000)  { src = s0; off = i; }
    else if (i < 36144)  { src = s1; off = i - 30000; }
    else if (i < 68912)  { src = s2; off = i - 36144; }
    else if (i < 73008)  { src = s3; off = i - 68912; }
    else if (i < 81200)  { src = s4; off = i - 73008; }
    else if (i < 277808) { src = s5; off = i - 81200; }
    else if (i < 343344) { src = s6; off = i - 277808; }
    else if (i < 359728) { src = s7; off = i - 343344; }
    else                 { src = s8; off = i - 359728; }
    if (*flag) dst[i] = ((const float*)src)[off];
    else       dst[i] = bfb2f((u32)((const u16*)src)[off]);
}

// ---------------- weight packers: [K][N] fp32 -> B-frag layout hi/lo ----------------
__global__ void k_pack(const float* __restrict__ W, int K, int Nshift,
                       u16* __restrict__ hi, u16* __restrict__ lo) {
    int i = blockIdx.x * 256 + threadIdx.x;
    int total = K << Nshift;
    if (i >= total) return;
    int k = i >> Nshift, n = i & ((1 << Nshift) - 1);
    float w = W[i];
    u16 h = (u16)f2bfb(w);
    float r = w - bfb2f((u32)h);
    int idx = ((((k >> 3) << Nshift) + n) << 3) + (k & 7);
    hi[idx] = h; lo[idx] = (u16)f2bfb(r);
}

// emb W1: rows 0..11 = hi(W), 12..23 = hi(W), 24..35 = lo(W), 36..63 = 0
__global__ void k_pack_emb1(const float* __restrict__ W /*12x512*/, u16* __restrict__ pk) {
    int i = blockIdx.x * 256 + threadIdx.x;
    if (i >= 64 * 512) return;
    int k = i >> 9, n = i & 511;
    u16 out = 0;
    if (k < 24) {
        out = (u16)f2bfb(W[(k % 12) * 512 + n]);
    } else if (k < 36) {
        float w = W[(k - 24) * 512 + n];
        u16 h = (u16)f2bfb(w);
        out = (u16)f2bfb(w - bfb2f((u32)h));
    }
    pk[((((k >> 3) << 9) + n) << 3) + (k & 7)] = out;
}

// ---------------- CSR build ----------------
__global__ void k_hist(const int* __restrict__ senders, int* __restrict__ counts) {
    int e = blockIdx.x * 256 + threadIdx.x;
    if (e < E_NUM) atomicAdd(&counts[senders[e]], 1);
}

__global__ __launch_bounds__(1024) void k_scan(const int* __restrict__ counts,
                                               int* __restrict__ rowstart) {
    __shared__ int part[1024];
    int t = threadIdx.x;
    int base = t * 10;
    int local[10];
    int sum = 0;
    #pragma unroll
    for (int i = 0; i < 10; i++) {
        int v = (base + i < NN) ? counts[base + i] : 0;
        local[i] = sum; sum += v;
    }
    part[t] = sum;
    __syncthreads();
    for (int off = 1; off < 1024; off <<= 1) {
        int v = (t >= off) ? part[t - off] : 0;
        __syncthreads();
        part[t] += v;
        __syncthreads();
    }
    int pre = (t == 0) ? 0 : part[t - 1];
    #pragma unroll
    for (int i = 0; i < 10; i++)
        if (base + i < NN) rowstart[base + i] = pre + local[i];
    if (t == 1023) rowstart[NN] = part[1023];
}

__global__ void k_copy_int(const int* __restrict__ src, int* __restrict__ dst, int n) {
    int i = blockIdx.x * 256 + threadIdx.x;
    if (i < n) dst[i] = src[i];
}

__global__ void k_fill(const int* __restrict__ senders, int* __restrict__ cursor,
                       int* __restrict__ edge_list) {
    int e = blockIdx.x * 256 + threadIdx.x;
    if (e >= E_NUM) return;
    int pos = atomicAdd(&cursor[senders[e]], 1);
    edge_list[pos] = e;
}

// ---------------- geometry in SORTED edge space ----------------
__global__ void k_geom(const float* __restrict__ posf, const int* __restrict__ species,
                       const int* __restrict__ senders, const int* __restrict__ receivers,
                       const int* __restrict__ edge_list,
                       int* __restrict__ ssend, int* __restrict__ srecv,
                       float* __restrict__ ux, float* __restrict__ uy, float* __restrict__ uz,
                       float* __restrict__ envb, u32* __restrict__ latin) {
    int e = blockIdx.x * 256 + threadIdx.x;
    if (e >= E_NUM) return;
    int orig = edge_list[e];
    int s = senders[orig], r = receivers[orig];
    ssend[e] = s; srecv[e] = r;
    float rx = posf[3 * r + 0] - posf[3 * s + 0];
    float ry = posf[3 * r + 1] - posf[3 * s + 1];
    float rz = posf[3 * r + 2] - posf[3 * s + 2];
    float d = sqrtf(rx * rx + ry * ry + rz * rz);
    float inv = 1.0f / fmaxf(d, 1e-6f);
    ux[e] = rx * inv; uy[e] = ry * inv; uz[e] = rz * inv;
    float xc = d * 0.5f;
    float env = 0.0f;
    if (xc < 1.0f) { float t = 1.0f - xc * xc; env = t * t; }
    envb[e] = env;
    float ft[12];
    float se = env * inv;
    #pragma unroll
    for (int n = 1; n <= 8; n++) ft[n - 1] = __sinf((float)n * PI_F * xc) * se;
    int ss = species[s], sr = species[r];
    ft[8] = (ss == 0) ? 1.0f : 0.0f;
    ft[9] = (ss == 1) ? 1.0f : 0.0f;
    ft[10] = (sr == 0) ? 1.0f : 0.0f;
    ft[11] = (sr == 1) ? 1.0f : 0.0f;
    u32 fh[12]; float fl[12];
    #pragma unroll
    for (int i = 0; i < 12; i++) {
        fh[i] = f2bfb(ft[i]);
        fl[i] = ft[i] - bfb2f(fh[i]);
    }
    #pragma unroll
    for (int j = 0; j < 6; j++) {
        u32 v = fh[2 * j] | (fh[2 * j + 1] << 16);
        latin[(size_t)j * E_NUM + e] = v;
        latin[(size_t)(12 + j) * E_NUM + e] = v;
        latin[(size_t)(6 + j) * E_NUM + e] = pack2(fl[2 * j], fl[2 * j + 1]);
    }
}

// ---------------- rho gather ----------------
__global__ __launch_bounds__(256) void k_rho_gather(
    const float* __restrict__ we, const int* __restrict__ rowstart,
    const float* __restrict__ ux, const float* __restrict__ uy,
    const float* __restrict__ uz,
    float* __restrict__ rho0, float* __restrict__ rho1) {
    int wv = (blockIdx.x * 256 + threadIdx.x) >> 6;
    int c = threadIdx.x & 63;
    if (wv >= NN) return;
    int start = rowstart[wv], end = rowstart[wv + 1];
    float s0 = 0.0f, sx = 0.0f, sy = 0.0f, sz = 0.0f;
    for (int j = start; j < end; j++) {
        float w = we[(size_t)j * 64 + c];
        float a = ux[j], b = uy[j], g = uz[j];
        s0 += w;
        sx = fmaf(w, a, sx);
        sy = fmaf(w, b, sy);
        sz = fmaf(w, g, sz);
    }
    const float inv3 = 1.0f / 3.0f;
    rho0[(size_t)wv * 64 + c] = s0 * inv3;
    rho1[(size_t)wv * 192 + 3 * c + 0] = sx * inv3;
    rho1[(size_t)wv * 192 + 3 * c + 1] = sy * inv3;
    rho1[(size_t)wv * 192 + 3 * c + 2] = sz * inv3;
}

// ---------------- stage layer 1 (round-14 verified path) ----------------
__global__ __launch_bounds__(512) void k_stage_l1(
    const float* __restrict__ Wv, const float* __restrict__ Wmix0,
    const float* __restrict__ rho0A, const float* __restrict__ rho1A,
    const float* __restrict__ rho0B, const float* __restrict__ rho1B,
    const int* __restrict__ ssend,
    const float* __restrict__ ux, const float* __restrict__ uy,
    const float* __restrict__ uz,
    const u16* __restrict__ x0, const u16* __restrict__ x1,
    u32* __restrict__ latin) {
    __shared__ u32 in2[32 * 64];
    __shared__ u32 xt0[32 * 64];
    int lane = threadIdx.x & 63;
    int sub = threadIdx.x >> 6;
    int subu = __builtin_amdgcn_readfirstlane(sub);
    int e = blockIdx.x * 64 + lane;
    int s = ssend[e];

    #pragma unroll
    for (int j = 0; j < 4; j++) {
        int rr = subu * 4 + j;
        u32 v = (u32)x1[(size_t)(2 * rr) * E_NUM + e] |
                ((u32)x1[(size_t)(2 * rr + 1) * E_NUM + e] << 16);
        in2[rr * 64 + lane] = v;
        latin[(size_t)rr * E_NUM + e] = v;
        u32 v0 = (u32)x0[(size_t)(2 * rr) * E_NUM + e] |
                 ((u32)x0[(size_t)(2 * rr + 1) * E_NUM + e] << 16);
        xt0[rr * 64 + lane] = v0;
    }
    __syncthreads();

    int c0 = subu * 8;
    float a[8] = {0, 0, 0, 0, 0, 0, 0, 0};
    float m1[8] = {0, 0, 0, 0, 0, 0, 0, 0};
    float m2[8] = {0, 0, 0, 0, 0, 0, 0, 0};
    for (int k2 = 0; k2 < 32; k2++) {
        u32 p0 = xt0[k2 * 64 + lane];
        float a0 = bfb2f(p0 & 0xffffu), a1 = bfb2f(p0 >> 16);
        const float* wv0 = Wv + (2 * k2) * 64 + c0;
        const float* wv1 = wv0 + 64;
        #pragma unroll
        for (int i = 0; i < 8; i++) a[i] = fmaf(a0, wv0[i], a[i]);
        #pragma unroll
        for (int i = 0; i < 8; i++) a[i] = fmaf(a1, wv1[i], a[i]);
        u32 p1 = in2[k2 * 64 + lane];
        float b0 = bfb2f(p1 & 0xffffu), b1 = bfb2f(p1 >> 16);
        const float* wm0 = Wmix0 + (2 * k2) * 128 + c0;
        const float* wm1 = wm0 + 128;
        #pragma unroll
        for (int i = 0; i < 8; i++) {
            m1[i] = fmaf(b0, wm0[i], m1[i]);
            m2[i] = fmaf(b0, wm0[64 + i], m2[i]);
            m1[i] = fmaf(b1, wm1[i], m1[i]);
            m2[i] = fmaf(b1, wm1[64 + i], m2[i]);
        }
    }
    float u0 = ux[e], u1 = uy[e], u2 = uz[e];
    const float* r1A = rho1A + (size_t)s * 192;
    const float* r0A = rho0A + (size_t)s * 64;
    const float* r1B = rho1B + (size_t)s * 192;
    const float* r0B = rho0B + (size_t)s * 64;
    float ts[8];
    #pragma unroll
    for (int i = 0; i < 8; i++) {
        int c = c0 + i;
        float v0 = a[i] * u0, v1 = a[i] * u1, v2 = a[i] * u2;
        float aA0 = r1A[3 * c], aA1 = r1A[3 * c + 1], aA2 = r1A[3 * c + 2];
        float rc = r0A[c];
        float w0 = m1[i] * v0 * rc + m2[i] * (v1 * aA2 - v2 * aA1);
        float w1 = m1[i] * v1 * rc + m2[i] * (v2 * aA0 - v0 * aA2);
        float w2 = m1[i] * v2 * rc + m2[i] * (v0 * aA1 - v1 * aA0);
        ts[i] = w0 * r1B[3 * c] + w1 * r1B[3 * c + 1] + w2 * r1B[3 * c + 2];
    }
    #pragma unroll
    for (int j = 0; j < 4; j++) {
        latin[(size_t)(32 + subu * 4 + j) * E_NUM + e] = pack2(ts[2 * j], ts[2 * j + 1]);
    }
    #pragma unroll
    for (int j = 0; j < 4; j++) {
        int ch = 2 * (subu * 4 + j);
        latin[(size_t)(64 + subu * 4 + j) * E_NUM + e] = pack2(r0B[ch], r0B[ch + 1]);
    }
}

// =====================================================================
// MFMA MLP v8: STAGE=0 (latin path, round-14 verified) or STAGE=1
// (fused lat0: stage x0, a=x0@Wv MFMA, tp_scal vs rhoA in LDS).
// inA region padded to 24 KB for all variants so epi never touches hA.
// =====================================================================
template<int KSTEPS, int MODE, int HASLO, int FUSEWE, int STAGE>
__global__ __launch_bounds__(512) void k_mlp(
    const u32* __restrict__ latin,
    const u16* __restrict__ W1hi, const u16* __restrict__ W1lo,
    const u16* __restrict__ W2hi, const u16* __restrict__ W2lo,
    const float* __restrict__ envb,
    u16* __restrict__ xout,
    const u16* __restrict__ wehi, const u16* __restrict__ welo,
    float* __restrict__ webuf,
    const u16* __restrict__ xin,
    const int* __restrict__ ssend,
    const float* __restrict__ ux, const float* __restrict__ uy,
    const float* __restrict__ uz,
    const float* __restrict__ rho0A, const float* __restrict__ rho1A,
    const u16* __restrict__ wvhi, const u16* __restrict__ wvlo) {
    constexpr int ROWDW = KSTEPS * 16;
    constexpr int INAREG = 24576;   // fixed 24 KB region for inA/epi
    __shared__ __align__(16) char smem[INAREG + 16640];
    u32* inA = (u32*)smem;
    u16* hA  = (u16*)(smem + INAREG);      // 16 KB
    float* tb = (float*)(smem + INAREG);   // 64x65 fp32 (prologue transpose)
    int lane = threadIdx.x & 63;
    int sub = threadIdx.x >> 6;
    int w = __builtin_amdgcn_readfirstlane(sub);
    int l15 = lane & 15, quad = lane >> 4;
    int e0 = blockIdx.x * 64;
    int e = e0 + lane;

    if (STAGE == 0) {
        constexpr int CPW = (KSTEPS * 4) / 8;
        #pragma unroll
        for (int j = 0; j < CPW; j++) {
            int c = w * CPW + j;
            u32x4 v;
            #pragma unroll
            for (int i = 0; i < 4; i++) v[i] = latin[(size_t)(c * 4 + i) * E_NUM + e];
            int slot = (c & ~7) | ((c ^ lane) & 7);
            *(u32x4*)(&inA[lane * ROWDW + slot * 4]) = v;
        }
        __syncthreads();
    } else {
        // stage x0 chunks 0..7
        {
            int c = w;
            u32x4 v;
            #pragma unroll
            for (int i = 0; i < 4; i++) {
                u32 lo = (u32)xin[(size_t)(8 * c + 2 * i) * E_NUM + e];
                u32 hi = (u32)xin[(size_t)(8 * c + 2 * i + 1) * E_NUM + e];
                v[i] = lo | (hi << 16);
            }
            int slot = (c & ~7) | ((c ^ lane) & 7);
            *(u32x4*)(&inA[lane * ROWDW + slot * 4]) = v;
        }
        __syncthreads();
        // mini-GEMM a = x0 @ Wv
        int mt = w & 3;
        int ntbA = (w >> 2) * 2;
        f32x4 accA[2];
        accA[0] = (f32x4){0.f, 0.f, 0.f, 0.f};
        accA[1] = (f32x4){0.f, 0.f, 0.f, 0.f};
        #pragma unroll
        for (int ks = 0; ks < 2; ks++) {
            int c = ks * 4 + quad;
            int m = mt * 16 + l15;
            int slot = (c & ~7) | ((c ^ m) & 7);
            bf16x8 af = *(const bf16x8*)(&inA[m * ROWDW + slot * 4]);
            #pragma unroll
            for (int nti = 0; nti < 2; nti++) {
                int n = (ntbA + nti) * 16 + l15;
                size_t bidx = (((size_t)c << 6) + n) << 3;
                bf16x8 bh = *(const bf16x8*)(wvhi + bidx);
                accA[nti] = __builtin_amdgcn_mfma_f32_16x16x32_bf16(af, bh, accA[nti], 0, 0, 0);
                bf16x8 bl = *(const bf16x8*)(wvlo + bidx);
                accA[nti] = __builtin_amdgcn_mfma_f32_16x16x32_bf16(af, bl, accA[nti], 0, 0, 0);
            }
        }
        __syncthreads();
        // transpose a -> tb, read back per-lane
        #pragma unroll
        for (int nti = 0; nti < 2; nti++) {
            #pragma unroll
            for (int r = 0; r < 4; r++) {
                int rowD = mt * 16 + quad * 4 + r;
                int colD = (ntbA + nti) * 16 + l15;
                tb[colD * 65 + rowD] = accA[nti][r];
            }
        }
        __syncthreads();
        int c0 = w * 8;
        float av[8];
        #pragma unroll
        for (int i = 0; i < 8; i++) av[i] = tb[(c0 + i) * 65 + lane];
        // tp_scal + rho0 rows
        int s = ssend[e];
        float u0 = ux[e], u1 = uy[e], u2 = uz[e];
        const float* r1 = rho1A + (size_t)s * 192;
        const float* r0 = rho0A + (size_t)s * 64;
        float ts[8], rr[8];
        #pragma unroll
        for (int i = 0; i < 8; i++) {
            int c = c0 + i;
            float dot = u0 * r1[3 * c] + u1 * r1[3 * c + 1] + u2 * r1[3 * c + 2];
            ts[i] = av[i] * dot;
            rr[i] = r0[c];
        }
        u32x4 tv, rv;
        #pragma unroll
        for (int j = 0; j < 4; j++) {
            tv[j] = pack2(ts[2 * j], ts[2 * j + 1]);
            rv[j] = pack2(rr[2 * j], rr[2 * j + 1]);
        }
        {
            int c = 8 + w;
            int slot = (c & ~7) | ((c ^ lane) & 7);
            *(u32x4*)(&inA[lane * ROWDW + slot * 4]) = tv;
        }
        {
            int c = 16 + w;
            int slot = (c & ~7) | ((c ^ lane) & 7);
            *(u32x4*)(&inA[lane * ROWDW + slot * 4]) = rv;
        }
        __syncthreads();
    }

    // ================= main MLP phases =================
    f32x4 acc2[2];
    acc2[0] = (f32x4){0.f, 0.f, 0.f, 0.f};
    acc2[1] = (f32x4){0.f, 0.f, 0.f, 0.f};
    int nt2 = w & 3;
    int mt2a = (w >> 2) * 2;

    #pragma unroll
    for (int hh = 0; hh < 4; hh++) {
        f32x4 acc[4];
        #pragma unroll
        for (int mt = 0; mt < 4; mt++) acc[mt] = (f32x4){0.f, 0.f, 0.f, 0.f};
        #pragma unroll
        for (int ks = 0; ks < KSTEPS; ks++) {
            int c = ks * 4 + quad;
            bf16x8 afr[4];
            #pragma unroll
            for (int mt = 0; mt < 4; mt++) {
                int m = mt * 16 + l15;
                int slot = (c & ~7) | ((c ^ m) & 7);
                afr[mt] = *(const bf16x8*)(&inA[m * ROWDW + slot * 4]);
            }
            int n = hh * 128 + w * 16 + l15;
            size_t bidx = (((size_t)c << 9) + n) << 3;
            bf16x8 bh = *(const bf16x8*)(W1hi + bidx);
            #pragma unroll
            for (int mt = 0; mt < 4; mt++)
                acc[mt] = __builtin_amdgcn_mfma_f32_16x16x32_bf16(afr[mt], bh, acc[mt], 0, 0, 0);
            if (HASLO) {
                bf16x8 bl = *(const bf16x8*)(W1lo + bidx);
                #pragma unroll
                for (int mt = 0; mt < 4; mt++)
                    acc[mt] = __builtin_amdgcn_mfma_f32_16x16x32_bf16(afr[mt], bl, acc[mt], 0, 0, 0);
            }
        }
        __syncthreads();
        {
            int kh = w * 16 + l15;
            int c = kh >> 3;
            #pragma unroll
            for (int mt = 0; mt < 4; mt++) {
                #pragma unroll
                for (int r = 0; r < 4; r++) {
                    int m = mt * 16 + quad * 4 + r;
                    float s = silu_fast(acc[mt][r]);
                    int slot = (c & 8) | ((c ^ m) & 7);
                    hA[m * 128 + slot * 8 + (kh & 7)] = (u16)f2bfb(s);
                }
            }
        }
        __syncthreads();
        #pragma unroll
        for (int ks = 0; ks < 4; ks++) {
            int c = ks * 4 + quad;
            int m0 = mt2a * 16 + l15;
            int m1i = m0 + 16;
            int s0 = (c & 8) | ((c ^ m0) & 7);
            int s1 = (c & 8) | ((c ^ m1i) & 7);
            bf16x8 a0 = *(const bf16x8*)(&hA[m0 * 128 + s0 * 8]);
            bf16x8 a1 = *(const bf16x8*)(&hA[m1i * 128 + s1 * 8]);
            size_t bidx = (((size_t)(hh * 16 + c) << 6) + nt2 * 16 + l15) << 3;
            bf16x8 bh = *(const bf16x8*)(W2hi + bidx);
            acc2[0] = __builtin_amdgcn_mfma_f32_16x16x32_bf16(a0, bh, acc2[0], 0, 0, 0);
            acc2[1] = __builtin_amdgcn_mfma_f32_16x16x32_bf16(a1, bh, acc2[1], 0, 0, 0);
            bf16x8 bl = *(const bf16x8*)(W2lo + bidx);
            acc2[0] = __builtin_amdgcn_mfma_f32_16x16x32_bf16(a0, bl, acc2[0], 0, 0, 0);
            acc2[1] = __builtin_amdgcn_mfma_f32_16x16x32_bf16(a1, bl, acc2[1], 0, 0, 0);
        }
    }
    // read xprev (lat_in rows 0..63 == current-layer x) from LDS before epi overlay
    float xo[8];
    if (MODE) {
        int c = w;
        int slot = (c & ~7) | ((c ^ lane) & 7);
        #pragma unroll
        for (int i = 0; i < 4; i++) {
            u32 pv = inA[lane * ROWDW + slot * 4 + i];
            xo[2 * i]     = bfb2f(pv & 0xffffu);
            xo[2 * i + 1] = bfb2f(pv >> 16);
        }
    }
    __syncthreads();
    float* epi = (float*)inA;   // 64 x 65 fp32 overlay (16.6 KB < 24 KB)
    #pragma unroll
    for (int mi = 0; mi < 2; mi++) {
        #pragma unroll
        for (int r = 0; r < 4; r++) {
            int m = (mt2a + mi) * 16 + quad * 4 + r;
            int c = nt2 * 16 + l15;
            epi[c * 65 + m] = acc2[mi][r];
        }
    }
    __syncthreads();
    float env = envb[e];
    const float is2 = 0.70710678118654752f;
    #pragma unroll
    for (int i = 0; i < 8; i++) {
        int c = w * 8 + i;
        float v = epi[c * 65 + lane];
        float res;
        if (MODE) res = (xo[i] + v * env) * is2;
        else      res = v * env;
        xout[(size_t)c * E_NUM + e] = (u16)f2bfb(res);
        if (FUSEWE) epi[c * 65 + lane] = res;
    }
    if (FUSEWE) {
        __syncthreads();
        int mt = w & 3;
        int ntb = (w >> 2) * 2;
        f32x4 accw[2];
        accw[0] = (f32x4){0.f, 0.f, 0.f, 0.f};
        accw[1] = (f32x4){0.f, 0.f, 0.f, 0.f};
        #pragma unroll
        for (int ks = 0; ks < 2; ks++) {
            bf16x8 af;
            #pragma unroll
            for (int j = 0; j < 8; j++)
                af[j] = (short)f2bfb(epi[(ks * 32 + quad * 8 + j) * 65 + mt * 16 + l15]);
            #pragma unroll
            for (int nti = 0; nti < 2; nti++) {
                int n4 = (ntb + nti) * 16 + l15;
                size_t bidx = (((size_t)(ks * 4 + quad) << 6) + n4) << 3;
                bf16x8 bh = *(const bf16x8*)(wehi + bidx);
                accw[nti] = __builtin_amdgcn_mfma_f32_16x16x32_bf16(af, bh, accw[nti], 0, 0, 0);
                bf16x8 bl = *(const bf16x8*)(welo + bidx);
                accw[nti] = __builtin_amdgcn_mfma_f32_16x16x32_bf16(af, bl, accw[nti], 0, 0, 0);
            }
        }
        #pragma unroll
        for (int nti = 0; nti < 2; nti++) {
            #pragma unroll
            for (int r = 0; r < 4; r++) {
                int rowD = mt * 16 + quad * 4 + r;
                int colD = (ntb + nti) * 16 + l15;
                webuf[(size_t)(e0 + rowD) * 64 + colD] = accw[nti][r];
            }
        }
    }
}

// ---------------- readout ----------------
__global__ void k_readout(const u16* __restrict__ x, const float* __restrict__ Wout,
                          const float* __restrict__ envb, const int* __restrict__ srecv,
                          float* __restrict__ node_acc) {
    int e = blockIdx.x * 256 + threadIdx.x;
    if (e >= E_NUM) return;
    float a = 0.0f;
    #pragma unroll
    for (int c = 0; c < 64; c++) {
        a = fmaf(bfb2f((u32)x[(size_t)c * E_NUM + e]), Wout[c], a);
    }
    a *= envb[e] * (1.0f / 3.0f);
    atomicAdd(&node_acc[srecv[e]], a);
}

__global__ void k_out(const float* __restrict__ node_acc, void* __restrict__ out,
                      const int* __restrict__ flag) {
    int n = blockIdx.x * 256 + threadIdx.x;
    if (n >= NN) return;
    float v = node_acc[n];
    if (*flag) ((float*)out)[n] = v;
    else       ((u16*)out)[n] = (u16)f2bfb(v);
}

extern "C" void kernel_launch(void* const* d_in, const int* in_sizes, int n_in,
                              void* d_out, int out_size, void* d_ws, size_t ws_size,
                              hipStream_t stream) {
    const void* posr   = d_in[0];
    const void* Wemb1r = d_in[1];
    const void* Wemb2r = d_in[2];
    const void* Wvr    = d_in[3];
    const void* Wenvr  = d_in[4];
    const void* Wlat1r = d_in[5];
    const void* Wlat2r = d_in[6];
    const void* Wmixr  = d_in[7];
    const void* Woutr  = d_in[8];
    const int* species   = (const int*)d_in[9];
    const int* senders   = (const int*)d_in[10];
    const int* receivers = (const int*)d_in[11];

    char* p = (char*)d_ws;
    auto alloc = [&](size_t bytes) -> void* {
        void* rp = (void*)p;
        p += (bytes + 255) & ~(size_t)255;
        return rp;
    };
    int*   flag  = (int*)alloc(4);
    float* wbuf  = (float*)alloc(359792 * 4);
    float* posf  = wbuf;
    float* Wemb1 = wbuf + 30000;
    float* Wemb2 = wbuf + 36144;
    float* Wv    = wbuf + 68912;
    float* Wenv  = wbuf + 73008;
    float* Wlat1 = wbuf + 81200;
    float* Wlat2 = wbuf + 277808;
    float* Wmix  = wbuf + 343344;
    float* Wout  = wbuf + 359728;
    const size_t E = E_NUM;
    float* ux   = (float*)alloc(E * 4);
    float* uy   = (float*)alloc(E * 4);
    float* uz   = (float*)alloc(E * 4);
    float* envb = (float*)alloc(E * 4);
    float* rho0A = (float*)alloc((size_t)NN * 64 * 4);
    float* rho1A = (float*)alloc((size_t)NN * 192 * 4);
    float* rho0B = (float*)alloc((size_t)NN * 64 * 4);
    float* rho1B = (float*)alloc((size_t)NN * 192 * 4);
    float* node_acc = (float*)alloc((size_t)NN * 4);
    int* counts    = (int*)alloc((size_t)NN * 4);
    int* rowstart  = (int*)alloc((size_t)(NN + 1) * 4);
    int* cursor    = (int*)alloc((size_t)NN * 4);
    int* edge_list = (int*)alloc(E * 4);
    int* ssend     = (int*)alloc(E * 4);
    int* srecv     = (int*)alloc(E * 4);
    void* unionbuf = alloc(96 * E * 4);
    u32*   latin = (u32*)unionbuf;                      // lat_in rows 0..95 / emb rows 0..31
    float* webuf = (float*)unionbuf + (size_t)32 * E;   // we region (rows 32..95)
    u16* x0 = (u16*)alloc(64 * E * 2);
    u16* x1 = (u16*)alloc(64 * E * 2);
    u16* w1hi = (u16*)alloc(2 * 98304 * 2);
    u16* w1lo = (u16*)alloc(2 * 98304 * 2);
    u16* w2hi = (u16*)alloc(2 * 32768 * 2);
    u16* w2lo = (u16*)alloc(2 * 32768 * 2);
    u16* e1hi = (u16*)alloc(32768 * 2);
    u16* e2hi = (u16*)alloc(32768 * 2);
    u16* e2lo = (u16*)alloc(32768 * 2);
    u16* we0hi = (u16*)alloc(4096 * 2);   // Wenv layer 0
    u16* we0lo = (u16*)alloc(4096 * 2);
    u16* we1hi = (u16*)alloc(4096 * 2);   // Wenv layer 1
    u16* we1lo = (u16*)alloc(4096 * 2);
    u16* wvhi  = (u16*)alloc(4096 * 2);   // Wv
    u16* wvlo  = (u16*)alloc(4096 * 2);

    hipMemsetAsync(flag, 0, 4, stream);
    hipMemsetAsync(counts, 0, (size_t)NN * 4, stream);
    hipMemsetAsync(node_acc, 0, (size_t)NN * 4, stream);
    hipMemsetAsync(latin + (size_t)18 * E, 0, (size_t)14 * E * 4, stream);

    k_detect<<<(15000 + 255) / 256, 256, 0, stream>>>((const u16*)posr, flag);

    k_cvt_all<<<(359792 + 255) / 256, 256, 0, stream>>>(
        posr, Wemb1r, Wemb2r, Wvr, Wenvr, Wlat1r, Wlat2r, Wmixr, Woutr,
        wbuf, flag);

    k_pack_emb1<<<128, 256, 0, stream>>>(Wemb1, e1hi);
    k_pack<<<128, 256, 0, stream>>>(Wemb2, 512, 6, e2hi, e2lo);
    k_pack<<<16, 256, 0, stream>>>(Wenv, 64, 6, we0hi, we0lo);
    k_pack<<<16, 256, 0, stream>>>(Wenv + 4096, 64, 6, we1hi, we1lo);
    k_pack<<<16, 256, 0, stream>>>(Wv, 64, 6, wvhi, wvlo);
    for (int l = 0; l < 2; l++) {
        k_pack<<<384, 256, 0, stream>>>(Wlat1 + l * 98304, 192, 9,
                                        w1hi + l * 98304, w1lo + l * 98304);
        k_pack<<<128, 256, 0, stream>>>(Wlat2 + l * 32768, 512, 6,
                                        w2hi + l * 32768, w2lo + l * 32768);
    }

    // CSR over senders -> sorted edge order
    k_hist<<<625, 256, 0, stream>>>(senders, counts);
    k_scan<<<1, 1024, 0, stream>>>(counts, rowstart);
    k_copy_int<<<(NN + 255) / 256, 256, 0, stream>>>(rowstart, cursor, NN);
    k_fill<<<625, 256, 0, stream>>>(senders, cursor, edge_list);

    // embedding + fused layer-0 we
    k_geom<<<625, 256, 0, stream>>>(posf, species, senders, receivers, edge_list,
                                    ssend, srecv, ux, uy, uz, envb, latin);
    k_mlp<2, 0, 0, 1, 0><<<2500, 512, 0, stream>>>(
        latin, e1hi, nullptr, e2hi, e2lo, envb, x0, we0hi, we0lo, webuf,
        nullptr, nullptr, nullptr, nullptr, nullptr, nullptr, nullptr,
        nullptr, nullptr);

    // layer 0 (fused stage) + fused layer-1 we
    k_rho_gather<<<2500, 256, 0, stream>>>(webuf, rowstart, ux, uy, uz,
                                           rho0A, rho1A);
    k_mlp<6, 1, 1, 1, 1><<<2500, 512, 0, stream>>>(
        nullptr, w1hi, w1lo, w2hi, w2lo, envb, x1, we1hi, we1lo, webuf,
        x0, ssend, ux, uy, uz, rho0A, rho1A, wvhi, wvlo);

    // layer 1 (round-14 verified latin path)
    k_rho_gather<<<2500, 256, 0, stream>>>(webuf, rowstart, ux, uy, uz,
                                           rho0B, rho1B);
    k_stage_l1<<<2500, 512, 0, stream>>>(Wv, Wmix, rho0A, rho1A, rho0B, rho1B,
                                         ssend, ux, uy, uz, x0, x1, latin);
    k_mlp<6, 1, 1, 0, 0><<<2500, 512, 0, stream>>>(
        latin, w1hi + 98304, w1lo + 98304, w2hi + 32768, w2lo + 32768,
        envb, x1, nullptr, nullptr, nullptr,
        nullptr, nullptr, nullptr, nullptr, nullptr, nullptr, nullptr,
        nullptr, nullptr);

    k_readout<<<625, 256, 0, stream>>>(x1, Wout, envb, srecv, node_acc);
    k_out<<<(NN + 255) / 256, 256, 0, stream>>>(node_acc, d_out, flag);
}

// Round 17
// 534.746 us; speedup vs baseline: 1.2423x; 1.0129x over previous
//
#include <hip/hip_runtime.h>
#include <hip/hip_bf16.h>

#define E_NUM 160000
#define NN 10000
#define PI_F 3.14159265358979323846f

using u16 = unsigned short;
using u32 = unsigned int;
typedef short bf16x8 __attribute__((ext_vector_type(8)));
typedef float f32x4 __attribute__((ext_vector_type(4)));
typedef u32 u32x4 __attribute__((ext_vector_type(4)));

__device__ __forceinline__ float silu_fast(float z) {
    return z * __builtin_amdgcn_rcpf(1.0f + __expf(-z));
}
__device__ __forceinline__ float bfb2f(u32 bits16) {
    return __builtin_bit_cast(float, bits16 << 16);
}
__device__ __forceinline__ u32 f2bfb(float f) {
    return (u32)__builtin_bit_cast(u16, __float2bfloat16(f));
}
__device__ __forceinline__ u32 pack2(float lo, float hi) {
    return f2bfb(lo) | (f2bfb(hi) << 16);
}

// ---------------- dtype detection (inputs fp32 vs bf16) ----------------
__global__ void k_detect(const u16* __restrict__ posraw, int* __restrict__ flag) {
    int i = blockIdx.x * 256 + threadIdx.x;
    if (i >= 15000) return;
    float v = bfb2f((u32)posraw[2 * i]);
    if (!(fabsf(v) < 1e4f)) atomicOr(flag, 1);
}

// ---------------- fused dual-dtype ingest of all 9 fp tensors ----------------
__global__ void k_cvt_all(const void* s0, const void* s1, const void* s2,
                          const void* s3, const void* s4, const void* s5,
                          const void* s6, const void* s7, const void* s8,
                          float* __restrict__ dst, const int* __restrict__ flag) {
    int i = blockIdx.x * 256 + threadIdx.x;
    if (i >= 359792) return;
    const void* src; int off;
    if      (i < 30000)  { src = s0; off = i; }
    else if (i < 36144)  { src = s1; off = i - 30000; }
    else if (i < 68912)  { src = s2; off = i - 36144; }
    else if (i < 73008)  { src = s3; off = i - 68912; }
    else if (i < 81200)  { src = s4; off = i - 73008; }
    else if (i < 277808) { src = s5; off = i - 81200; }
    else if (i < 343344) { src = s6; off = i - 277808; }
    else if (i < 359728) { src = s7; off = i - 343344; }
    else                 { src = s8; off = i - 359728; }
    if (*flag) dst[i] = ((const float*)src)[off];
    else       dst[i] = bfb2f((u32)((const u16*)src)[off]);
}

// ---------------- weight packers: [K][N] fp32 -> B-frag layout hi/lo ----------------
__global__ void k_pack(const float* __restrict__ W, int K, int Nshift,
                       u16* __restrict__ hi, u16* __restrict__ lo) {
    int i = blockIdx.x * 256 + threadIdx.x;
    int total = K << Nshift;
    if (i >= total) return;
    int k = i >> Nshift, n = i & ((1 << Nshift) - 1);
    float w = W[i];
    u16 h = (u16)f2bfb(w);
    float r = w - bfb2f((u32)h);
    int idx = ((((k >> 3) << Nshift) + n) << 3) + (k & 7);
    hi[idx] = h; lo[idx] = (u16)f2bfb(r);
}

// emb W1: rows 0..11 = hi(W), 12..23 = hi(W), 24..35 = lo(W), 36..63 = 0
__global__ void k_pack_emb1(const float* __restrict__ W /*12x512*/, u16* __restrict__ pk) {
    int i = blockIdx.x * 256 + threadIdx.x;
    if (i >= 64 * 512) return;
    int k = i >> 9, n = i & 511;
    u16 out = 0;
    if (k < 24) {
        out = (u16)f2bfb(W[(k % 12) * 512 + n]);
    } else if (k < 36) {
        float w = W[(k - 24) * 512 + n];
        u16 h = (u16)f2bfb(w);
        out = (u16)f2bfb(w - bfb2f((u32)h));
    }
    pk[((((k >> 3) << 9) + n) << 3) + (k & 7)] = out;
}

// ---------------- CSR build ----------------
__global__ void k_hist(const int* __restrict__ senders, int* __restrict__ counts) {
    int e = blockIdx.x * 256 + threadIdx.x;
    if (e < E_NUM) atomicAdd(&counts[senders[e]], 1);
}

__global__ __launch_bounds__(1024) void k_scan(const int* __restrict__ counts,
                                               int* __restrict__ rowstart) {
    __shared__ int part[1024];
    int t = threadIdx.x;
    int base = t * 10;
    int local[10];
    int sum = 0;
    #pragma unroll
    for (int i = 0; i < 10; i++) {
        int v = (base + i < NN) ? counts[base + i] : 0;
        local[i] = sum; sum += v;
    }
    part[t] = sum;
    __syncthreads();
    for (int off = 1; off < 1024; off <<= 1) {
        int v = (t >= off) ? part[t - off] : 0;
        __syncthreads();
        part[t] += v;
        __syncthreads();
    }
    int pre = (t == 0) ? 0 : part[t - 1];
    #pragma unroll
    for (int i = 0; i < 10; i++)
        if (base + i < NN) rowstart[base + i] = pre + local[i];
    if (t == 1023) rowstart[NN] = part[1023];
}

__global__ void k_copy_int(const int* __restrict__ src, int* __restrict__ dst, int n) {
    int i = blockIdx.x * 256 + threadIdx.x;
    if (i < n) dst[i] = src[i];
}

__global__ void k_fill(const int* __restrict__ senders, int* __restrict__ cursor,
                       int* __restrict__ edge_list) {
    int e = blockIdx.x * 256 + threadIdx.x;
    if (e >= E_NUM) return;
    int pos = atomicAdd(&cursor[senders[e]], 1);
    edge_list[pos] = e;
}

// ---------------- geometry in SORTED edge space ----------------
__global__ void k_geom(const float* __restrict__ posf, const int* __restrict__ species,
                       const int* __restrict__ senders, const int* __restrict__ receivers,
                       const int* __restrict__ edge_list,
                       int* __restrict__ ssend, int* __restrict__ srecv,
                       float* __restrict__ ux, float* __restrict__ uy, float* __restrict__ uz,
                       float* __restrict__ envb, u32* __restrict__ latin) {
    int e = blockIdx.x * 256 + threadIdx.x;
    if (e >= E_NUM) return;
    int orig = edge_list[e];
    int s = senders[orig], r = receivers[orig];
    ssend[e] = s; srecv[e] = r;
    float rx = posf[3 * r + 0] - posf[3 * s + 0];
    float ry = posf[3 * r + 1] - posf[3 * s + 1];
    float rz = posf[3 * r + 2] - posf[3 * s + 2];
    float d = sqrtf(rx * rx + ry * ry + rz * rz);
    float inv = 1.0f / fmaxf(d, 1e-6f);
    ux[e] = rx * inv; uy[e] = ry * inv; uz[e] = rz * inv;
    float xc = d * 0.5f;
    float env = 0.0f;
    if (xc < 1.0f) { float t = 1.0f - xc * xc; env = t * t; }
    envb[e] = env;
    float ft[12];
    float se = env * inv;
    #pragma unroll
    for (int n = 1; n <= 8; n++) ft[n - 1] = __sinf((float)n * PI_F * xc) * se;
    int ss = species[s], sr = species[r];
    ft[8] = (ss == 0) ? 1.0f : 0.0f;
    ft[9] = (ss == 1) ? 1.0f : 0.0f;
    ft[10] = (sr == 0) ? 1.0f : 0.0f;
    ft[11] = (sr == 1) ? 1.0f : 0.0f;
    u32 fh[12]; float fl[12];
    #pragma unroll
    for (int i = 0; i < 12; i++) {
        fh[i] = f2bfb(ft[i]);
        fl[i] = ft[i] - bfb2f(fh[i]);
    }
    #pragma unroll
    for (int j = 0; j < 6; j++) {
        u32 v = fh[2 * j] | (fh[2 * j + 1] << 16);
        latin[(size_t)j * E_NUM + e] = v;
        latin[(size_t)(12 + j) * E_NUM + e] = v;
        latin[(size_t)(6 + j) * E_NUM + e] = pack2(fl[2 * j], fl[2 * j + 1]);
    }
}

// ---------------- rho gather ----------------
__global__ __launch_bounds__(256) void k_rho_gather(
    const float* __restrict__ we, const int* __restrict__ rowstart,
    const float* __restrict__ ux, const float* __restrict__ uy,
    const float* __restrict__ uz,
    float* __restrict__ rho0, float* __restrict__ rho1) {
    int wv = (blockIdx.x * 256 + threadIdx.x) >> 6;
    int c = threadIdx.x & 63;
    if (wv >= NN) return;
    int start = rowstart[wv], end = rowstart[wv + 1];
    float s0 = 0.0f, sx = 0.0f, sy = 0.0f, sz = 0.0f;
    for (int j = start; j < end; j++) {
        float w = we[(size_t)j * 64 + c];
        float a = ux[j], b = uy[j], g = uz[j];
        s0 += w;
        sx = fmaf(w, a, sx);
        sy = fmaf(w, b, sy);
        sz = fmaf(w, g, sz);
    }
    const float inv3 = 1.0f / 3.0f;
    rho0[(size_t)wv * 64 + c] = s0 * inv3;
    rho1[(size_t)wv * 192 + 3 * c + 0] = sx * inv3;
    rho1[(size_t)wv * 192 + 3 * c + 1] = sy * inv3;
    rho1[(size_t)wv * 192 + 3 * c + 2] = sz * inv3;
}

// =====================================================================
// MFMA MLP v9:
//  STAGE=0: input from latin (verified).
//  STAGE=1: fused lat0 (verified round 16): stage x0, a=x0@Wv, tp vs rhoA.
//  STAGE=2: fused lat1 (redesigned): stage x1->inA + x0->xt0; GEMMs
//   a=x0@Wv, m=x1@Wmix; SINGLE transpose round into disjoint tbA/tbB/tbC;
//   per-lane V1 chain (identical math to verified k_stage_l1).
// =====================================================================
template<int KSTEPS, int MODE, int HASLO, int FUSEWE, int STAGE>
__global__ __launch_bounds__(512) void k_mlp(
    const u32* __restrict__ latin,
    const u16* __restrict__ W1hi, const u16* __restrict__ W1lo,
    const u16* __restrict__ W2hi, const u16* __restrict__ W2lo,
    const float* __restrict__ envb,
    u16* __restrict__ xout,
    const u16* __restrict__ wehi, const u16* __restrict__ welo,
    float* __restrict__ webuf,
    const u16* __restrict__ xin,
    const u16* __restrict__ x0t,
    const int* __restrict__ ssend,
    const float* __restrict__ ux, const float* __restrict__ uy,
    const float* __restrict__ uz,
    const float* __restrict__ rho0A, const float* __restrict__ rho1A,
    const float* __restrict__ rho0B, const float* __restrict__ rho1B,
    const u16* __restrict__ wvhi, const u16* __restrict__ wvlo,
    const u16* __restrict__ wmhi, const u16* __restrict__ wmlo) {
    constexpr int ROWDW = KSTEPS * 16;
    constexpr int INAREG = 24576;
    constexpr int SMEMSZ = (STAGE == 2) ? (INAREG + 3 * 16640) : (INAREG + 16640);
    __shared__ __align__(16) char smem[SMEMSZ];
    u32* inA = (u32*)smem;
    u16* hA  = (u16*)(smem + INAREG);           // 16 KB (phases)
    float* tbA = (float*)(smem + INAREG);       // 64x65 fp32
    float* tbB = (float*)(smem + INAREG + 16640);
    float* tbC = (float*)(smem + INAREG + 2 * 16640);
    u32* xt0 = (u32*)(smem + INAREG + 16640);   // x0 tile (STAGE==2), 8 KB, dies at m1 transpose
    int lane = threadIdx.x & 63;
    int sub = threadIdx.x >> 6;
    int w = __builtin_amdgcn_readfirstlane(sub);
    int l15 = lane & 15, quad = lane >> 4;
    int e0 = blockIdx.x * 64;
    int e = e0 + lane;

    if (STAGE == 0) {
        constexpr int CPW = (KSTEPS * 4) / 8;
        #pragma unroll
        for (int j = 0; j < CPW; j++) {
            int c = w * CPW + j;
            u32x4 v;
            #pragma unroll
            for (int i = 0; i < 4; i++) v[i] = latin[(size_t)(c * 4 + i) * E_NUM + e];
            int slot = (c & ~7) | ((c ^ lane) & 7);
            *(u32x4*)(&inA[lane * ROWDW + slot * 4]) = v;
        }
        __syncthreads();
    } else {
        // stage xin chunks 0..7 -> inA
        {
            int c = w;
            u32x4 v;
            #pragma unroll
            for (int i = 0; i < 4; i++) {
                u32 lo = (u32)xin[(size_t)(8 * c + 2 * i) * E_NUM + e];
                u32 hi = (u32)xin[(size_t)(8 * c + 2 * i + 1) * E_NUM + e];
                v[i] = lo | (hi << 16);
            }
            int slot = (c & ~7) | ((c ^ lane) & 7);
            *(u32x4*)(&inA[lane * ROWDW + slot * 4]) = v;
        }
        if (STAGE == 2) {
            int c = w;
            u32x4 v;
            #pragma unroll
            for (int i = 0; i < 4; i++) {
                u32 lo = (u32)x0t[(size_t)(8 * c + 2 * i) * E_NUM + e];
                u32 hi = (u32)x0t[(size_t)(8 * c + 2 * i + 1) * E_NUM + e];
                v[i] = lo | (hi << 16);
            }
            int slot = (c ^ lane) & 7;
            *(u32x4*)(&xt0[lane * 32 + slot * 4]) = v;
        }
        __syncthreads();
        // mini-GEMM a = x0 @ Wv
        int mt = w & 3;
        int ntbA = (w >> 2) * 2;
        f32x4 accA[2];
        accA[0] = (f32x4){0.f, 0.f, 0.f, 0.f};
        accA[1] = (f32x4){0.f, 0.f, 0.f, 0.f};
        #pragma unroll
        for (int ks = 0; ks < 2; ks++) {
            int c = ks * 4 + quad;
            int m = mt * 16 + l15;
            bf16x8 af;
            if (STAGE == 1) {
                int slot = (c & ~7) | ((c ^ m) & 7);
                af = *(const bf16x8*)(&inA[m * ROWDW + slot * 4]);
            } else {
                int slot = (c ^ m) & 7;
                af = *(const bf16x8*)(&xt0[m * 32 + slot * 4]);
            }
            #pragma unroll
            for (int nti = 0; nti < 2; nti++) {
                int n = (ntbA + nti) * 16 + l15;
                size_t bidx = (((size_t)c << 6) + n) << 3;
                bf16x8 bh = *(const bf16x8*)(wvhi + bidx);
                accA[nti] = __builtin_amdgcn_mfma_f32_16x16x32_bf16(af, bh, accA[nti], 0, 0, 0);
                bf16x8 bl = *(const bf16x8*)(wvlo + bidx);
                accA[nti] = __builtin_amdgcn_mfma_f32_16x16x32_bf16(af, bl, accA[nti], 0, 0, 0);
            }
        }
        // mini-GEMM m = x1 @ Wmix (STAGE==2)
        f32x4 accM[4];
        if (STAGE == 2) {
            #pragma unroll
            for (int i = 0; i < 4; i++) accM[i] = (f32x4){0.f, 0.f, 0.f, 0.f};
            int nbM = (w >> 2) * 4;   // waves 0-3: n-tiles 0..3 (m1); 4-7: 4..7 (m2)
            #pragma unroll
            for (int ks = 0; ks < 2; ks++) {
                int c = ks * 4 + quad;
                int m = mt * 16 + l15;
                int slot = (c & ~7) | ((c ^ m) & 7);
                bf16x8 af = *(const bf16x8*)(&inA[m * ROWDW + slot * 4]);
                #pragma unroll
                for (int nti = 0; nti < 4; nti++) {
                    int n = (nbM + nti) * 16 + l15;
                    size_t bidx = (((size_t)c << 7) + n) << 3;
                    bf16x8 bh = *(const bf16x8*)(wmhi + bidx);
                    accM[nti] = __builtin_amdgcn_mfma_f32_16x16x32_bf16(af, bh, accM[nti], 0, 0, 0);
                    bf16x8 bl = *(const bf16x8*)(wmlo + bidx);
                    accM[nti] = __builtin_amdgcn_mfma_f32_16x16x32_bf16(af, bl, accM[nti], 0, 0, 0);
                }
            }
        }
        __syncthreads();   // all GEMM LDS reads done
        // ---- SINGLE transpose round into disjoint buffers ----
        #pragma unroll
        for (int nti = 0; nti < 2; nti++) {
            #pragma unroll
            for (int r = 0; r < 4; r++) {
                int rowD = mt * 16 + quad * 4 + r;
                int colD = (ntbA + nti) * 16 + l15;
                tbA[colD * 65 + rowD] = accA[nti][r];
            }
        }
        if (STAGE == 2) {
            float* dst = (w < 4) ? tbB : tbC;
            #pragma unroll
            for (int nti = 0; nti < 4; nti++) {
                #pragma unroll
                for (int r = 0; r < 4; r++) {
                    int rowD = mt * 16 + quad * 4 + r;
                    int colD = nti * 16 + l15;   // n minus 0 or 64
                    dst[colD * 65 + rowD] = accM[nti][r];
                }
            }
        }
        __syncthreads();
        int c0 = w * 8;
        float av[8], m1v[8], m2v[8];
        #pragma unroll
        for (int i = 0; i < 8; i++) av[i] = tbA[(c0 + i) * 65 + lane];
        if (STAGE == 2) {
            #pragma unroll
            for (int i = 0; i < 8; i++) m1v[i] = tbB[(c0 + i) * 65 + lane];
            #pragma unroll
            for (int i = 0; i < 8; i++) m2v[i] = tbC[(c0 + i) * 65 + lane];
        }
        // per-lane tp math + gathers
        int s = ssend[e];
        float u0 = ux[e], u1 = uy[e], u2 = uz[e];
        float ts[8], rr[8];
        if (STAGE == 1) {
            const float* r1 = rho1A + (size_t)s * 192;
            const float* r0 = rho0A + (size_t)s * 64;
            #pragma unroll
            for (int i = 0; i < 8; i++) {
                int c = c0 + i;
                float dot = u0 * r1[3 * c] + u1 * r1[3 * c + 1] + u2 * r1[3 * c + 2];
                ts[i] = av[i] * dot;
                rr[i] = r0[c];
            }
        } else {
            const float* r1A = rho1A + (size_t)s * 192;
            const float* r0A = rho0A + (size_t)s * 64;
            const float* r1B = rho1B + (size_t)s * 192;
            const float* r0B = rho0B + (size_t)s * 64;
            #pragma unroll
            for (int i = 0; i < 8; i++) {
                int c = c0 + i;
                float v0 = av[i] * u0, v1 = av[i] * u1, v2 = av[i] * u2;
                float aA0 = r1A[3 * c], aA1 = r1A[3 * c + 1], aA2 = r1A[3 * c + 2];
                float rc = r0A[c];
                float w0 = m1v[i] * v0 * rc + m2v[i] * (v1 * aA2 - v2 * aA1);
                float w1 = m1v[i] * v1 * rc + m2v[i] * (v2 * aA0 - v0 * aA2);
                float w2 = m1v[i] * v2 * rc + m2v[i] * (v0 * aA1 - v1 * aA0);
                ts[i] = w0 * r1B[3 * c] + w1 * r1B[3 * c + 1] + w2 * r1B[3 * c + 2];
                rr[i] = r0B[c];
            }
        }
        u32x4 tv, rv;
        #pragma unroll
        for (int j = 0; j < 4; j++) {
            tv[j] = pack2(ts[2 * j], ts[2 * j + 1]);
            rv[j] = pack2(rr[2 * j], rr[2 * j + 1]);
        }
        {
            int c = 8 + w;
            int slot = (c & ~7) | ((c ^ lane) & 7);
            *(u32x4*)(&inA[lane * ROWDW + slot * 4]) = tv;
        }
        {
            int c = 16 + w;
            int slot = (c & ~7) | ((c ^ lane) & 7);
            *(u32x4*)(&inA[lane * ROWDW + slot * 4]) = rv;
        }
        __syncthreads();
    }

    // ================= main MLP phases =================
    f32x4 acc2[2];
    acc2[0] = (f32x4){0.f, 0.f, 0.f, 0.f};
    acc2[1] = (f32x4){0.f, 0.f, 0.f, 0.f};
    int nt2 = w & 3;
    int mt2a = (w >> 2) * 2;

    #pragma unroll
    for (int hh = 0; hh < 4; hh++) {
        f32x4 acc[4];
        #pragma unroll
        for (int mt = 0; mt < 4; mt++) acc[mt] = (f32x4){0.f, 0.f, 0.f, 0.f};
        #pragma unroll
        for (int ks = 0; ks < KSTEPS; ks++) {
            int c = ks * 4 + quad;
            bf16x8 afr[4];
            #pragma unroll
            for (int mt = 0; mt < 4; mt++) {
                int m = mt * 16 + l15;
                int slot = (c & ~7) | ((c ^ m) & 7);
                afr[mt] = *(const bf16x8*)(&inA[m * ROWDW + slot * 4]);
            }
            int n = hh * 128 + w * 16 + l15;
            size_t bidx = (((size_t)c << 9) + n) << 3;
            bf16x8 bh = *(const bf16x8*)(W1hi + bidx);
            #pragma unroll
            for (int mt = 0; mt < 4; mt++)
                acc[mt] = __builtin_amdgcn_mfma_f32_16x16x32_bf16(afr[mt], bh, acc[mt], 0, 0, 0);
            if (HASLO) {
                bf16x8 bl = *(const bf16x8*)(W1lo + bidx);
                #pragma unroll
                for (int mt = 0; mt < 4; mt++)
                    acc[mt] = __builtin_amdgcn_mfma_f32_16x16x32_bf16(afr[mt], bl, acc[mt], 0, 0, 0);
            }
        }
        __syncthreads();
        {
            int kh = w * 16 + l15;
            int c = kh >> 3;
            #pragma unroll
            for (int mt = 0; mt < 4; mt++) {
                #pragma unroll
                for (int r = 0; r < 4; r++) {
                    int m = mt * 16 + quad * 4 + r;
                    float s = silu_fast(acc[mt][r]);
                    int slot = (c & 8) | ((c ^ m) & 7);
                    hA[m * 128 + slot * 8 + (kh & 7)] = (u16)f2bfb(s);
                }
            }
        }
        __syncthreads();
        #pragma unroll
        for (int ks = 0; ks < 4; ks++) {
            int c = ks * 4 + quad;
            int m0 = mt2a * 16 + l15;
            int m1i = m0 + 16;
            int s0 = (c & 8) | ((c ^ m0) & 7);
            int s1 = (c & 8) | ((c ^ m1i) & 7);
            bf16x8 a0 = *(const bf16x8*)(&hA[m0 * 128 + s0 * 8]);
            bf16x8 a1 = *(const bf16x8*)(&hA[m1i * 128 + s1 * 8]);
            size_t bidx = (((size_t)(hh * 16 + c) << 6) + nt2 * 16 + l15) << 3;
            bf16x8 bh = *(const bf16x8*)(W2hi + bidx);
            acc2[0] = __builtin_amdgcn_mfma_f32_16x16x32_bf16(a0, bh, acc2[0], 0, 0, 0);
            acc2[1] = __builtin_amdgcn_mfma_f32_16x16x32_bf16(a1, bh, acc2[1], 0, 0, 0);
            bf16x8 bl = *(const bf16x8*)(W2lo + bidx);
            acc2[0] = __builtin_amdgcn_mfma_f32_16x16x32_bf16(a0, bl, acc2[0], 0, 0, 0);
            acc2[1] = __builtin_amdgcn_mfma_f32_16x16x32_bf16(a1, bl, acc2[1], 0, 0, 0);
        }
    }
    // read xprev (chunks 0..7 hold current-layer x) from LDS before epi overlay
    float xo[8];
    if (MODE) {
        int c = w;
        int slot = (c & ~7) | ((c ^ lane) & 7);
        #pragma unroll
        for (int i = 0; i < 4; i++) {
            u32 pv = inA[lane * ROWDW + slot * 4 + i];
            xo[2 * i]     = bfb2f(pv & 0xffffu);
            xo[2 * i + 1] = bfb2f(pv >> 16);
        }
    }
    __syncthreads();
    float* epi = (float*)inA;   // 64 x 65 fp32 overlay
    #pragma unroll
    for (int mi = 0; mi < 2; mi++) {
        #pragma unroll
        for (int r = 0; r < 4; r++) {
            int m = (mt2a + mi) * 16 + quad * 4 + r;
            int c = nt2 * 16 + l15;
            epi[c * 65 + m] = acc2[mi][r];
        }
    }
    __syncthreads();
    float env = envb[e];
    const float is2 = 0.70710678118654752f;
    #pragma unroll
    for (int i = 0; i < 8; i++) {
        int c = w * 8 + i;
        float v = epi[c * 65 + lane];
        float res;
        if (MODE) res = (xo[i] + v * env) * is2;
        else      res = v * env;
        xout[(size_t)c * E_NUM + e] = (u16)f2bfb(res);
        if (FUSEWE) epi[c * 65 + lane] = res;
    }
    if (FUSEWE) {
        __syncthreads();
        int mt = w & 3;
        int ntb = (w >> 2) * 2;
        f32x4 accw[2];
        accw[0] = (f32x4){0.f, 0.f, 0.f, 0.f};
        accw[1] = (f32x4){0.f, 0.f, 0.f, 0.f};
        #pragma unroll
        for (int ks = 0; ks < 2; ks++) {
            bf16x8 af;
            #pragma unroll
            for (int j = 0; j < 8; j++)
                af[j] = (short)f2bfb(epi[(ks * 32 + quad * 8 + j) * 65 + mt * 16 + l15]);
            #pragma unroll
            for (int nti = 0; nti < 2; nti++) {
                int n4 = (ntb + nti) * 16 + l15;
                size_t bidx = (((size_t)(ks * 4 + quad) << 6) + n4) << 3;
                bf16x8 bh = *(const bf16x8*)(wehi + bidx);
                accw[nti] = __builtin_amdgcn_mfma_f32_16x16x32_bf16(af, bh, accw[nti], 0, 0, 0);
                bf16x8 bl = *(const bf16x8*)(welo + bidx);
                accw[nti] = __builtin_amdgcn_mfma_f32_16x16x32_bf16(af, bl, accw[nti], 0, 0, 0);
            }
        }
        #pragma unroll
        for (int nti = 0; nti < 2; nti++) {
            #pragma unroll
            for (int r = 0; r < 4; r++) {
                int rowD = mt * 16 + quad * 4 + r;
                int colD = (ntb + nti) * 16 + l15;
                webuf[(size_t)(e0 + rowD) * 64 + colD] = accw[nti][r];
            }
        }
    }
}

// ---------------- readout ----------------
__global__ void k_readout(const u16* __restrict__ x, const float* __restrict__ Wout,
                          const float* __restrict__ envb, const int* __restrict__ srecv,
                          float* __restrict__ node_acc) {
    int e = blockIdx.x * 256 + threadIdx.x;
    if (e >= E_NUM) return;
    float a = 0.0f;
    #pragma unroll
    for (int c = 0; c < 64; c++) {
        a = fmaf(bfb2f((u32)x[(size_t)c * E_NUM + e]), Wout[c], a);
    }
    a *= envb[e] * (1.0f / 3.0f);
    atomicAdd(&node_acc[srecv[e]], a);
}

__global__ void k_out(const float* __restrict__ node_acc, void* __restrict__ out,
                      const int* __restrict__ flag) {
    int n = blockIdx.x * 256 + threadIdx.x;
    if (n >= NN) return;
    float v = node_acc[n];
    if (*flag) ((float*)out)[n] = v;
    else       ((u16*)out)[n] = (u16)f2bfb(v);
}

extern "C" void kernel_launch(void* const* d_in, const int* in_sizes, int n_in,
                              void* d_out, int out_size, void* d_ws, size_t ws_size,
                              hipStream_t stream) {
    const void* posr   = d_in[0];
    const void* Wemb1r = d_in[1];
    const void* Wemb2r = d_in[2];
    const void* Wvr    = d_in[3];
    const void* Wenvr  = d_in[4];
    const void* Wlat1r = d_in[5];
    const void* Wlat2r = d_in[6];
    const void* Wmixr  = d_in[7];
    const void* Woutr  = d_in[8];
    const int* species   = (const int*)d_in[9];
    const int* senders   = (const int*)d_in[10];
    const int* receivers = (const int*)d_in[11];

    char* p = (char*)d_ws;
    auto alloc = [&](size_t bytes) -> void* {
        void* rp = (void*)p;
        p += (bytes + 255) & ~(size_t)255;
        return rp;
    };
    int*   flag  = (int*)alloc(4);
    float* wbuf  = (float*)alloc(359792 * 4);
    float* posf  = wbuf;
    float* Wemb1 = wbuf + 30000;
    float* Wemb2 = wbuf + 36144;
    float* Wv    = wbuf + 68912;
    float* Wenv  = wbuf + 73008;
    float* Wlat1 = wbuf + 81200;
    float* Wlat2 = wbuf + 277808;
    float* Wmix  = wbuf + 343344;
    float* Wout  = wbuf + 359728;
    const size_t E = E_NUM;
    float* ux   = (float*)alloc(E * 4);
    float* uy   = (float*)alloc(E * 4);
    float* uz   = (float*)alloc(E * 4);
    float* envb = (float*)alloc(E * 4);
    float* rho0A = (float*)alloc((size_t)NN * 64 * 4);
    float* rho1A = (float*)alloc((size_t)NN * 192 * 4);
    float* rho0B = (float*)alloc((size_t)NN * 64 * 4);
    float* rho1B = (float*)alloc((size_t)NN * 192 * 4);
    float* node_acc = (float*)alloc((size_t)NN * 4);
    int* counts    = (int*)alloc((size_t)NN * 4);
    int* rowstart  = (int*)alloc((size_t)(NN + 1) * 4);
    int* cursor    = (int*)alloc((size_t)NN * 4);
    int* edge_list = (int*)alloc(E * 4);
    int* ssend     = (int*)alloc(E * 4);
    int* srecv     = (int*)alloc(E * 4);
    void* unionbuf = alloc(96 * E * 4);
    u32*   latin = (u32*)unionbuf;                      // emb input rows 0..31
    float* webuf = (float*)unionbuf + (size_t)32 * E;   // we region (rows 32..95)
    u16* x0 = (u16*)alloc(64 * E * 2);
    u16* x1 = (u16*)alloc(64 * E * 2);
    u16* w1hi = (u16*)alloc(2 * 98304 * 2);
    u16* w1lo = (u16*)alloc(2 * 98304 * 2);
    u16* w2hi = (u16*)alloc(2 * 32768 * 2);
    u16* w2lo = (u16*)alloc(2 * 32768 * 2);
    u16* e1hi = (u16*)alloc(32768 * 2);
    u16* e2hi = (u16*)alloc(32768 * 2);
    u16* e2lo = (u16*)alloc(32768 * 2);
    u16* we0hi = (u16*)alloc(4096 * 2);
    u16* we0lo = (u16*)alloc(4096 * 2);
    u16* we1hi = (u16*)alloc(4096 * 2);
    u16* we1lo = (u16*)alloc(4096 * 2);
    u16* wvhi  = (u16*)alloc(4096 * 2);
    u16* wvlo  = (u16*)alloc(4096 * 2);
    u16* wmhi  = (u16*)alloc(8192 * 2);   // Wmix layer 0 (64x128)
    u16* wmlo  = (u16*)alloc(8192 * 2);

    hipMemsetAsync(flag, 0, 4, stream);
    hipMemsetAsync(counts, 0, (size_t)NN * 4, stream);
    hipMemsetAsync(node_acc, 0, (size_t)NN * 4, stream);
    hipMemsetAsync(latin + (size_t)18 * E, 0, (size_t)14 * E * 4, stream);

    k_detect<<<(15000 + 255) / 256, 256, 0, stream>>>((const u16*)posr, flag);

    k_cvt_all<<<(359792 + 255) / 256, 256, 0, stream>>>(
        posr, Wemb1r, Wemb2r, Wvr, Wenvr, Wlat1r, Wlat2r, Wmixr, Woutr,
        wbuf, flag);

    k_pack_emb1<<<128, 256, 0, stream>>>(Wemb1, e1hi);
    k_pack<<<128, 256, 0, stream>>>(Wemb2, 512, 6, e2hi, e2lo);
    k_pack<<<16, 256, 0, stream>>>(Wenv, 64, 6, we0hi, we0lo);
    k_pack<<<16, 256, 0, stream>>>(Wenv + 4096, 64, 6, we1hi, we1lo);
    k_pack<<<16, 256, 0, stream>>>(Wv, 64, 6, wvhi, wvlo);
    k_pack<<<32, 256, 0, stream>>>(Wmix, 64, 7, wmhi, wmlo);
    for (int l = 0; l < 2; l++) {
        k_pack<<<384, 256, 0, stream>>>(Wlat1 + l * 98304, 192, 9,
                                        w1hi + l * 98304, w1lo + l * 98304);
        k_pack<<<128, 256, 0, stream>>>(Wlat2 + l * 32768, 512, 6,
                                        w2hi + l * 32768, w2lo + l * 32768);
    }

    // CSR over senders -> sorted edge order
    k_hist<<<625, 256, 0, stream>>>(senders, counts);
    k_scan<<<1, 1024, 0, stream>>>(counts, rowstart);
    k_copy_int<<<(NN + 255) / 256, 256, 0, stream>>>(rowstart, cursor, NN);
    k_fill<<<625, 256, 0, stream>>>(senders, cursor, edge_list);

    // embedding + fused layer-0 we
    k_geom<<<625, 256, 0, stream>>>(posf, species, senders, receivers, edge_list,
                                    ssend, srecv, ux, uy, uz, envb, latin);
    k_mlp<2, 0, 0, 1, 0><<<2500, 512, 0, stream>>>(
        latin, e1hi, nullptr, e2hi, e2lo, envb, x0, we0hi, we0lo, webuf,
        nullptr, nullptr, nullptr, nullptr, nullptr, nullptr,
        nullptr, nullptr, nullptr, nullptr, nullptr, nullptr, nullptr, nullptr);

    // layer 0 (fused stage, verified) + fused layer-1 we
    k_rho_gather<<<2500, 256, 0, stream>>>(webuf, rowstart, ux, uy, uz,
                                           rho0A, rho1A);
    k_mlp<6, 1, 1, 1, 1><<<2500, 512, 0, stream>>>(
        nullptr, w1hi, w1lo, w2hi, w2lo, envb, x1, we1hi, we1lo, webuf,
        x0, nullptr, ssend, ux, uy, uz, rho0A, rho1A, nullptr, nullptr,
        wvhi, wvlo, nullptr, nullptr);

    // layer 1 (fused stage, redesigned transposes)
    k_rho_gather<<<2500, 256, 0, stream>>>(webuf, rowstart, ux, uy, uz,
                                           rho0B, rho1B);
    k_mlp<6, 1, 1, 0, 2><<<2500, 512, 0, stream>>>(
        nullptr, w1hi + 98304, w1lo + 98304, w2hi + 32768, w2lo + 32768,
        envb, x1, nullptr, nullptr, nullptr,
        x1, x0, ssend, ux, uy, uz, rho0A, rho1A, rho0B, rho1B,
        wvhi, wvlo, wmhi, wmlo);

    k_readout<<<625, 256, 0, stream>>>(x1, Wout, envb, srecv, node_acc);
    k_out<<<(NN + 255) / 256, 256, 0, stream>>>(node_acc, d_out, flag);
}

// Round 18
// 531.358 us; speedup vs baseline: 1.2502x; 1.0064x over previous
//
#include <hip/hip_runtime.h>
#include <hip/hip_bf16.h>

#define E_NUM 160000
#define NN 10000
#define PI_F 3.14159265358979323846f

using u16 = unsigned short;
using u32 = unsigned int;
typedef short bf16x8 __attribute__((ext_vector_type(8)));
typedef float f32x4 __attribute__((ext_vector_type(4)));
typedef u32 u32x4 __attribute__((ext_vector_type(4)));

__device__ __forceinline__ float silu_fast(float z) {
    return z * __builtin_amdgcn_rcpf(1.0f + __expf(-z));
}
__device__ __forceinline__ float bfb2f(u32 bits16) {
    return __builtin_bit_cast(float, bits16 << 16);
}
__device__ __forceinline__ u32 f2bfb(float f) {
    return (u32)__builtin_bit_cast(u16, __float2bfloat16(f));
}
__device__ __forceinline__ u32 pack2(float lo, float hi) {
    return f2bfb(lo) | (f2bfb(hi) << 16);
}

// ---------------- dtype detection (inputs fp32 vs bf16) ----------------
__global__ void k_detect(const u16* __restrict__ posraw, int* __restrict__ flag) {
    int i = blockIdx.x * 256 + threadIdx.x;
    if (i >= 15000) return;
    float v = bfb2f((u32)posraw[2 * i]);
    if (!(fabsf(v) < 1e4f)) atomicOr(flag, 1);
}

// ---------------- fused dual-dtype ingest of all 9 fp tensors ----------------
__global__ void k_cvt_all(const void* s0, const void* s1, const void* s2,
                          const void* s3, const void* s4, const void* s5,
                          const void* s6, const void* s7, const void* s8,
                          float* __restrict__ dst, const int* __restrict__ flag) {
    int i = blockIdx.x * 256 + threadIdx.x;
    if (i >= 359792) return;
    const void* src; int off;
    if      (i < 30000)  { src = s0; off = i; }
    else if (i < 36144)  { src = s1; off = i - 30000; }
    else if (i < 68912)  { src = s2; off = i - 36144; }
    else if (i < 73008)  { src = s3; off = i - 68912; }
    else if (i < 81200)  { src = s4; off = i - 73008; }
    else if (i < 277808) { src = s5; off = i - 81200; }
    else if (i < 343344) { src = s6; off = i - 277808; }
    else if (i < 359728) { src = s7; off = i - 343344; }
    else                 { src = s8; off = i - 359728; }
    if (*flag) dst[i] = ((const float*)src)[off];
    else       dst[i] = bfb2f((u32)((const u16*)src)[off]);
}

// ---------------- weight packers: [K][N] fp32 -> B-frag layout hi/lo ----------------
__global__ void k_pack(const float* __restrict__ W, int K, int Nshift,
                       u16* __restrict__ hi, u16* __restrict__ lo) {
    int i = blockIdx.x * 256 + threadIdx.x;
    int total = K << Nshift;
    if (i >= total) return;
    int k = i >> Nshift, n = i & ((1 << Nshift) - 1);
    float w = W[i];
    u16 h = (u16)f2bfb(w);
    float r = w - bfb2f((u32)h);
    int idx = ((((k >> 3) << Nshift) + n) << 3) + (k & 7);
    hi[idx] = h; lo[idx] = (u16)f2bfb(r);
}

// emb W1: rows 0..11 = hi(W), 12..23 = hi(W), 24..35 = lo(W), 36..63 = 0
__global__ void k_pack_emb1(const float* __restrict__ W /*12x512*/, u16* __restrict__ pk) {
    int i = blockIdx.x * 256 + threadIdx.x;
    if (i >= 64 * 512) return;
    int k = i >> 9, n = i & 511;
    u16 out = 0;
    if (k < 24) {
        out = (u16)f2bfb(W[(k % 12) * 512 + n]);
    } else if (k < 36) {
        float w = W[(k - 24) * 512 + n];
        u16 h = (u16)f2bfb(w);
        out = (u16)f2bfb(w - bfb2f((u32)h));
    }
    pk[((((k >> 3) << 9) + n) << 3) + (k & 7)] = out;
}

// ---------------- CSR build ----------------
__global__ void k_hist(const int* __restrict__ senders, int* __restrict__ counts) {
    int e = blockIdx.x * 256 + threadIdx.x;
    if (e < E_NUM) atomicAdd(&counts[senders[e]], 1);
}

__global__ __launch_bounds__(1024) void k_scan(const int* __restrict__ counts,
                                               int* __restrict__ rowstart) {
    __shared__ int part[1024];
    int t = threadIdx.x;
    int base = t * 10;
    int local[10];
    int sum = 0;
    #pragma unroll
    for (int i = 0; i < 10; i++) {
        int v = (base + i < NN) ? counts[base + i] : 0;
        local[i] = sum; sum += v;
    }
    part[t] = sum;
    __syncthreads();
    for (int off = 1; off < 1024; off <<= 1) {
        int v = (t >= off) ? part[t - off] : 0;
        __syncthreads();
        part[t] += v;
        __syncthreads();
    }
    int pre = (t == 0) ? 0 : part[t - 1];
    #pragma unroll
    for (int i = 0; i < 10; i++)
        if (base + i < NN) rowstart[base + i] = pre + local[i];
    if (t == 1023) rowstart[NN] = part[1023];
}

__global__ void k_copy_int(const int* __restrict__ src, int* __restrict__ dst, int n) {
    int i = blockIdx.x * 256 + threadIdx.x;
    if (i < n) dst[i] = src[i];
}

__global__ void k_fill(const int* __restrict__ senders, int* __restrict__ cursor,
                       int* __restrict__ edge_list) {
    int e = blockIdx.x * 256 + threadIdx.x;
    if (e >= E_NUM) return;
    int pos = atomicAdd(&cursor[senders[e]], 1);
    edge_list[pos] = e;
}

// ---------------- geometry in SORTED edge space ----------------
__global__ void k_geom(const float* __restrict__ posf, const int* __restrict__ species,
                       const int* __restrict__ senders, const int* __restrict__ receivers,
                       const int* __restrict__ edge_list,
                       int* __restrict__ ssend, int* __restrict__ srecv,
                       float* __restrict__ ux, float* __restrict__ uy, float* __restrict__ uz,
                       float* __restrict__ envb, u32* __restrict__ latin) {
    int e = blockIdx.x * 256 + threadIdx.x;
    if (e >= E_NUM) return;
    int orig = edge_list[e];
    int s = senders[orig], r = receivers[orig];
    ssend[e] = s; srecv[e] = r;
    float rx = posf[3 * r + 0] - posf[3 * s + 0];
    float ry = posf[3 * r + 1] - posf[3 * s + 1];
    float rz = posf[3 * r + 2] - posf[3 * s + 2];
    float d = sqrtf(rx * rx + ry * ry + rz * rz);
    float inv = 1.0f / fmaxf(d, 1e-6f);
    ux[e] = rx * inv; uy[e] = ry * inv; uz[e] = rz * inv;
    float xc = d * 0.5f;
    float env = 0.0f;
    if (xc < 1.0f) { float t = 1.0f - xc * xc; env = t * t; }
    envb[e] = env;
    float ft[12];
    float se = env * inv;
    #pragma unroll
    for (int n = 1; n <= 8; n++) ft[n - 1] = __sinf((float)n * PI_F * xc) * se;
    int ss = species[s], sr = species[r];
    ft[8] = (ss == 0) ? 1.0f : 0.0f;
    ft[9] = (ss == 1) ? 1.0f : 0.0f;
    ft[10] = (sr == 0) ? 1.0f : 0.0f;
    ft[11] = (sr == 1) ? 1.0f : 0.0f;
    u32 fh[12]; float fl[12];
    #pragma unroll
    for (int i = 0; i < 12; i++) {
        fh[i] = f2bfb(ft[i]);
        fl[i] = ft[i] - bfb2f(fh[i]);
    }
    #pragma unroll
    for (int j = 0; j < 6; j++) {
        u32 v = fh[2 * j] | (fh[2 * j + 1] << 16);
        latin[(size_t)j * E_NUM + e] = v;
        latin[(size_t)(12 + j) * E_NUM + e] = v;
        latin[(size_t)(6 + j) * E_NUM + e] = pack2(fl[2 * j], fl[2 * j + 1]);
    }
}

// ---------------- rho gather ----------------
__global__ __launch_bounds__(256) void k_rho_gather(
    const float* __restrict__ we, const int* __restrict__ rowstart,
    const float* __restrict__ ux, const float* __restrict__ uy,
    const float* __restrict__ uz,
    float* __restrict__ rho0, float* __restrict__ rho1) {
    int wv = (blockIdx.x * 256 + threadIdx.x) >> 6;
    int c = threadIdx.x & 63;
    if (wv >= NN) return;
    int start = rowstart[wv], end = rowstart[wv + 1];
    float s0 = 0.0f, sx = 0.0f, sy = 0.0f, sz = 0.0f;
    for (int j = start; j < end; j++) {
        float w = we[(size_t)j * 64 + c];
        float a = ux[j], b = uy[j], g = uz[j];
        s0 += w;
        sx = fmaf(w, a, sx);
        sy = fmaf(w, b, sy);
        sz = fmaf(w, g, sz);
    }
    const float inv3 = 1.0f / 3.0f;
    rho0[(size_t)wv * 64 + c] = s0 * inv3;
    rho1[(size_t)wv * 192 + 3 * c + 0] = sx * inv3;
    rho1[(size_t)wv * 192 + 3 * c + 1] = sy * inv3;
    rho1[(size_t)wv * 192 + 3 * c + 2] = sz * inv3;
}

// =====================================================================
// MFMA MLP v10:
//  STAGE=0: input from latin (verified).
//  STAGE=1: fused lat0 (verified).
//  STAGE=2: fused lat1, m1/m2 transposed through ONE u16 buffer with
//   interleaved bf16 halves (waves 0-3 even slots, 4-7 odd) -> LDS
//   57856 B, back to 2 blocks/CU.
// =====================================================================
template<int KSTEPS, int MODE, int HASLO, int FUSEWE, int STAGE>
__global__ __launch_bounds__(512) void k_mlp(
    const u32* __restrict__ latin,
    const u16* __restrict__ W1hi, const u16* __restrict__ W1lo,
    const u16* __restrict__ W2hi, const u16* __restrict__ W2lo,
    const float* __restrict__ envb,
    u16* __restrict__ xout,
    const u16* __restrict__ wehi, const u16* __restrict__ welo,
    float* __restrict__ webuf,
    const u16* __restrict__ xin,
    const u16* __restrict__ x0t,
    const int* __restrict__ ssend,
    const float* __restrict__ ux, const float* __restrict__ uy,
    const float* __restrict__ uz,
    const float* __restrict__ rho0A, const float* __restrict__ rho1A,
    const float* __restrict__ rho0B, const float* __restrict__ rho1B,
    const u16* __restrict__ wvhi, const u16* __restrict__ wvlo,
    const u16* __restrict__ wmhi, const u16* __restrict__ wmlo) {
    constexpr int ROWDW = KSTEPS * 16;
    constexpr int INAREG = 24576;
    constexpr int SMEMSZ = (STAGE == 2) ? (INAREG + 2 * 16640) : (INAREG + 16640);
    __shared__ __align__(16) char smem[SMEMSZ];
    u32* inA = (u32*)smem;
    u16* hA  = (u16*)(smem + INAREG);           // 16 KB (phases)
    float* tbA = (float*)(smem + INAREG);       // 64x65 fp32 (a transpose)
    u16* mb   = (u16*)(smem + INAREG + 16640);  // m1/m2 interleaved bf16
    u32* mb32 = (u32*)(smem + INAREG + 16640);
    u32* xt0  = (u32*)(smem + INAREG + 16640);  // x0 tile (dies before mb writes)
    int lane = threadIdx.x & 63;
    int sub = threadIdx.x >> 6;
    int w = __builtin_amdgcn_readfirstlane(sub);
    int l15 = lane & 15, quad = lane >> 4;
    int e0 = blockIdx.x * 64;
    int e = e0 + lane;

    if (STAGE == 0) {
        constexpr int CPW = (KSTEPS * 4) / 8;
        #pragma unroll
        for (int j = 0; j < CPW; j++) {
            int c = w * CPW + j;
            u32x4 v;
            #pragma unroll
            for (int i = 0; i < 4; i++) v[i] = latin[(size_t)(c * 4 + i) * E_NUM + e];
            int slot = (c & ~7) | ((c ^ lane) & 7);
            *(u32x4*)(&inA[lane * ROWDW + slot * 4]) = v;
        }
        __syncthreads();
    } else {
        // stage xin chunks 0..7 -> inA
        {
            int c = w;
            u32x4 v;
            #pragma unroll
            for (int i = 0; i < 4; i++) {
                u32 lo = (u32)xin[(size_t)(8 * c + 2 * i) * E_NUM + e];
                u32 hi = (u32)xin[(size_t)(8 * c + 2 * i + 1) * E_NUM + e];
                v[i] = lo | (hi << 16);
            }
            int slot = (c & ~7) | ((c ^ lane) & 7);
            *(u32x4*)(&inA[lane * ROWDW + slot * 4]) = v;
        }
        if (STAGE == 2) {
            int c = w;
            u32x4 v;
            #pragma unroll
            for (int i = 0; i < 4; i++) {
                u32 lo = (u32)x0t[(size_t)(8 * c + 2 * i) * E_NUM + e];
                u32 hi = (u32)x0t[(size_t)(8 * c + 2 * i + 1) * E_NUM + e];
                v[i] = lo | (hi << 16);
            }
            int slot = (c ^ lane) & 7;
            *(u32x4*)(&xt0[lane * 32 + slot * 4]) = v;
        }
        __syncthreads();
        // mini-GEMM a = x0 @ Wv
        int mt = w & 3;
        int ntbA = (w >> 2) * 2;
        f32x4 accA[2];
        accA[0] = (f32x4){0.f, 0.f, 0.f, 0.f};
        accA[1] = (f32x4){0.f, 0.f, 0.f, 0.f};
        #pragma unroll
        for (int ks = 0; ks < 2; ks++) {
            int c = ks * 4 + quad;
            int m = mt * 16 + l15;
            bf16x8 af;
            if (STAGE == 1) {
                int slot = (c & ~7) | ((c ^ m) & 7);
                af = *(const bf16x8*)(&inA[m * ROWDW + slot * 4]);
            } else {
                int slot = (c ^ m) & 7;
                af = *(const bf16x8*)(&xt0[m * 32 + slot * 4]);
            }
            #pragma unroll
            for (int nti = 0; nti < 2; nti++) {
                int n = (ntbA + nti) * 16 + l15;
                size_t bidx = (((size_t)c << 6) + n) << 3;
                bf16x8 bh = *(const bf16x8*)(wvhi + bidx);
                accA[nti] = __builtin_amdgcn_mfma_f32_16x16x32_bf16(af, bh, accA[nti], 0, 0, 0);
                bf16x8 bl = *(const bf16x8*)(wvlo + bidx);
                accA[nti] = __builtin_amdgcn_mfma_f32_16x16x32_bf16(af, bl, accA[nti], 0, 0, 0);
            }
        }
        // mini-GEMM m = x1 @ Wmix (STAGE==2)
        f32x4 accM[4];
        if (STAGE == 2) {
            #pragma unroll
            for (int i = 0; i < 4; i++) accM[i] = (f32x4){0.f, 0.f, 0.f, 0.f};
            int nbM = (w >> 2) * 4;   // waves 0-3: m1 (cols 0..63); 4-7: m2 (cols 64..127)
            #pragma unroll
            for (int ks = 0; ks < 2; ks++) {
                int c = ks * 4 + quad;
                int m = mt * 16 + l15;
                int slot = (c & ~7) | ((c ^ m) & 7);
                bf16x8 af = *(const bf16x8*)(&inA[m * ROWDW + slot * 4]);
                #pragma unroll
                for (int nti = 0; nti < 4; nti++) {
                    int n = (nbM + nti) * 16 + l15;
                    size_t bidx = (((size_t)c << 7) + n) << 3;
                    bf16x8 bh = *(const bf16x8*)(wmhi + bidx);
                    accM[nti] = __builtin_amdgcn_mfma_f32_16x16x32_bf16(af, bh, accM[nti], 0, 0, 0);
                    bf16x8 bl = *(const bf16x8*)(wmlo + bidx);
                    accM[nti] = __builtin_amdgcn_mfma_f32_16x16x32_bf16(af, bl, accM[nti], 0, 0, 0);
                }
            }
        }
        __syncthreads();   // all GEMM LDS reads done (xt0 dead)
        // ---- single transpose round: a -> tbA (fp32), m1/m2 -> mb (bf16 halves)
        #pragma unroll
        for (int nti = 0; nti < 2; nti++) {
            #pragma unroll
            for (int r = 0; r < 4; r++) {
                int rowD = mt * 16 + quad * 4 + r;
                int colD = (ntbA + nti) * 16 + l15;
                tbA[colD * 65 + rowD] = accA[nti][r];
            }
        }
        if (STAGE == 2) {
            int sel = (w >= 4) ? 1 : 0;
            #pragma unroll
            for (int nti = 0; nti < 4; nti++) {
                #pragma unroll
                for (int r = 0; r < 4; r++) {
                    int rowD = mt * 16 + quad * 4 + r;
                    int colD = nti * 16 + l15;
                    mb[((colD * 65 + rowD) << 1) + sel] = (u16)f2bfb(accM[nti][r]);
                }
            }
        }
        __syncthreads();
        int c0 = w * 8;
        float av[8], m1v[8], m2v[8];
        #pragma unroll
        for (int i = 0; i < 8; i++) av[i] = tbA[(c0 + i) * 65 + lane];
        if (STAGE == 2) {
            #pragma unroll
            for (int i = 0; i < 8; i++) {
                u32 pv = mb32[(c0 + i) * 65 + lane];
                m1v[i] = bfb2f(pv & 0xffffu);
                m2v[i] = bfb2f(pv >> 16);
            }
        }
        // per-lane tp math + gathers
        int s = ssend[e];
        float u0 = ux[e], u1 = uy[e], u2 = uz[e];
        float ts[8], rr[8];
        if (STAGE == 1) {
            const float* r1 = rho1A + (size_t)s * 192;
            const float* r0 = rho0A + (size_t)s * 64;
            #pragma unroll
            for (int i = 0; i < 8; i++) {
                int c = c0 + i;
                float dot = u0 * r1[3 * c] + u1 * r1[3 * c + 1] + u2 * r1[3 * c + 2];
                ts[i] = av[i] * dot;
                rr[i] = r0[c];
            }
        } else {
            const float* r1A = rho1A + (size_t)s * 192;
            const float* r0A = rho0A + (size_t)s * 64;
            const float* r1B = rho1B + (size_t)s * 192;
            const float* r0B = rho0B + (size_t)s * 64;
            #pragma unroll
            for (int i = 0; i < 8; i++) {
                int c = c0 + i;
                float v0 = av[i] * u0, v1 = av[i] * u1, v2 = av[i] * u2;
                float aA0 = r1A[3 * c], aA1 = r1A[3 * c + 1], aA2 = r1A[3 * c + 2];
                float rc = r0A[c];
                float w0 = m1v[i] * v0 * rc + m2v[i] * (v1 * aA2 - v2 * aA1);
                float w1 = m1v[i] * v1 * rc + m2v[i] * (v2 * aA0 - v0 * aA2);
                float w2 = m1v[i] * v2 * rc + m2v[i] * (v0 * aA1 - v1 * aA0);
                ts[i] = w0 * r1B[3 * c] + w1 * r1B[3 * c + 1] + w2 * r1B[3 * c + 2];
                rr[i] = r0B[c];
            }
        }
        u32x4 tv, rv;
        #pragma unroll
        for (int j = 0; j < 4; j++) {
            tv[j] = pack2(ts[2 * j], ts[2 * j + 1]);
            rv[j] = pack2(rr[2 * j], rr[2 * j + 1]);
        }
        {
            int c = 8 + w;
            int slot = (c & ~7) | ((c ^ lane) & 7);
            *(u32x4*)(&inA[lane * ROWDW + slot * 4]) = tv;
        }
        {
            int c = 16 + w;
            int slot = (c & ~7) | ((c ^ lane) & 7);
            *(u32x4*)(&inA[lane * ROWDW + slot * 4]) = rv;
        }
        __syncthreads();
    }

    // ================= main MLP phases =================
    f32x4 acc2[2];
    acc2[0] = (f32x4){0.f, 0.f, 0.f, 0.f};
    acc2[1] = (f32x4){0.f, 0.f, 0.f, 0.f};
    int nt2 = w & 3;
    int mt2a = (w >> 2) * 2;

    #pragma unroll
    for (int hh = 0; hh < 4; hh++) {
        f32x4 acc[4];
        #pragma unroll
        for (int mt = 0; mt < 4; mt++) acc[mt] = (f32x4){0.f, 0.f, 0.f, 0.f};
        #pragma unroll
        for (int ks = 0; ks < KSTEPS; ks++) {
            int c = ks * 4 + quad;
            bf16x8 afr[4];
            #pragma unroll
            for (int mt = 0; mt < 4; mt++) {
                int m = mt * 16 + l15;
                int slot = (c & ~7) | ((c ^ m) & 7);
                afr[mt] = *(const bf16x8*)(&inA[m * ROWDW + slot * 4]);
            }
            int n = hh * 128 + w * 16 + l15;
            size_t bidx = (((size_t)c << 9) + n) << 3;
            bf16x8 bh = *(const bf16x8*)(W1hi + bidx);
            #pragma unroll
            for (int mt = 0; mt < 4; mt++)
                acc[mt] = __builtin_amdgcn_mfma_f32_16x16x32_bf16(afr[mt], bh, acc[mt], 0, 0, 0);
            if (HASLO) {
                bf16x8 bl = *(const bf16x8*)(W1lo + bidx);
                #pragma unroll
                for (int mt = 0; mt < 4; mt++)
                    acc[mt] = __builtin_amdgcn_mfma_f32_16x16x32_bf16(afr[mt], bl, acc[mt], 0, 0, 0);
            }
        }
        __syncthreads();
        {
            int kh = w * 16 + l15;
            int c = kh >> 3;
            #pragma unroll
            for (int mt = 0; mt < 4; mt++) {
                #pragma unroll
                for (int r = 0; r < 4; r++) {
                    int m = mt * 16 + quad * 4 + r;
                    float s = silu_fast(acc[mt][r]);
                    int slot = (c & 8) | ((c ^ m) & 7);
                    hA[m * 128 + slot * 8 + (kh & 7)] = (u16)f2bfb(s);
                }
            }
        }
        __syncthreads();
        #pragma unroll
        for (int ks = 0; ks < 4; ks++) {
            int c = ks * 4 + quad;
            int m0 = mt2a * 16 + l15;
            int m1i = m0 + 16;
            int s0 = (c & 8) | ((c ^ m0) & 7);
            int s1 = (c & 8) | ((c ^ m1i) & 7);
            bf16x8 a0 = *(const bf16x8*)(&hA[m0 * 128 + s0 * 8]);
            bf16x8 a1 = *(const bf16x8*)(&hA[m1i * 128 + s1 * 8]);
            size_t bidx = (((size_t)(hh * 16 + c) << 6) + nt2 * 16 + l15) << 3;
            bf16x8 bh = *(const bf16x8*)(W2hi + bidx);
            acc2[0] = __builtin_amdgcn_mfma_f32_16x16x32_bf16(a0, bh, acc2[0], 0, 0, 0);
            acc2[1] = __builtin_amdgcn_mfma_f32_16x16x32_bf16(a1, bh, acc2[1], 0, 0, 0);
            bf16x8 bl = *(const bf16x8*)(W2lo + bidx);
            acc2[0] = __builtin_amdgcn_mfma_f32_16x16x32_bf16(a0, bl, acc2[0], 0, 0, 0);
            acc2[1] = __builtin_amdgcn_mfma_f32_16x16x32_bf16(a1, bl, acc2[1], 0, 0, 0);
        }
    }
    // read xprev (chunks 0..7 hold current-layer x) from LDS before epi overlay
    float xo[8];
    if (MODE) {
        int c = w;
        int slot = (c & ~7) | ((c ^ lane) & 7);
        #pragma unroll
        for (int i = 0; i < 4; i++) {
            u32 pv = inA[lane * ROWDW + slot * 4 + i];
            xo[2 * i]     = bfb2f(pv & 0xffffu);
            xo[2 * i + 1] = bfb2f(pv >> 16);
        }
    }
    __syncthreads();
    float* epi = (float*)inA;   // 64 x 65 fp32 overlay
    #pragma unroll
    for (int mi = 0; mi < 2; mi++) {
        #pragma unroll
        for (int r = 0; r < 4; r++) {
            int m = (mt2a + mi) * 16 + quad * 4 + r;
            int c = nt2 * 16 + l15;
            epi[c * 65 + m] = acc2[mi][r];
        }
    }
    __syncthreads();
    float env = envb[e];
    const float is2 = 0.70710678118654752f;
    #pragma unroll
    for (int i = 0; i < 8; i++) {
        int c = w * 8 + i;
        float v = epi[c * 65 + lane];
        float res;
        if (MODE) res = (xo[i] + v * env) * is2;
        else      res = v * env;
        xout[(size_t)c * E_NUM + e] = (u16)f2bfb(res);
        if (FUSEWE) epi[c * 65 + lane] = res;
    }
    if (FUSEWE) {
        __syncthreads();
        int mt = w & 3;
        int ntb = (w >> 2) * 2;
        f32x4 accw[2];
        accw[0] = (f32x4){0.f, 0.f, 0.f, 0.f};
        accw[1] = (f32x4){0.f, 0.f, 0.f, 0.f};
        #pragma unroll
        for (int ks = 0; ks < 2; ks++) {
            bf16x8 af;
            #pragma unroll
            for (int j = 0; j < 8; j++)
                af[j] = (short)f2bfb(epi[(ks * 32 + quad * 8 + j) * 65 + mt * 16 + l15]);
            #pragma unroll
            for (int nti = 0; nti < 2; nti++) {
                int n4 = (ntb + nti) * 16 + l15;
                size_t bidx = (((size_t)(ks * 4 + quad) << 6) + n4) << 3;
                bf16x8 bh = *(const bf16x8*)(wehi + bidx);
                accw[nti] = __builtin_amdgcn_mfma_f32_16x16x32_bf16(af, bh, accw[nti], 0, 0, 0);
                bf16x8 bl = *(const bf16x8*)(welo + bidx);
                accw[nti] = __builtin_amdgcn_mfma_f32_16x16x32_bf16(af, bl, accw[nti], 0, 0, 0);
            }
        }
        #pragma unroll
        for (int nti = 0; nti < 2; nti++) {
            #pragma unroll
            for (int r = 0; r < 4; r++) {
                int rowD = mt * 16 + quad * 4 + r;
                int colD = (ntb + nti) * 16 + l15;
                webuf[(size_t)(e0 + rowD) * 64 + colD] = accw[nti][r];
            }
        }
    }
}

// ---------------- readout ----------------
__global__ void k_readout(const u16* __restrict__ x, const float* __restrict__ Wout,
                          const float* __restrict__ envb, const int* __restrict__ srecv,
                          float* __restrict__ node_acc) {
    int e = blockIdx.x * 256 + threadIdx.x;
    if (e >= E_NUM) return;
    float a = 0.0f;
    #pragma unroll
    for (int c = 0; c < 64; c++) {
        a = fmaf(bfb2f((u32)x[(size_t)c * E_NUM + e]), Wout[c], a);
    }
    a *= envb[e] * (1.0f / 3.0f);
    atomicAdd(&node_acc[srecv[e]], a);
}

__global__ void k_out(const float* __restrict__ node_acc, void* __restrict__ out,
                      const int* __restrict__ flag) {
    int n = blockIdx.x * 256 + threadIdx.x;
    if (n >= NN) return;
    float v = node_acc[n];
    if (*flag) ((float*)out)[n] = v;
    else       ((u16*)out)[n] = (u16)f2bfb(v);
}

extern "C" void kernel_launch(void* const* d_in, const int* in_sizes, int n_in,
                              void* d_out, int out_size, void* d_ws, size_t ws_size,
                              hipStream_t stream) {
    const void* posr   = d_in[0];
    const void* Wemb1r = d_in[1];
    const void* Wemb2r = d_in[2];
    const void* Wvr    = d_in[3];
    const void* Wenvr  = d_in[4];
    const void* Wlat1r = d_in[5];
    const void* Wlat2r = d_in[6];
    const void* Wmixr  = d_in[7];
    const void* Woutr  = d_in[8];
    const int* species   = (const int*)d_in[9];
    const int* senders   = (const int*)d_in[10];
    const int* receivers = (const int*)d_in[11];

    char* p = (char*)d_ws;
    auto alloc = [&](size_t bytes) -> void* {
        void* rp = (void*)p;
        p += (bytes + 255) & ~(size_t)255;
        return rp;
    };
    int*   flag  = (int*)alloc(4);
    float* wbuf  = (float*)alloc(359792 * 4);
    float* posf  = wbuf;
    float* Wemb1 = wbuf + 30000;
    float* Wemb2 = wbuf + 36144;
    float* Wv    = wbuf + 68912;
    float* Wenv  = wbuf + 73008;
    float* Wlat1 = wbuf + 81200;
    float* Wlat2 = wbuf + 277808;
    float* Wmix  = wbuf + 343344;
    float* Wout  = wbuf + 359728;
    const size_t E = E_NUM;
    float* ux   = (float*)alloc(E * 4);
    float* uy   = (float*)alloc(E * 4);
    float* uz   = (float*)alloc(E * 4);
    float* envb = (float*)alloc(E * 4);
    float* rho0A = (float*)alloc((size_t)NN * 64 * 4);
    float* rho1A = (float*)alloc((size_t)NN * 192 * 4);
    float* rho0B = (float*)alloc((size_t)NN * 64 * 4);
    float* rho1B = (float*)alloc((size_t)NN * 192 * 4);
    float* node_acc = (float*)alloc((size_t)NN * 4);
    int* counts    = (int*)alloc((size_t)NN * 4);
    int* rowstart  = (int*)alloc((size_t)(NN + 1) * 4);
    int* cursor    = (int*)alloc((size_t)NN * 4);
    int* edge_list = (int*)alloc(E * 4);
    int* ssend     = (int*)alloc(E * 4);
    int* srecv     = (int*)alloc(E * 4);
    void* unionbuf = alloc(96 * E * 4);
    u32*   latin = (u32*)unionbuf;                      // emb input rows 0..31
    float* webuf = (float*)unionbuf + (size_t)32 * E;   // we region (rows 32..95)
    u16* x0 = (u16*)alloc(64 * E * 2);
    u16* x1 = (u16*)alloc(64 * E * 2);
    u16* w1hi = (u16*)alloc(2 * 98304 * 2);
    u16* w1lo = (u16*)alloc(2 * 98304 * 2);
    u16* w2hi = (u16*)alloc(2 * 32768 * 2);
    u16* w2lo = (u16*)alloc(2 * 32768 * 2);
    u16* e1hi = (u16*)alloc(32768 * 2);
    u16* e2hi = (u16*)alloc(32768 * 2);
    u16* e2lo = (u16*)alloc(32768 * 2);
    u16* we0hi = (u16*)alloc(4096 * 2);
    u16* we0lo = (u16*)alloc(4096 * 2);
    u16* we1hi = (u16*)alloc(4096 * 2);
    u16* we1lo = (u16*)alloc(4096 * 2);
    u16* wvhi  = (u16*)alloc(4096 * 2);
    u16* wvlo  = (u16*)alloc(4096 * 2);
    u16* wmhi  = (u16*)alloc(8192 * 2);   // Wmix layer 0 (64x128)
    u16* wmlo  = (u16*)alloc(8192 * 2);

    hipMemsetAsync(flag, 0, 4, stream);
    hipMemsetAsync(counts, 0, (size_t)NN * 4, stream);
    hipMemsetAsync(node_acc, 0, (size_t)NN * 4, stream);
    hipMemsetAsync(latin + (size_t)18 * E, 0, (size_t)14 * E * 4, stream);

    k_detect<<<(15000 + 255) / 256, 256, 0, stream>>>((const u16*)posr, flag);

    k_cvt_all<<<(359792 + 255) / 256, 256, 0, stream>>>(
        posr, Wemb1r, Wemb2r, Wvr, Wenvr, Wlat1r, Wlat2r, Wmixr, Woutr,
        wbuf, flag);

    k_pack_emb1<<<128, 256, 0, stream>>>(Wemb1, e1hi);
    k_pack<<<128, 256, 0, stream>>>(Wemb2, 512, 6, e2hi, e2lo);
    k_pack<<<16, 256, 0, stream>>>(Wenv, 64, 6, we0hi, we0lo);
    k_pack<<<16, 256, 0, stream>>>(Wenv + 4096, 64, 6, we1hi, we1lo);
    k_pack<<<16, 256, 0, stream>>>(Wv, 64, 6, wvhi, wvlo);
    k_pack<<<32, 256, 0, stream>>>(Wmix, 64, 7, wmhi, wmlo);
    for (int l = 0; l < 2; l++) {
        k_pack<<<384, 256, 0, stream>>>(Wlat1 + l * 98304, 192, 9,
                                        w1hi + l * 98304, w1lo + l * 98304);
        k_pack<<<128, 256, 0, stream>>>(Wlat2 + l * 32768, 512, 6,
                                        w2hi + l * 32768, w2lo + l * 32768);
    }

    // CSR over senders -> sorted edge order
    k_hist<<<625, 256, 0, stream>>>(senders, counts);
    k_scan<<<1, 1024, 0, stream>>>(counts, rowstart);
    k_copy_int<<<(NN + 255) / 256, 256, 0, stream>>>(rowstart, cursor, NN);
    k_fill<<<625, 256, 0, stream>>>(senders, cursor, edge_list);

    // embedding + fused layer-0 we
    k_geom<<<625, 256, 0, stream>>>(posf, species, senders, receivers, edge_list,
                                    ssend, srecv, ux, uy, uz, envb, latin);
    k_mlp<2, 0, 0, 1, 0><<<2500, 512, 0, stream>>>(
        latin, e1hi, nullptr, e2hi, e2lo, envb, x0, we0hi, we0lo, webuf,
        nullptr, nullptr, nullptr, nullptr, nullptr, nullptr,
        nullptr, nullptr, nullptr, nullptr, nullptr, nullptr, nullptr, nullptr);

    // layer 0 (fused stage, verified) + fused layer-1 we
    k_rho_gather<<<2500, 256, 0, stream>>>(webuf, rowstart, ux, uy, uz,
                                           rho0A, rho1A);
    k_mlp<6, 1, 1, 1, 1><<<2500, 512, 0, stream>>>(
        nullptr, w1hi, w1lo, w2hi, w2lo, envb, x1, we1hi, we1lo, webuf,
        x0, nullptr, ssend, ux, uy, uz, rho0A, rho1A, nullptr, nullptr,
        wvhi, wvlo, nullptr, nullptr);

    // layer 1 (fused stage, compact m transpose)
    k_rho_gather<<<2500, 256, 0, stream>>>(webuf, rowstart, ux, uy, uz,
                                           rho0B, rho1B);
    k_mlp<6, 1, 1, 0, 2><<<2500, 512, 0, stream>>>(
        nullptr, w1hi + 98304, w1lo + 98304, w2hi + 32768, w2lo + 32768,
        envb, x1, nullptr, nullptr, nullptr,
        x1, x0, ssend, ux, uy, uz, rho0A, rho1A, rho0B, rho1B,
        wvhi, wvlo, wmhi, wmlo);

    k_readout<<<625, 256, 0, stream>>>(x1, Wout, envb, srecv, node_acc);
    k_out<<<(NN + 255) / 256, 256, 0, stream>>>(node_acc, d_out, flag);
}

// Round 19
// 497.807 us; speedup vs baseline: 1.3344x; 1.0674x over previous
//
#include <hip/hip_runtime.h>
#include <hip/hip_bf16.h>

#define E_NUM 160000
#define NN 10000
#define PI_F 3.14159265358979323846f

using u16 = unsigned short;
using u32 = unsigned int;
typedef short bf16x8 __attribute__((ext_vector_type(8)));
typedef float f32x4 __attribute__((ext_vector_type(4)));
typedef u32 u32x4 __attribute__((ext_vector_type(4)));

__device__ __forceinline__ float silu_fast(float z) {
    return z * __builtin_amdgcn_rcpf(1.0f + __expf(-z));
}
__device__ __forceinline__ float bfb2f(u32 bits16) {
    return __builtin_bit_cast(float, bits16 << 16);
}
__device__ __forceinline__ u32 f2bfb(float f) {
    return (u32)__builtin_bit_cast(u16, __float2bfloat16(f));
}
__device__ __forceinline__ u32 pack2(float lo, float hi) {
    return f2bfb(lo) | (f2bfb(hi) << 16);
}

// ---------------- dtype detection (inputs fp32 vs bf16) ----------------
__global__ void k_detect(const u16* __restrict__ posraw, int* __restrict__ flag) {
    int i = blockIdx.x * 256 + threadIdx.x;
    if (i >= 15000) return;
    float v = bfb2f((u32)posraw[2 * i]);
    if (!(fabsf(v) < 1e4f)) atomicOr(flag, 1);
}

// ---------------- fused dual-dtype ingest of all 9 fp tensors ----------------
__global__ void k_cvt_all(const void* s0, const void* s1, const void* s2,
                          const void* s3, const void* s4, const void* s5,
                          const void* s6, const void* s7, const void* s8,
                          float* __restrict__ dst, const int* __restrict__ flag) {
    int i = blockIdx.x * 256 + threadIdx.x;
    if (i >= 359792) return;
    const void* src; int off;
    if      (i < 30000)  { src = s0; off = i; }
    else if (i < 36144)  { src = s1; off = i - 30000; }
    else if (i < 68912)  { src = s2; off = i - 36144; }
    else if (i < 73008)  { src = s3; off = i - 68912; }
    else if (i < 81200)  { src = s4; off = i - 73008; }
    else if (i < 277808) { src = s5; off = i - 81200; }
    else if (i < 343344) { src = s6; off = i - 277808; }
    else if (i < 359728) { src = s7; off = i - 343344; }
    else                 { src = s8; off = i - 359728; }
    if (*flag) dst[i] = ((const float*)src)[off];
    else       dst[i] = bfb2f((u32)((const u16*)src)[off]);
}

// ---------------- weight packers: [K][N] fp32 -> B-frag layout hi/lo ----------------
__global__ void k_pack(const float* __restrict__ W, int K, int Nshift,
                       u16* __restrict__ hi, u16* __restrict__ lo) {
    int i = blockIdx.x * 256 + threadIdx.x;
    int total = K << Nshift;
    if (i >= total) return;
    int k = i >> Nshift, n = i & ((1 << Nshift) - 1);
    float w = W[i];
    u16 h = (u16)f2bfb(w);
    float r = w - bfb2f((u32)h);
    int idx = ((((k >> 3) << Nshift) + n) << 3) + (k & 7);
    hi[idx] = h; lo[idx] = (u16)f2bfb(r);
}

// emb W1: rows 0..11 = hi(W), 12..23 = hi(W), 24..35 = lo(W), 36..63 = 0
__global__ void k_pack_emb1(const float* __restrict__ W /*12x512*/, u16* __restrict__ pk) {
    int i = blockIdx.x * 256 + threadIdx.x;
    if (i >= 64 * 512) return;
    int k = i >> 9, n = i & 511;
    u16 out = 0;
    if (k < 24) {
        out = (u16)f2bfb(W[(k % 12) * 512 + n]);
    } else if (k < 36) {
        float w = W[(k - 24) * 512 + n];
        u16 h = (u16)f2bfb(w);
        out = (u16)f2bfb(w - bfb2f((u32)h));
    }
    pk[((((k >> 3) << 9) + n) << 3) + (k & 7)] = out;
}

// ---------------- CSR build ----------------
__global__ void k_hist(const int* __restrict__ senders, int* __restrict__ counts) {
    int e = blockIdx.x * 256 + threadIdx.x;
    if (e < E_NUM) atomicAdd(&counts[senders[e]], 1);
}

__global__ __launch_bounds__(1024) void k_scan(const int* __restrict__ counts,
                                               int* __restrict__ rowstart) {
    __shared__ int part[1024];
    int t = threadIdx.x;
    int base = t * 10;
    int local[10];
    int sum = 0;
    #pragma unroll
    for (int i = 0; i < 10; i++) {
        int v = (base + i < NN) ? counts[base + i] : 0;
        local[i] = sum; sum += v;
    }
    part[t] = sum;
    __syncthreads();
    for (int off = 1; off < 1024; off <<= 1) {
        int v = (t >= off) ? part[t - off] : 0;
        __syncthreads();
        part[t] += v;
        __syncthreads();
    }
    int pre = (t == 0) ? 0 : part[t - 1];
    #pragma unroll
    for (int i = 0; i < 10; i++)
        if (base + i < NN) rowstart[base + i] = pre + local[i];
    if (t == 1023) rowstart[NN] = part[1023];
}

__global__ void k_copy_int(const int* __restrict__ src, int* __restrict__ dst, int n) {
    int i = blockIdx.x * 256 + threadIdx.x;
    if (i < n) dst[i] = src[i];
}

__global__ void k_fill(const int* __restrict__ senders, int* __restrict__ cursor,
                       int* __restrict__ edge_list) {
    int e = blockIdx.x * 256 + threadIdx.x;
    if (e >= E_NUM) return;
    int pos = atomicAdd(&cursor[senders[e]], 1);
    edge_list[pos] = e;
}

// ---------------- geometry in SORTED edge space ----------------
__global__ void k_geom(const float* __restrict__ posf, const int* __restrict__ species,
                       const int* __restrict__ senders, const int* __restrict__ receivers,
                       const int* __restrict__ edge_list,
                       int* __restrict__ ssend, int* __restrict__ srecv,
                       float* __restrict__ ux, float* __restrict__ uy, float* __restrict__ uz,
                       float* __restrict__ envb, u32* __restrict__ latin) {
    int e = blockIdx.x * 256 + threadIdx.x;
    if (e >= E_NUM) return;
    int orig = edge_list[e];
    int s = senders[orig], r = receivers[orig];
    ssend[e] = s; srecv[e] = r;
    float rx = posf[3 * r + 0] - posf[3 * s + 0];
    float ry = posf[3 * r + 1] - posf[3 * s + 1];
    float rz = posf[3 * r + 2] - posf[3 * s + 2];
    float d = sqrtf(rx * rx + ry * ry + rz * rz);
    float inv = 1.0f / fmaxf(d, 1e-6f);
    ux[e] = rx * inv; uy[e] = ry * inv; uz[e] = rz * inv;
    float xc = d * 0.5f;
    float env = 0.0f;
    if (xc < 1.0f) { float t = 1.0f - xc * xc; env = t * t; }
    envb[e] = env;
    float ft[12];
    float se = env * inv;
    #pragma unroll
    for (int n = 1; n <= 8; n++) ft[n - 1] = __sinf((float)n * PI_F * xc) * se;
    int ss = species[s], sr = species[r];
    ft[8] = (ss == 0) ? 1.0f : 0.0f;
    ft[9] = (ss == 1) ? 1.0f : 0.0f;
    ft[10] = (sr == 0) ? 1.0f : 0.0f;
    ft[11] = (sr == 1) ? 1.0f : 0.0f;
    u32 fh[12]; float fl[12];
    #pragma unroll
    for (int i = 0; i < 12; i++) {
        fh[i] = f2bfb(ft[i]);
        fl[i] = ft[i] - bfb2f(fh[i]);
    }
    #pragma unroll
    for (int j = 0; j < 6; j++) {
        u32 v = fh[2 * j] | (fh[2 * j + 1] << 16);
        latin[(size_t)j * E_NUM + e] = v;
        latin[(size_t)(12 + j) * E_NUM + e] = v;
        latin[(size_t)(6 + j) * E_NUM + e] = pack2(fl[2 * j], fl[2 * j + 1]);
    }
}

// ---------------- rho gather ----------------
__global__ __launch_bounds__(256) void k_rho_gather(
    const float* __restrict__ we, const int* __restrict__ rowstart,
    const float* __restrict__ ux, const float* __restrict__ uy,
    const float* __restrict__ uz,
    float* __restrict__ rho0, float* __restrict__ rho1) {
    int wv = (blockIdx.x * 256 + threadIdx.x) >> 6;
    int c = threadIdx.x & 63;
    if (wv >= NN) return;
    int start = rowstart[wv], end = rowstart[wv + 1];
    float s0 = 0.0f, sx = 0.0f, sy = 0.0f, sz = 0.0f;
    for (int j = start; j < end; j++) {
        float w = we[(size_t)j * 64 + c];
        float a = ux[j], b = uy[j], g = uz[j];
        s0 += w;
        sx = fmaf(w, a, sx);
        sy = fmaf(w, b, sy);
        sz = fmaf(w, g, sz);
    }
    const float inv3 = 1.0f / 3.0f;
    rho0[(size_t)wv * 64 + c] = s0 * inv3;
    rho1[(size_t)wv * 192 + 3 * c + 0] = sx * inv3;
    rho1[(size_t)wv * 192 + 3 * c + 1] = sy * inv3;
    rho1[(size_t)wv * 192 + 3 * c + 2] = sz * inv3;
}

// =====================================================================
// MFMA MLP v11: identical to v10 but with __launch_bounds__(512, 4) to
// cap unified VGPR/AGPR allocation at 128/wave -> 2 blocks/CU.
// =====================================================================
template<int KSTEPS, int MODE, int HASLO, int FUSEWE, int STAGE>
__global__ __launch_bounds__(512, 4) void k_mlp(
    const u32* __restrict__ latin,
    const u16* __restrict__ W1hi, const u16* __restrict__ W1lo,
    const u16* __restrict__ W2hi, const u16* __restrict__ W2lo,
    const float* __restrict__ envb,
    u16* __restrict__ xout,
    const u16* __restrict__ wehi, const u16* __restrict__ welo,
    float* __restrict__ webuf,
    const u16* __restrict__ xin,
    const u16* __restrict__ x0t,
    const int* __restrict__ ssend,
    const float* __restrict__ ux, const float* __restrict__ uy,
    const float* __restrict__ uz,
    const float* __restrict__ rho0A, const float* __restrict__ rho1A,
    const float* __restrict__ rho0B, const float* __restrict__ rho1B,
    const u16* __restrict__ wvhi, const u16* __restrict__ wvlo,
    const u16* __restrict__ wmhi, const u16* __restrict__ wmlo) {
    constexpr int ROWDW = KSTEPS * 16;
    constexpr int INAREG = 24576;
    constexpr int SMEMSZ = (STAGE == 2) ? (INAREG + 2 * 16640) : (INAREG + 16640);
    __shared__ __align__(16) char smem[SMEMSZ];
    u32* inA = (u32*)smem;
    u16* hA  = (u16*)(smem + INAREG);           // 16 KB (phases)
    float* tbA = (float*)(smem + INAREG);       // 64x65 fp32 (a transpose)
    u16* mb   = (u16*)(smem + INAREG + 16640);  // m1/m2 interleaved bf16
    u32* mb32 = (u32*)(smem + INAREG + 16640);
    u32* xt0  = (u32*)(smem + INAREG + 16640);  // x0 tile (dies before mb writes)
    int lane = threadIdx.x & 63;
    int sub = threadIdx.x >> 6;
    int w = __builtin_amdgcn_readfirstlane(sub);
    int l15 = lane & 15, quad = lane >> 4;
    int e0 = blockIdx.x * 64;
    int e = e0 + lane;

    if (STAGE == 0) {
        constexpr int CPW = (KSTEPS * 4) / 8;
        #pragma unroll
        for (int j = 0; j < CPW; j++) {
            int c = w * CPW + j;
            u32x4 v;
            #pragma unroll
            for (int i = 0; i < 4; i++) v[i] = latin[(size_t)(c * 4 + i) * E_NUM + e];
            int slot = (c & ~7) | ((c ^ lane) & 7);
            *(u32x4*)(&inA[lane * ROWDW + slot * 4]) = v;
        }
        __syncthreads();
    } else {
        // stage xin chunks 0..7 -> inA
        {
            int c = w;
            u32x4 v;
            #pragma unroll
            for (int i = 0; i < 4; i++) {
                u32 lo = (u32)xin[(size_t)(8 * c + 2 * i) * E_NUM + e];
                u32 hi = (u32)xin[(size_t)(8 * c + 2 * i + 1) * E_NUM + e];
                v[i] = lo | (hi << 16);
            }
            int slot = (c & ~7) | ((c ^ lane) & 7);
            *(u32x4*)(&inA[lane * ROWDW + slot * 4]) = v;
        }
        if (STAGE == 2) {
            int c = w;
            u32x4 v;
            #pragma unroll
            for (int i = 0; i < 4; i++) {
                u32 lo = (u32)x0t[(size_t)(8 * c + 2 * i) * E_NUM + e];
                u32 hi = (u32)x0t[(size_t)(8 * c + 2 * i + 1) * E_NUM + e];
                v[i] = lo | (hi << 16);
            }
            int slot = (c ^ lane) & 7;
            *(u32x4*)(&xt0[lane * 32 + slot * 4]) = v;
        }
        __syncthreads();
        // mini-GEMM a = x0 @ Wv
        int mt = w & 3;
        int ntbA = (w >> 2) * 2;
        f32x4 accA[2];
        accA[0] = (f32x4){0.f, 0.f, 0.f, 0.f};
        accA[1] = (f32x4){0.f, 0.f, 0.f, 0.f};
        #pragma unroll
        for (int ks = 0; ks < 2; ks++) {
            int c = ks * 4 + quad;
            int m = mt * 16 + l15;
            bf16x8 af;
            if (STAGE == 1) {
                int slot = (c & ~7) | ((c ^ m) & 7);
                af = *(const bf16x8*)(&inA[m * ROWDW + slot * 4]);
            } else {
                int slot = (c ^ m) & 7;
                af = *(const bf16x8*)(&xt0[m * 32 + slot * 4]);
            }
            #pragma unroll
            for (int nti = 0; nti < 2; nti++) {
                int n = (ntbA + nti) * 16 + l15;
                size_t bidx = (((size_t)c << 6) + n) << 3;
                bf16x8 bh = *(const bf16x8*)(wvhi + bidx);
                accA[nti] = __builtin_amdgcn_mfma_f32_16x16x32_bf16(af, bh, accA[nti], 0, 0, 0);
                bf16x8 bl = *(const bf16x8*)(wvlo + bidx);
                accA[nti] = __builtin_amdgcn_mfma_f32_16x16x32_bf16(af, bl, accA[nti], 0, 0, 0);
            }
        }
        // mini-GEMM m = x1 @ Wmix (STAGE==2)
        f32x4 accM[4];
        if (STAGE == 2) {
            #pragma unroll
            for (int i = 0; i < 4; i++) accM[i] = (f32x4){0.f, 0.f, 0.f, 0.f};
            int nbM = (w >> 2) * 4;
            #pragma unroll
            for (int ks = 0; ks < 2; ks++) {
                int c = ks * 4 + quad;
                int m = mt * 16 + l15;
                int slot = (c & ~7) | ((c ^ m) & 7);
                bf16x8 af = *(const bf16x8*)(&inA[m * ROWDW + slot * 4]);
                #pragma unroll
                for (int nti = 0; nti < 4; nti++) {
                    int n = (nbM + nti) * 16 + l15;
                    size_t bidx = (((size_t)c << 7) + n) << 3;
                    bf16x8 bh = *(const bf16x8*)(wmhi + bidx);
                    accM[nti] = __builtin_amdgcn_mfma_f32_16x16x32_bf16(af, bh, accM[nti], 0, 0, 0);
                    bf16x8 bl = *(const bf16x8*)(wmlo + bidx);
                    accM[nti] = __builtin_amdgcn_mfma_f32_16x16x32_bf16(af, bl, accM[nti], 0, 0, 0);
                }
            }
        }
        __syncthreads();   // all GEMM LDS reads done (xt0 dead)
        // ---- single transpose round: a -> tbA (fp32), m1/m2 -> mb (bf16 halves)
        #pragma unroll
        for (int nti = 0; nti < 2; nti++) {
            #pragma unroll
            for (int r = 0; r < 4; r++) {
                int rowD = mt * 16 + quad * 4 + r;
                int colD = (ntbA + nti) * 16 + l15;
                tbA[colD * 65 + rowD] = accA[nti][r];
            }
        }
        if (STAGE == 2) {
            int sel = (w >= 4) ? 1 : 0;
            #pragma unroll
            for (int nti = 0; nti < 4; nti++) {
                #pragma unroll
                for (int r = 0; r < 4; r++) {
                    int rowD = mt * 16 + quad * 4 + r;
                    int colD = nti * 16 + l15;
                    mb[((colD * 65 + rowD) << 1) + sel] = (u16)f2bfb(accM[nti][r]);
                }
            }
        }
        __syncthreads();
        int c0 = w * 8;
        float av[8], m1v[8], m2v[8];
        #pragma unroll
        for (int i = 0; i < 8; i++) av[i] = tbA[(c0 + i) * 65 + lane];
        if (STAGE == 2) {
            #pragma unroll
            for (int i = 0; i < 8; i++) {
                u32 pv = mb32[(c0 + i) * 65 + lane];
                m1v[i] = bfb2f(pv & 0xffffu);
                m2v[i] = bfb2f(pv >> 16);
            }
        }
        // per-lane tp math + gathers
        int s = ssend[e];
        float u0 = ux[e], u1 = uy[e], u2 = uz[e];
        float ts[8], rr[8];
        if (STAGE == 1) {
            const float* r1 = rho1A + (size_t)s * 192;
            const float* r0 = rho0A + (size_t)s * 64;
            #pragma unroll
            for (int i = 0; i < 8; i++) {
                int c = c0 + i;
                float dot = u0 * r1[3 * c] + u1 * r1[3 * c + 1] + u2 * r1[3 * c + 2];
                ts[i] = av[i] * dot;
                rr[i] = r0[c];
            }
        } else {
            const float* r1A = rho1A + (size_t)s * 192;
            const float* r0A = rho0A + (size_t)s * 64;
            const float* r1B = rho1B + (size_t)s * 192;
            const float* r0B = rho0B + (size_t)s * 64;
            #pragma unroll
            for (int i = 0; i < 8; i++) {
                int c = c0 + i;
                float v0 = av[i] * u0, v1 = av[i] * u1, v2 = av[i] * u2;
                float aA0 = r1A[3 * c], aA1 = r1A[3 * c + 1], aA2 = r1A[3 * c + 2];
                float rc = r0A[c];
                float w0 = m1v[i] * v0 * rc + m2v[i] * (v1 * aA2 - v2 * aA1);
                float w1 = m1v[i] * v1 * rc + m2v[i] * (v2 * aA0 - v0 * aA2);
                float w2 = m1v[i] * v2 * rc + m2v[i] * (v0 * aA1 - v1 * aA0);
                ts[i] = w0 * r1B[3 * c] + w1 * r1B[3 * c + 1] + w2 * r1B[3 * c + 2];
                rr[i] = r0B[c];
            }
        }
        u32x4 tv, rv;
        #pragma unroll
        for (int j = 0; j < 4; j++) {
            tv[j] = pack2(ts[2 * j], ts[2 * j + 1]);
            rv[j] = pack2(rr[2 * j], rr[2 * j + 1]);
        }
        {
            int c = 8 + w;
            int slot = (c & ~7) | ((c ^ lane) & 7);
            *(u32x4*)(&inA[lane * ROWDW + slot * 4]) = tv;
        }
        {
            int c = 16 + w;
            int slot = (c & ~7) | ((c ^ lane) & 7);
            *(u32x4*)(&inA[lane * ROWDW + slot * 4]) = rv;
        }
        __syncthreads();
    }

    // ================= main MLP phases =================
    f32x4 acc2[2];
    acc2[0] = (f32x4){0.f, 0.f, 0.f, 0.f};
    acc2[1] = (f32x4){0.f, 0.f, 0.f, 0.f};
    int nt2 = w & 3;
    int mt2a = (w >> 2) * 2;

    #pragma unroll
    for (int hh = 0; hh < 4; hh++) {
        f32x4 acc[4];
        #pragma unroll
        for (int mt = 0; mt < 4; mt++) acc[mt] = (f32x4){0.f, 0.f, 0.f, 0.f};
        #pragma unroll
        for (int ks = 0; ks < KSTEPS; ks++) {
            int c = ks * 4 + quad;
            bf16x8 afr[4];
            #pragma unroll
            for (int mt = 0; mt < 4; mt++) {
                int m = mt * 16 + l15;
                int slot = (c & ~7) | ((c ^ m) & 7);
                afr[mt] = *(const bf16x8*)(&inA[m * ROWDW + slot * 4]);
            }
            int n = hh * 128 + w * 16 + l15;
            size_t bidx = (((size_t)c << 9) + n) << 3;
            bf16x8 bh = *(const bf16x8*)(W1hi + bidx);
            #pragma unroll
            for (int mt = 0; mt < 4; mt++)
                acc[mt] = __builtin_amdgcn_mfma_f32_16x16x32_bf16(afr[mt], bh, acc[mt], 0, 0, 0);
            if (HASLO) {
                bf16x8 bl = *(const bf16x8*)(W1lo + bidx);
                #pragma unroll
                for (int mt = 0; mt < 4; mt++)
                    acc[mt] = __builtin_amdgcn_mfma_f32_16x16x32_bf16(afr[mt], bl, acc[mt], 0, 0, 0);
            }
        }
        __syncthreads();
        {
            int kh = w * 16 + l15;
            int c = kh >> 3;
            #pragma unroll
            for (int mt = 0; mt < 4; mt++) {
                #pragma unroll
                for (int r = 0; r < 4; r++) {
                    int m = mt * 16 + quad * 4 + r;
                    float s = silu_fast(acc[mt][r]);
                    int slot = (c & 8) | ((c ^ m) & 7);
                    hA[m * 128 + slot * 8 + (kh & 7)] = (u16)f2bfb(s);
                }
            }
        }
        __syncthreads();
        #pragma unroll
        for (int ks = 0; ks < 4; ks++) {
            int c = ks * 4 + quad;
            int m0 = mt2a * 16 + l15;
            int m1i = m0 + 16;
            int s0 = (c & 8) | ((c ^ m0) & 7);
            int s1 = (c & 8) | ((c ^ m1i) & 7);
            bf16x8 a0 = *(const bf16x8*)(&hA[m0 * 128 + s0 * 8]);
            bf16x8 a1 = *(const bf16x8*)(&hA[m1i * 128 + s1 * 8]);
            size_t bidx = (((size_t)(hh * 16 + c) << 6) + nt2 * 16 + l15) << 3;
            bf16x8 bh = *(const bf16x8*)(W2hi + bidx);
            acc2[0] = __builtin_amdgcn_mfma_f32_16x16x32_bf16(a0, bh, acc2[0], 0, 0, 0);
            acc2[1] = __builtin_amdgcn_mfma_f32_16x16x32_bf16(a1, bh, acc2[1], 0, 0, 0);
            bf16x8 bl = *(const bf16x8*)(W2lo + bidx);
            acc2[0] = __builtin_amdgcn_mfma_f32_16x16x32_bf16(a0, bl, acc2[0], 0, 0, 0);
            acc2[1] = __builtin_amdgcn_mfma_f32_16x16x32_bf16(a1, bl, acc2[1], 0, 0, 0);
        }
    }
    // read xprev (chunks 0..7 hold current-layer x) from LDS before epi overlay
    float xo[8];
    if (MODE) {
        int c = w;
        int slot = (c & ~7) | ((c ^ lane) & 7);
        #pragma unroll
        for (int i = 0; i < 4; i++) {
            u32 pv = inA[lane * ROWDW + slot * 4 + i];
            xo[2 * i]     = bfb2f(pv & 0xffffu);
            xo[2 * i + 1] = bfb2f(pv >> 16);
        }
    }
    __syncthreads();
    float* epi = (float*)inA;   // 64 x 65 fp32 overlay
    #pragma unroll
    for (int mi = 0; mi < 2; mi++) {
        #pragma unroll
        for (int r = 0; r < 4; r++) {
            int m = (mt2a + mi) * 16 + quad * 4 + r;
            int c = nt2 * 16 + l15;
            epi[c * 65 + m] = acc2[mi][r];
        }
    }
    __syncthreads();
    float env = envb[e];
    const float is2 = 0.70710678118654752f;
    #pragma unroll
    for (int i = 0; i < 8; i++) {
        int c = w * 8 + i;
        float v = epi[c * 65 + lane];
        float res;
        if (MODE) res = (xo[i] + v * env) * is2;
        else      res = v * env;
        xout[(size_t)c * E_NUM + e] = (u16)f2bfb(res);
        if (FUSEWE) epi[c * 65 + lane] = res;
    }
    if (FUSEWE) {
        __syncthreads();
        int mt = w & 3;
        int ntb = (w >> 2) * 2;
        f32x4 accw[2];
        accw[0] = (f32x4){0.f, 0.f, 0.f, 0.f};
        accw[1] = (f32x4){0.f, 0.f, 0.f, 0.f};
        #pragma unroll
        for (int ks = 0; ks < 2; ks++) {
            bf16x8 af;
            #pragma unroll
            for (int j = 0; j < 8; j++)
                af[j] = (short)f2bfb(epi[(ks * 32 + quad * 8 + j) * 65 + mt * 16 + l15]);
            #pragma unroll
            for (int nti = 0; nti < 2; nti++) {
                int n4 = (ntb + nti) * 16 + l15;
                size_t bidx = (((size_t)(ks * 4 + quad) << 6) + n4) << 3;
                bf16x8 bh = *(const bf16x8*)(wehi + bidx);
                accw[nti] = __builtin_amdgcn_mfma_f32_16x16x32_bf16(af, bh, accw[nti], 0, 0, 0);
                bf16x8 bl = *(const bf16x8*)(welo + bidx);
                accw[nti] = __builtin_amdgcn_mfma_f32_16x16x32_bf16(af, bl, accw[nti], 0, 0, 0);
            }
        }
        #pragma unroll
        for (int nti = 0; nti < 2; nti++) {
            #pragma unroll
            for (int r = 0; r < 4; r++) {
                int rowD = mt * 16 + quad * 4 + r;
                int colD = (ntb + nti) * 16 + l15;
                webuf[(size_t)(e0 + rowD) * 64 + colD] = accw[nti][r];
            }
        }
    }
}

// ---------------- readout ----------------
__global__ void k_readout(const u16* __restrict__ x, const float* __restrict__ Wout,
                          const float* __restrict__ envb, const int* __restrict__ srecv,
                          float* __restrict__ node_acc) {
    int e = blockIdx.x * 256 + threadIdx.x;
    if (e >= E_NUM) return;
    float a = 0.0f;
    #pragma unroll
    for (int c = 0; c < 64; c++) {
        a = fmaf(bfb2f((u32)x[(size_t)c * E_NUM + e]), Wout[c], a);
    }
    a *= envb[e] * (1.0f / 3.0f);
    atomicAdd(&node_acc[srecv[e]], a);
}

__global__ void k_out(const float* __restrict__ node_acc, void* __restrict__ out,
                      const int* __restrict__ flag) {
    int n = blockIdx.x * 256 + threadIdx.x;
    if (n >= NN) return;
    float v = node_acc[n];
    if (*flag) ((float*)out)[n] = v;
    else       ((u16*)out)[n] = (u16)f2bfb(v);
}

extern "C" void kernel_launch(void* const* d_in, const int* in_sizes, int n_in,
                              void* d_out, int out_size, void* d_ws, size_t ws_size,
                              hipStream_t stream) {
    const void* posr   = d_in[0];
    const void* Wemb1r = d_in[1];
    const void* Wemb2r = d_in[2];
    const void* Wvr    = d_in[3];
    const void* Wenvr  = d_in[4];
    const void* Wlat1r = d_in[5];
    const void* Wlat2r = d_in[6];
    const void* Wmixr  = d_in[7];
    const void* Woutr  = d_in[8];
    const int* species   = (const int*)d_in[9];
    const int* senders   = (const int*)d_in[10];
    const int* receivers = (const int*)d_in[11];

    char* p = (char*)d_ws;
    auto alloc = [&](size_t bytes) -> void* {
        void* rp = (void*)p;
        p += (bytes + 255) & ~(size_t)255;
        return rp;
    };
    int*   flag  = (int*)alloc(4);
    float* wbuf  = (float*)alloc(359792 * 4);
    float* posf  = wbuf;
    float* Wemb1 = wbuf + 30000;
    float* Wemb2 = wbuf + 36144;
    float* Wv    = wbuf + 68912;
    float* Wenv  = wbuf + 73008;
    float* Wlat1 = wbuf + 81200;
    float* Wlat2 = wbuf + 277808;
    float* Wmix  = wbuf + 343344;
    float* Wout  = wbuf + 359728;
    const size_t E = E_NUM;
    float* ux   = (float*)alloc(E * 4);
    float* uy   = (float*)alloc(E * 4);
    float* uz   = (float*)alloc(E * 4);
    float* envb = (float*)alloc(E * 4);
    float* rho0A = (float*)alloc((size_t)NN * 64 * 4);
    float* rho1A = (float*)alloc((size_t)NN * 192 * 4);
    float* rho0B = (float*)alloc((size_t)NN * 64 * 4);
    float* rho1B = (float*)alloc((size_t)NN * 192 * 4);
    float* node_acc = (float*)alloc((size_t)NN * 4);
    int* counts    = (int*)alloc((size_t)NN * 4);
    int* rowstart  = (int*)alloc((size_t)(NN + 1) * 4);
    int* cursor    = (int*)alloc((size_t)NN * 4);
    int* edge_list = (int*)alloc(E * 4);
    int* ssend     = (int*)alloc(E * 4);
    int* srecv     = (int*)alloc(E * 4);
    void* unionbuf = alloc(96 * E * 4);
    u32*   latin = (u32*)unionbuf;
    float* webuf = (float*)unionbuf + (size_t)32 * E;
    u16* x0 = (u16*)alloc(64 * E * 2);
    u16* x1 = (u16*)alloc(64 * E * 2);
    u16* w1hi = (u16*)alloc(2 * 98304 * 2);
    u16* w1lo = (u16*)alloc(2 * 98304 * 2);
    u16* w2hi = (u16*)alloc(2 * 32768 * 2);
    u16* w2lo = (u16*)alloc(2 * 32768 * 2);
    u16* e1hi = (u16*)alloc(32768 * 2);
    u16* e2hi = (u16*)alloc(32768 * 2);
    u16* e2lo = (u16*)alloc(32768 * 2);
    u16* we0hi = (u16*)alloc(4096 * 2);
    u16* we0lo = (u16*)alloc(4096 * 2);
    u16* we1hi = (u16*)alloc(4096 * 2);
    u16* we1lo = (u16*)alloc(4096 * 2);
    u16* wvhi  = (u16*)alloc(4096 * 2);
    u16* wvlo  = (u16*)alloc(4096 * 2);
    u16* wmhi  = (u16*)alloc(8192 * 2);
    u16* wmlo  = (u16*)alloc(8192 * 2);

    hipMemsetAsync(flag, 0, 4, stream);
    hipMemsetAsync(counts, 0, (size_t)NN * 4, stream);
    hipMemsetAsync(node_acc, 0, (size_t)NN * 4, stream);
    hipMemsetAsync(latin + (size_t)18 * E, 0, (size_t)14 * E * 4, stream);

    k_detect<<<(15000 + 255) / 256, 256, 0, stream>>>((const u16*)posr, flag);

    k_cvt_all<<<(359792 + 255) / 256, 256, 0, stream>>>(
        posr, Wemb1r, Wemb2r, Wvr, Wenvr, Wlat1r, Wlat2r, Wmixr, Woutr,
        wbuf, flag);

    k_pack_emb1<<<128, 256, 0, stream>>>(Wemb1, e1hi);
    k_pack<<<128, 256, 0, stream>>>(Wemb2, 512, 6, e2hi, e2lo);
    k_pack<<<16, 256, 0, stream>>>(Wenv, 64, 6, we0hi, we0lo);
    k_pack<<<16, 256, 0, stream>>>(Wenv + 4096, 64, 6, we1hi, we1lo);
    k_pack<<<16, 256, 0, stream>>>(Wv, 64, 6, wvhi, wvlo);
    k_pack<<<32, 256, 0, stream>>>(Wmix, 64, 7, wmhi, wmlo);
    for (int l = 0; l < 2; l++) {
        k_pack<<<384, 256, 0, stream>>>(Wlat1 + l * 98304, 192, 9,
                                        w1hi + l * 98304, w1lo + l * 98304);
        k_pack<<<128, 256, 0, stream>>>(Wlat2 + l * 32768, 512, 6,
                                        w2hi + l * 32768, w2lo + l * 32768);
    }

    // CSR over senders -> sorted edge order
    k_hist<<<625, 256, 0, stream>>>(senders, counts);
    k_scan<<<1, 1024, 0, stream>>>(counts, rowstart);
    k_copy_int<<<(NN + 255) / 256, 256, 0, stream>>>(rowstart, cursor, NN);
    k_fill<<<625, 256, 0, stream>>>(senders, cursor, edge_list);

    // embedding + fused layer-0 we
    k_geom<<<625, 256, 0, stream>>>(posf, species, senders, receivers, edge_list,
                                    ssend, srecv, ux, uy, uz, envb, latin);
    k_mlp<2, 0, 0, 1, 0><<<2500, 512, 0, stream>>>(
        latin, e1hi, nullptr, e2hi, e2lo, envb, x0, we0hi, we0lo, webuf,
        nullptr, nullptr, nullptr, nullptr, nullptr, nullptr,
        nullptr, nullptr, nullptr, nullptr, nullptr, nullptr, nullptr, nullptr);

    // layer 0 (fused stage) + fused layer-1 we
    k_rho_gather<<<2500, 256, 0, stream>>>(webuf, rowstart, ux, uy, uz,
                                           rho0A, rho1A);
    k_mlp<6, 1, 1, 1, 1><<<2500, 512, 0, stream>>>(
        nullptr, w1hi, w1lo, w2hi, w2lo, envb, x1, we1hi, we1lo, webuf,
        x0, nullptr, ssend, ux, uy, uz, rho0A, rho1A, nullptr, nullptr,
        wvhi, wvlo, nullptr, nullptr);

    // layer 1 (fused stage, compact m transpose)
    k_rho_gather<<<2500, 256, 0, stream>>>(webuf, rowstart, ux, uy, uz,
                                           rho0B, rho1B);
    k_mlp<6, 1, 1, 0, 2><<<2500, 512, 0, stream>>>(
        nullptr, w1hi + 98304, w1lo + 98304, w2hi + 32768, w2lo + 32768,
        envb, x1, nullptr, nullptr, nullptr,
        x1, x0, ssend, ux, uy, uz, rho0A, rho1A, rho0B, rho1B,
        wvhi, wvlo, wmhi, wmlo);

    k_readout<<<625, 256, 0, stream>>>(x1, Wout, envb, srecv, node_acc);
    k_out<<<(NN + 255) / 256, 256, 0, stream>>>(node_acc, d_out, flag);
}